// Round 2
// 122.666 us; speedup vs baseline: 1.1661x; 1.1661x over previous
//
#include <hip/hip_runtime.h>

// HTMM: C=32 states, L=4 fanout, M=128 symbols, DEPTH=7.
// Level starts: {0,1,5,21,85,341,1365,5461,21845}.
// SINGLE kernel, 256 blocks x 256 threads, one block per level-4 subtree.
// R14 = R13 resubmitted verbatim (R13 bench died with "container failed
// twice" = infra, not kernel: no compile error, no mismatch, and the
// barrier/spin logic is byte-identical to the R12 kernel that measured 83us).
// R13 change under test: top-tree DOWN sweep distributed across blocks.
// Evidence: OccupancyPercent 8.08 vs 12.5 full-residency => ~29us of the 83us
// kernel runs with ~0 occupancy. Cause: block 0 alone executed D0-D3 (full
// top-tree down sweep) after the barrier while 255 blocks exited. Fix: after
// the redundant phase-3 up sweep every block holds the full tbrT, so the
// down-sweep ll terms of each top node are computed by the lowest-indexed
// block whose path-walk passes through it (d=0: s==0, d=1: s&63==0,
// d=2: s&15==0, d=3: s&3==0), in group g==d: that group upgrades its step-d
// wonly128 to wu128 (same w, extra u) + 4-child ll epilogue. Coverage is
// exact/disjoint; block-0's serial D-phases (and 4 syncthreads) are gone.
// Groups 4-7 idle through phase 5 (they contributed nothing; halves LDS
// contention on the walk's critical path).

static constexpr int OFF_B4   = 0;      // level-4 betas [s*32+i] (8192 f)
static constexpr int OFF_PART = 8192;   // 256 doubles (512 f)
static constexpr int IC1      = 8704;   // 16 arrival counters, stride 32 ints
static constexpr int IROOT1   = 9216;   // arrival root counter
static constexpr int IREL     = 9248;   // 16 release words, stride 32 ints
static constexpr int IC2      = 9760;   // 16 finalize counters, stride 32 ints
static constexpr int IROOT2   = 10272;  // finalize root counter
static constexpr int MAGIC    = 0x5CA1AB1E;

__device__ __forceinline__ float rsum32(float v) {
#pragma unroll
  for (int k = 1; k <= 16; k <<= 1) v += __shfl_xor(v, k);
  return v;
}
__device__ __forceinline__ void rsum32x2(float& a, float& b) {
#pragma unroll
  for (int k = 1; k <= 16; k <<= 1) { a += __shfl_xor(a, k); b += __shfl_xor(b, k); }
}
__device__ __forceinline__ void rsum32x4(float& a, float& b, float& c, float& d) {
#pragma unroll
  for (int k = 1; k <= 16; k <<= 1) {
    a += __shfl_xor(a, k); b += __shfl_xor(b, k);
    c += __shfl_xor(c, k); d += __shfl_xor(d, k);
  }
}
__device__ __forceinline__ float4 exp4f(float4 v) {
  return make_float4(__expf(v.x), __expf(v.y), __expf(v.z), __expf(v.w));
}

__device__ __forceinline__ float dot128(const float* Wr, const float* X) {
  float t0 = 0.f, t1 = 0.f, t2 = 0.f, t3 = 0.f;
#pragma unroll
  for (int j = 0; j < 32; ++j) {
    const float4 x = *(const float4*)(X + j * 4);
    t0 = fmaf(Wr[4 * j + 0], x.x, t0);
    t1 = fmaf(Wr[4 * j + 1], x.y, t1);
    t2 = fmaf(Wr[4 * j + 2], x.z, t2);
    t3 = fmaf(Wr[4 * j + 3], x.w, t3);
  }
  return (t0 + t1) + (t2 + t3);
}
// Two parents, shared Wr: 8 independent FMA chains, 2 LDS streams.
__device__ __forceinline__ void dot128x2(const float* Wr, const float* X0,
                                         const float* X1, float& o0, float& o1) {
  float a0 = 0.f, a1 = 0.f, a2 = 0.f, a3 = 0.f;
  float b0 = 0.f, b1 = 0.f, b2 = 0.f, b3 = 0.f;
#pragma unroll
  for (int j = 0; j < 32; ++j) {
    const float4 x = *(const float4*)(X0 + j * 4);
    const float4 y = *(const float4*)(X1 + j * 4);
    a0 = fmaf(Wr[4 * j + 0], x.x, a0); b0 = fmaf(Wr[4 * j + 0], y.x, b0);
    a1 = fmaf(Wr[4 * j + 1], x.y, a1); b1 = fmaf(Wr[4 * j + 1], y.y, b1);
    a2 = fmaf(Wr[4 * j + 2], x.z, a2); b2 = fmaf(Wr[4 * j + 2], y.z, b2);
    a3 = fmaf(Wr[4 * j + 3], x.w, a3); b3 = fmaf(Wr[4 * j + 3], y.w, b3);
  }
  o0 = (a0 + a1) + (a2 + a3);
  o1 = (b0 + b1) + (b2 + b3);
}

__device__ __forceinline__ void wu128(const float* Wr, const float* ALG,
                                      const float* rb, int lane,
                                      float w[4], float u[4]) {
  w[0] = w[1] = w[2] = w[3] = 0.f;
  u[0] = u[1] = u[2] = u[3] = 0.f;
#pragma unroll
  for (int ii = 0; ii < 32; ii += 4) {
    const float4 rv = *(const float4*)(rb + ii);
#pragma unroll
    for (int di = 0; di < 4; ++di) {
      const int i = ii + di;
      const float rr = (di == 0) ? rv.x : (di == 1) ? rv.y : (di == 2) ? rv.z : rv.w;
      const float4 av = *(const float4*)(ALG + i * 128 + lane * 4);
      w[0] = fmaf(Wr[i * 4 + 0], rr, w[0]); u[0] = fmaf(av.x, rr, u[0]);
      w[1] = fmaf(Wr[i * 4 + 1], rr, w[1]); u[1] = fmaf(av.y, rr, u[1]);
      w[2] = fmaf(Wr[i * 4 + 2], rr, w[2]); u[2] = fmaf(av.z, rr, u[2]);
      w[3] = fmaf(Wr[i * 4 + 3], rr, w[3]); u[3] = fmaf(av.w, rr, u[3]);
    }
  }
}
// Two parents share the SAME ALG ds_read_b128 stream (2x FLOP per LDS read).
__device__ __forceinline__ void wu128x2(const float* Wr, const float* ALG,
                                        const float* rb0, const float* rb1, int lane,
                                        float w0[4], float u0[4],
                                        float w1[4], float u1[4]) {
#pragma unroll
  for (int l = 0; l < 4; ++l) { w0[l] = u0[l] = w1[l] = u1[l] = 0.f; }
#pragma unroll
  for (int ii = 0; ii < 32; ii += 4) {
    const float4 r0 = *(const float4*)(rb0 + ii);
    const float4 r1 = *(const float4*)(rb1 + ii);
#pragma unroll
    for (int di = 0; di < 4; ++di) {
      const int i = ii + di;
      const float q0 = (di == 0) ? r0.x : (di == 1) ? r0.y : (di == 2) ? r0.z : r0.w;
      const float q1 = (di == 0) ? r1.x : (di == 1) ? r1.y : (di == 2) ? r1.z : r1.w;
      const float4 av = *(const float4*)(ALG + i * 128 + lane * 4);
      w0[0] = fmaf(Wr[i * 4 + 0], q0, w0[0]); w1[0] = fmaf(Wr[i * 4 + 0], q1, w1[0]);
      u0[0] = fmaf(av.x, q0, u0[0]);          u1[0] = fmaf(av.x, q1, u1[0]);
      w0[1] = fmaf(Wr[i * 4 + 1], q0, w0[1]); w1[1] = fmaf(Wr[i * 4 + 1], q1, w1[1]);
      u0[1] = fmaf(av.y, q0, u0[1]);          u1[1] = fmaf(av.y, q1, u1[1]);
      w0[2] = fmaf(Wr[i * 4 + 2], q0, w0[2]); w1[2] = fmaf(Wr[i * 4 + 2], q1, w1[2]);
      u0[2] = fmaf(av.z, q0, u0[2]);          u1[2] = fmaf(av.z, q1, u1[2]);
      w0[3] = fmaf(Wr[i * 4 + 3], q0, w0[3]); w1[3] = fmaf(Wr[i * 4 + 3], q1, w1[3]);
      u0[3] = fmaf(av.w, q0, u0[3]);          u1[3] = fmaf(av.w, q1, u1[3]);
    }
  }
}
// Path walk: w only.
__device__ __forceinline__ void wonly128(const float* Wr, const float* rb,
                                         float w[4]) {
  w[0] = w[1] = w[2] = w[3] = 0.f;
#pragma unroll
  for (int ii = 0; ii < 32; ii += 4) {
    const float4 rv = *(const float4*)(rb + ii);
#pragma unroll
    for (int di = 0; di < 4; ++di) {
      const int i = ii + di;
      const float rr = (di == 0) ? rv.x : (di == 1) ? rv.y : (di == 2) ? rv.z : rv.w;
      w[0] = fmaf(Wr[i * 4 + 0], rr, w[0]);
      w[1] = fmaf(Wr[i * 4 + 1], rr, w[1]);
      w[2] = fmaf(Wr[i * 4 + 2], rr, w[2]);
      w[3] = fmaf(Wr[i * 4 + 3], rr, w[3]);
    }
  }
}

__global__ __launch_bounds__(256, 1) void k_fused(const int* __restrict__ labels,
                                                  const float* __restrict__ A,
                                                  const float* __restrict__ B,
                                                  const float* __restrict__ Pi,
                                                  const float* __restrict__ SP,
                                                  float* __restrict__ ws,
                                                  float* __restrict__ out) {
  __shared__ __align__(16) float scr[4224];
  __shared__ __align__(16) float regB[4224];
  __shared__ __align__(16) float sPt[132];
  __shared__ __align__(16) float tbrT[2720];
  __shared__ __align__(16) float tbS[672];
  __shared__ __align__(16) float ownb[32];
  __shared__ __align__(16) float r_buf[512];
  __shared__ int labs[425];
  __shared__ int fin;
  const int t = threadIdx.x, lane = t & 31, grp = t >> 5;  // 8 groups
  const int s = blockIdx.x;
  int* wsi = (int*)ws;
  double* partd = (double*)(ws + OFF_PART);
  const float4* A4 = (const float4*)A;
  const float4* B4 = (const float4*)B;

  // ---------- phase 1: softmax tables ----------
  const float sv0 = SP[0], sv1 = SP[1], sv2 = SP[2], sv3 = SP[3];
  const float sp0 = __expf(sv0), sp1 = __expf(sv1), sp2 = __expf(sv2), sp3 = __expf(sv3);
  const float spsum = sp0 + sp1 + sp2 + sp3;
  const float spinv = 1.f / spsum;
  const float lss = __logf(spsum);
  float4 c4 = make_float4(0.f, 0.f, 0.f, 0.f);
  for (int i = 0; i < 32; ++i) {
    const float4 e = exp4f(A4[i * 32 + lane]);
    c4.x += e.x; c4.y += e.y; c4.z += e.z; c4.w += e.w;
  }
  const float4 inv4 = make_float4(sp0 * spinv / c4.x, sp1 * spinv / c4.y,
                                  sp2 * spinv / c4.z, sp3 * spinv / c4.w);
  const float4 sub4 = make_float4(__logf(c4.x) - (sv0 - lss), __logf(c4.y) - (sv1 - lss),
                                  __logf(c4.z) - (sv2 - lss), __logf(c4.w) - (sv3 - lss));
#pragma unroll
  for (int k = 0; k < 4; ++k) {  // asp (up layout, stride 132)
    const int i = grp * 4 + k;
    const float4 e = exp4f(A4[i * 32 + lane]);
    *(float4*)(scr + i * 132 + 4 * lane) =
        make_float4(e.x * inv4.x, e.y * inv4.y, e.z * inv4.z, e.w * inv4.w);
  }
#pragma unroll
  for (int rI = 0; rI < 4; ++rI) {  // smB^T
    const int i = grp + rI * 8;
    const float4 e = exp4f(B4[i * 32 + lane]);
    const float sinv = 1.f / rsum32(e.x + e.y + e.z + e.w);
    regB[(4 * lane + 0) * 33 + i] = e.x * sinv;
    regB[(4 * lane + 1) * 33 + i] = e.y * sinv;
    regB[(4 * lane + 2) * 33 + i] = e.z * sinv;
    regB[(4 * lane + 3) * 33 + i] = e.w * sinv;
  }
  if (grp < 4) {  // smPi^T
    const float e = __expf(Pi[lane * 4 + grp]);
    sPt[grp * 33 + lane] = e / rsum32(e);
  }
  for (int idx = t; idx < 341; idx += 256) labs[idx] = labels[idx];
  if (t < 84) {
    int g, d;
    if (t < 4) { g = 341 + 4 * s + t; d = 341 + t; }
    else if (t < 20) { g = 1365 + 16 * s + (t - 4); d = 345 + (t - 4); }
    else { g = 5461 + 64 * s + (t - 20); d = 361 + (t - 20); }
    labs[d] = labels[g];
  }
  __syncthreads();
  float Wr[128];  // up orientation
#pragma unroll
  for (int j = 0; j < 32; ++j) {
    const float4 v = *(const float4*)(scr + lane * 132 + j * 4);
    Wr[4 * j] = v.x; Wr[4 * j + 1] = v.y; Wr[4 * j + 2] = v.z; Wr[4 * j + 3] = v.w;
  }
  __syncthreads();

  // ---------- phase 2: subtree up sweep ----------
#pragma unroll
  for (int h = 0; h < 2; ++h) {  // S1: 64 leaves, batches of 4
    const int q0 = grp + 32 * h, q1 = q0 + 8, q2 = q0 + 16, q3 = q0 + 24;
    float v0 = sPt[(q0 & 3) * 33 + lane] * regB[labs[361 + q0] * 33 + lane];
    float v1 = sPt[(q1 & 3) * 33 + lane] * regB[labs[361 + q1] * 33 + lane];
    float v2 = sPt[(q2 & 3) * 33 + lane] * regB[labs[361 + q2] * 33 + lane];
    float v3 = sPt[(q3 & 3) * 33 + lane] * regB[labs[361 + q3] * 33 + lane];
    float s0 = v0, s1 = v1, s2 = v2, s3 = v3;
    rsum32x4(s0, s1, s2, s3);
    scr[(q0 >> 2) * 128 + lane * 4 + (q0 & 3)] = v0 / s0;
    scr[(q1 >> 2) * 128 + lane * 4 + (q1 & 3)] = v1 / s1;
    scr[(q2 >> 2) * 128 + lane * 4 + (q2 & 3)] = v2 / s2;
    scr[(q3 >> 2) * 128 + lane * 4 + (q3 & 3)] = v3 / s3;
  }
  __syncthreads();
  {  // S2: 16 L6 parents, paired
    const int p0 = grp, p1 = grp + 8;
    float tb0, tb1;
    dot128x2(Wr, scr + p0 * 128, scr + p1 * 128, tb0, tb1);
    float bl0 = tb0 * regB[labs[345 + p0] * 33 + lane];
    float bl1 = tb1 * regB[labs[345 + p1] * 33 + lane];
    float s0 = bl0, s1 = bl1;
    rsum32x2(s0, s1);
    bl0 /= s0; bl1 /= s1;
    tbS[(5 + p0) * 32 + lane] = tb0;
    tbS[(5 + p1) * 32 + lane] = tb1;
    scr[2048 + (p0 >> 2) * 128 + lane * 4 + (p0 & 3)] = bl0;  // X6
    scr[2048 + (p1 >> 2) * 128 + lane * 4 + (p1 & 3)] = bl1;
  }
  __syncthreads();
  if (grp < 4) {  // S3: 4 L5 parents
    const float tb = dot128(Wr, scr + 2048 + grp * 128);
    float bl = tb * regB[labs[341 + grp] * 33 + lane];
    bl /= rsum32(bl);
    tbS[(1 + grp) * 32 + lane] = tb;
    scr[2560 + lane * 4 + grp] = bl;  // X5
  }
  __syncthreads();
  if (grp == 0) {  // S4: own level-4 root; publish b4
    const float tb = dot128(Wr, scr + 2560);
    float bl = tb * regB[labs[85 + s] * 33 + lane];
    bl /= rsum32(bl);
    tbS[lane] = tb;
    ownb[lane] = bl;
    ws[OFF_B4 + s * 32 + lane] = bl;
  }
  __syncthreads();

  // ---------- tree barrier: pure-atomic arrival + fan-out release words,
  // ----------               RMW polls (coherence-point reads) ----------
  if (t == 0) {
    __threadfence();
    if (atomicAdd(&wsi[IC1 + 32 * (s >> 4)], 1) == 15) {
      if (atomicAdd(&wsi[IROOT1], 1) == 15) {
        // last arriver releases all 16 group lines
#pragma unroll
        for (int g = 0; g < 16; ++g) atomicExch(&wsi[IREL + 32 * g], MAGIC);
      }
    }
    while (atomicAdd(&wsi[IREL + 32 * (s >> 4)], 0) != MAGIC)
      __builtin_amdgcn_s_sleep(2);
  }
  __syncthreads();
  __threadfence();

  // ---------- phase 3: top up sweep (redundant per block), paired ----------
#pragma unroll
  for (int k = 0; k < 4; ++k) {  // 64 L3 parents: 4 paired rounds
    const int p0 = grp + 16 * k, p1 = p0 + 8;
    float* st0 = scr + grp * 128;
    float* st1 = scr + 1024 + grp * 128;
#pragma unroll
    for (int l = 0; l < 4; ++l) {
      st0[lane * 4 + l] = ws[OFF_B4 + (p0 * 4 + l) * 32 + lane];
      st1[lane * 4 + l] = ws[OFF_B4 + (p1 * 4 + l) * 32 + lane];
    }
    float tb0, tb1;
    dot128x2(Wr, st0, st1, tb0, tb1);
    float bl0 = tb0 * regB[labs[21 + p0] * 33 + lane];
    float bl1 = tb1 * regB[labs[21 + p1] * 33 + lane];
    float s0 = bl0, s1 = bl1;
    rsum32x2(s0, s1);
    bl0 /= s0; bl1 /= s1;
    tbrT[(21 + p0) * 32 + lane] = tb0;
    tbrT[(21 + p1) * 32 + lane] = tb1;
    scr[2048 + (p0 >> 2) * 128 + lane * 4 + (p0 & 3)] = bl0;  // bX3
    scr[2048 + (p1 >> 2) * 128 + lane * 4 + (p1 & 3)] = bl1;
  }
  __syncthreads();
  {  // 16 L2 parents, paired
    const int p0 = grp, p1 = grp + 8;
    float tb0, tb1;
    dot128x2(Wr, scr + 2048 + p0 * 128, scr + 2048 + p1 * 128, tb0, tb1);
    float bl0 = tb0 * regB[labs[5 + p0] * 33 + lane];
    float bl1 = tb1 * regB[labs[5 + p1] * 33 + lane];
    float s0 = bl0, s1 = bl1;
    rsum32x2(s0, s1);
    bl0 /= s0; bl1 /= s1;
    tbrT[(5 + p0) * 32 + lane] = tb0;
    tbrT[(5 + p1) * 32 + lane] = tb1;
    scr[1024 + (p0 >> 2) * 128 + lane * 4 + (p0 & 3)] = bl0;  // bX2
    scr[1024 + (p1 >> 2) * 128 + lane * 4 + (p1 & 3)] = bl1;
  }
  __syncthreads();
  if (grp < 4) {  // 4 L1 parents
    const float tb = dot128(Wr, scr + 1024 + grp * 128);
    float bl = tb * regB[labs[1 + grp] * 33 + lane];
    bl /= rsum32(bl);
    tbrT[(1 + grp) * 32 + lane] = tb;
    scr[1536 + lane * 4 + grp] = bl;  // bX1
  }
  __syncthreads();
  if (grp == 0) tbrT[lane] = dot128(Wr, scr + 1536);  // root tb
  __syncthreads();

  // ---------- phase 4: transition to down tables ----------
  for (int idx = t; idx < 4224; idx += 256) regB[idx] = __logf(regB[idx]);
  if (t < 132) sPt[t] = __logf(sPt[t]);
#pragma unroll
  for (int i = 0; i < 32; ++i) {  // Wr -> down orient (lane=j); scr -> ALG
    const float4 av = A4[i * 32 + lane];
    const float4 e = exp4f(av);
    const float4 asp = make_float4(e.x * inv4.x, e.y * inv4.y, e.z * inv4.z, e.w * inv4.w);
    Wr[i * 4 + 0] = asp.x; Wr[i * 4 + 1] = asp.y;
    Wr[i * 4 + 2] = asp.z; Wr[i * 4 + 3] = asp.w;
    if (grp == (i >> 2))
      *(float4*)(scr + i * 128 + lane * 4) =
          make_float4(asp.x * (av.x - sub4.x), asp.y * (av.y - sub4.y),
                      asp.z * (av.z - sub4.z), asp.w * (av.w - sub4.w));
  }
  __syncthreads();

  // ---------- phase 5: top down, DISTRIBUTED owners (grps 0-3 walk; grp g
  // ---------- owns the level-g node on this block's path iff this block is
  // ---------- the lowest-indexed block through it) ----------
  double ll = 0.0;
  float eps4own = 0.f;  // valid in grp 0
  if (grp < 4) {
    const int n1 = 1 + (s >> 6), n2 = 5 + (s >> 4), n3 = 21 + (s >> 2);
    const int a0 = s >> 6, a1 = (s >> 4) & 3, a2 = (s >> 2) & 3, a3 = s & 3;
    float w[4], uv[4];
    float* rb = r_buf + grp * 32;

    // ---- step 0: root (owner: block 0, grp 0) ----
    float tbv = tbrT[lane];
    float bcv = tbv * __expf(regB[labs[0] * 33 + lane]);
    bcv /= rsum32(bcv);
    rb[lane] = bcv / tbv;
    if (grp == 0 && s == 0) {
      ll += (double)(bcv * regB[labs[0] * 33 + lane]);  // root eps*logB
      wu128(Wr, scr, rb, lane, w, uv);
      const float lb0 = regB[labs[1] * 33 + lane], lb1 = regB[labs[2] * 33 + lane];
      const float lb2 = regB[labs[3] * 33 + lane], lb3 = regB[labs[4] * 33 + lane];
      float b0 = tbrT[1 * 32 + lane] * __expf(lb0);
      float b1 = tbrT[2 * 32 + lane] * __expf(lb1);
      float b2 = tbrT[3 * 32 + lane] * __expf(lb2);
      float b3 = tbrT[4 * 32 + lane] * __expf(lb3);
      float s0 = b0, s1 = b1, s2 = b2, s3 = b3;
      rsum32x4(s0, s1, s2, s3);
      b0 /= s0; b1 /= s1; b2 /= s2; b3 /= s3;
      ll += (double)(b0 * uv[0]) + (double)(b0 * w[0] * lb0);
      ll += (double)(b1 * uv[1]) + (double)(b1 * w[1] * lb1);
      ll += (double)(b2 * uv[2]) + (double)(b2 * w[2] * lb2);
      ll += (double)(b3 * uv[3]) + (double)(b3 * w[3] * lb3);
    } else {
      wonly128(Wr, rb, w);
    }

    // ---- step 1: node n1 (owner: s&63==0, grp 1) ----
    tbv = tbrT[n1 * 32 + lane];
    bcv = tbv * __expf(regB[labs[n1] * 33 + lane]);
    bcv /= rsum32(bcv);
    rb[lane] = (bcv * w[a0]) / tbv;
    if (grp == 1 && (s & 63) == 0) {
      wu128(Wr, scr, rb, lane, w, uv);
      const int cb = 5 + 4 * (s >> 6);
      const float lb0 = regB[labs[cb + 0] * 33 + lane], lb1 = regB[labs[cb + 1] * 33 + lane];
      const float lb2 = regB[labs[cb + 2] * 33 + lane], lb3 = regB[labs[cb + 3] * 33 + lane];
      float b0 = tbrT[(cb + 0) * 32 + lane] * __expf(lb0);
      float b1 = tbrT[(cb + 1) * 32 + lane] * __expf(lb1);
      float b2 = tbrT[(cb + 2) * 32 + lane] * __expf(lb2);
      float b3 = tbrT[(cb + 3) * 32 + lane] * __expf(lb3);
      float s0 = b0, s1 = b1, s2 = b2, s3 = b3;
      rsum32x4(s0, s1, s2, s3);
      b0 /= s0; b1 /= s1; b2 /= s2; b3 /= s3;
      ll += (double)(b0 * uv[0]) + (double)(b0 * w[0] * lb0);
      ll += (double)(b1 * uv[1]) + (double)(b1 * w[1] * lb1);
      ll += (double)(b2 * uv[2]) + (double)(b2 * w[2] * lb2);
      ll += (double)(b3 * uv[3]) + (double)(b3 * w[3] * lb3);
    } else {
      wonly128(Wr, rb, w);
    }

    // ---- step 2: node n2 (owner: s&15==0, grp 2) ----
    tbv = tbrT[n2 * 32 + lane];
    bcv = tbv * __expf(regB[labs[n2] * 33 + lane]);
    bcv /= rsum32(bcv);
    rb[lane] = (bcv * w[a1]) / tbv;
    if (grp == 2 && (s & 15) == 0) {
      wu128(Wr, scr, rb, lane, w, uv);
      const int cb = 21 + 4 * (s >> 4);
      const float lb0 = regB[labs[cb + 0] * 33 + lane], lb1 = regB[labs[cb + 1] * 33 + lane];
      const float lb2 = regB[labs[cb + 2] * 33 + lane], lb3 = regB[labs[cb + 3] * 33 + lane];
      float b0 = tbrT[(cb + 0) * 32 + lane] * __expf(lb0);
      float b1 = tbrT[(cb + 1) * 32 + lane] * __expf(lb1);
      float b2 = tbrT[(cb + 2) * 32 + lane] * __expf(lb2);
      float b3 = tbrT[(cb + 3) * 32 + lane] * __expf(lb3);
      float s0 = b0, s1 = b1, s2 = b2, s3 = b3;
      rsum32x4(s0, s1, s2, s3);
      b0 /= s0; b1 /= s1; b2 /= s2; b3 /= s3;
      ll += (double)(b0 * uv[0]) + (double)(b0 * w[0] * lb0);
      ll += (double)(b1 * uv[1]) + (double)(b1 * w[1] * lb1);
      ll += (double)(b2 * uv[2]) + (double)(b2 * w[2] * lb2);
      ll += (double)(b3 * uv[3]) + (double)(b3 * w[3] * lb3);
    } else {
      wonly128(Wr, rb, w);
    }

    // ---- step 3: node n3 (owner: s&3==0, grp 3); children are L4 (b4) ----
    tbv = tbrT[n3 * 32 + lane];
    bcv = tbv * __expf(regB[labs[n3] * 33 + lane]);
    bcv /= rsum32(bcv);
    rb[lane] = (bcv * w[a2]) / tbv;
    if (grp == 3 && (s & 3) == 0) {
      wu128(Wr, scr, rb, lane, w, uv);
      const int cb = s & ~3;  // 4*(s>>2)
#pragma unroll
      for (int l = 0; l < 4; ++l) {
        const int ci = cb + l;
        const float bc = ws[OFF_B4 + ci * 32 + lane];
        const float e = bc * w[l];
        ll += (double)(bc * uv[l]) + (double)(e * regB[labs[85 + ci] * 33 + lane]);
      }
    } else {
      wonly128(Wr, rb, w);
    }
    eps4own = ownb[lane] * w[a3];
  }
  __syncthreads();

  // ---------- phase 6: subtree down sweep ----------
  if (grp == 0) {  // d0: own L4 node -> L5 children
    r_buf[lane] = eps4own / tbS[lane];
    float w[4], u[4];
    wu128(Wr, scr, r_buf, lane, w, u);
#pragma unroll
    for (int l = 0; l < 4; ++l) {
      const int lab = labs[341 + l];
      const float tbv = tbS[(1 + l) * 32 + lane];
      float bcv = tbv * __expf(regB[lab * 33 + lane]);
      bcv /= rsum32(bcv);
      const float e = bcv * w[l];
      ll += (double)(bcv * u[l]) + (double)(e * regB[lab * 33 + lane]);
      tbS[(1 + l) * 32 + lane] = e / tbv;
    }
  }
  __syncthreads();
  if (grp < 4) {  // d1: 4 L5 parents -> L6 children
    const int p = grp;
    r_buf[p * 32 + lane] = tbS[(1 + p) * 32 + lane];
    float w[4], u[4];
    wu128(Wr, scr, r_buf + p * 32, lane, w, u);
#pragma unroll
    for (int l = 0; l < 4; ++l) {
      const int q = p * 4 + l;
      const int lab = labs[345 + q];
      const float tbv = tbS[(5 + q) * 32 + lane];
      float bcv = tbv * __expf(regB[lab * 33 + lane]);
      bcv /= rsum32(bcv);
      const float e = bcv * w[l];
      ll += (double)(bcv * u[l]) + (double)(e * regB[lab * 33 + lane]);
      tbS[(5 + q) * 32 + lane] = e / tbv;
    }
  }
  __syncthreads();
  {  // d2: 16 L6 parents -> leaves, paired
    const int p0 = grp, p1 = grp + 8;
    float* rb0 = r_buf + grp * 32;
    float* rb1 = r_buf + 256 + grp * 32;
    rb0[lane] = tbS[(5 + p0) * 32 + lane];
    rb1[lane] = tbS[(5 + p1) * 32 + lane];
    float w0[4], u0[4], w1[4], u1[4];
    wu128x2(Wr, scr, rb0, rb1, lane, w0, u0, w1, u1);
#pragma unroll
    for (int l = 0; l < 4; ++l) {
      const int q0 = p0 * 4 + l, q1 = p1 * 4 + l;
      const float lb0 = regB[labs[361 + q0] * 33 + lane];
      const float lb1 = regB[labs[361 + q1] * 33 + lane];
      const float lp = sPt[l * 33 + lane];
      float b0 = __expf(lp + lb0);
      float b1 = __expf(lp + lb1);
      float s0 = b0, s1 = b1;
      rsum32x2(s0, s1);
      b0 /= s0; b1 /= s1;
      const float e0 = b0 * w0[l], e1 = b1 * w1[l];
      ll += (double)(b0 * u0[l]) + (double)(e0 * lb0) + (double)(e0 * lp);
      ll += (double)(b1 * u1[l]) + (double)(e1 * lb1) + (double)(e1 * lp);
    }
  }

  // ---------- phase 7: partials + tree finalize (poll-free atomics) ----------
#pragma unroll
  for (int k = 32; k >= 1; k >>= 1) ll += __shfl_xor(ll, k);
  double* rbd = (double*)r_buf;
  __syncthreads();
  if ((t & 63) == 0) rbd[t >> 6] = ll;
  __syncthreads();
  if (t == 0) {
    partd[s] = (rbd[0] + rbd[1]) + (rbd[2] + rbd[3]);
    __threadfence();
    int f = 0;
    if (atomicAdd(&wsi[IC2 + 32 * (s >> 4)], 1) == 15)
      if (atomicAdd(&wsi[IROOT2], 1) == 15) f = 1;
    fin = f;
  }
  __syncthreads();
  if (fin) {  // last block: all partials visible (first-touch reads)
    __threadfence();
    if (t < 64) {
      double v = 0.0;
      for (int k = t; k < 256; k += 64) v += partd[k];
#pragma unroll
      for (int k = 32; k >= 1; k >>= 1) v += __shfl_xor(v, k);
      if (t == 0) out[0] = (float)v;
    }
  }
}

extern "C" void kernel_launch(void* const* d_in, const int* in_sizes, int n_in,
                              void* d_out, int out_size, void* d_ws, size_t ws_size,
                              hipStream_t stream) {
  (void)in_sizes; (void)n_in; (void)out_size; (void)ws_size;
  const int* labels = (const int*)d_in[0];
  const float* A = (const float*)d_in[1];
  const float* B = (const float*)d_in[2];
  const float* Pi = (const float*)d_in[3];
  const float* SP = (const float*)d_in[4];
  float* ws = (float*)d_ws;
  float* out = (float*)d_out;

  // zero the counter region (ints IC1..IROOT2: [8704, 10273) * 4 bytes)
  hipMemsetAsync((char*)d_ws + IC1 * 4, 0, (IROOT2 + 1 - IC1) * 4, stream);
  hipLaunchKernelGGL(k_fused, dim3(256), dim3(256), 0, stream,
                     labels, A, B, Pi, SP, ws, out);
}

// Round 3
// 116.563 us; speedup vs baseline: 1.2272x; 1.0524x over previous
//
#include <hip/hip_runtime.h>

// HTMM: C=32 states, L=4 fanout, M=128 symbols, DEPTH=7.
// Level starts: {0,1,5,21,85,341,1365,5461,21845}.
// R15: SPLIT the single kernel at the device barrier into two kernels.
// Rationale: R14 measured 64.5us with only ~9us of modeled critical-path
// compute, VALUBusy 12.9%, HBM 0.17% => ~55us unattributed. The only
// structure outside the phase model is the in-kernel device barrier
// (2x __threadfence = L2 writeback+invalidate on non-coherent XCD L2s,
// chained device atomics, 16-line release, 256 RMW spin-pollers).
// The kernel boundary gives cross-XCD ordering for free (~2us graph gap).
// k_up   = phases 1-2 (tables + subtree up sweep), publish b4 to ws.
// k_down = full pipeline: recompute tables + own subtree (identical values,
//          ~+1.5us, avoids spilling tbS/ownb), top up sweep reading k_up's
//          b4, down tables, distributed top-down walk (R13), subtree down,
//          partials + poll-free finalize. k_down must NOT rewrite b4
//          (would race with other blocks' phase-3 reads).
// This is simultaneously the highest-expected-impact change and the
// localization experiment: per-kernel rocprof durs attribute the time.

static constexpr int OFF_B4   = 0;      // level-4 betas [s*32+i] (8192 f)
static constexpr int OFF_PART = 8192;   // 256 doubles (512 f)
static constexpr int IC1      = 8704;   // (unused in split version)
static constexpr int IROOT1   = 9216;
static constexpr int IREL     = 9248;
static constexpr int IC2      = 9760;   // 16 finalize counters, stride 32 ints
static constexpr int IROOT2   = 10272;  // finalize root counter

__device__ __forceinline__ float rsum32(float v) {
#pragma unroll
  for (int k = 1; k <= 16; k <<= 1) v += __shfl_xor(v, k);
  return v;
}
__device__ __forceinline__ void rsum32x2(float& a, float& b) {
#pragma unroll
  for (int k = 1; k <= 16; k <<= 1) { a += __shfl_xor(a, k); b += __shfl_xor(b, k); }
}
__device__ __forceinline__ void rsum32x4(float& a, float& b, float& c, float& d) {
#pragma unroll
  for (int k = 1; k <= 16; k <<= 1) {
    a += __shfl_xor(a, k); b += __shfl_xor(b, k);
    c += __shfl_xor(c, k); d += __shfl_xor(d, k);
  }
}
__device__ __forceinline__ float4 exp4f(float4 v) {
  return make_float4(__expf(v.x), __expf(v.y), __expf(v.z), __expf(v.w));
}

__device__ __forceinline__ float dot128(const float* Wr, const float* X) {
  float t0 = 0.f, t1 = 0.f, t2 = 0.f, t3 = 0.f;
#pragma unroll
  for (int j = 0; j < 32; ++j) {
    const float4 x = *(const float4*)(X + j * 4);
    t0 = fmaf(Wr[4 * j + 0], x.x, t0);
    t1 = fmaf(Wr[4 * j + 1], x.y, t1);
    t2 = fmaf(Wr[4 * j + 2], x.z, t2);
    t3 = fmaf(Wr[4 * j + 3], x.w, t3);
  }
  return (t0 + t1) + (t2 + t3);
}
// Two parents, shared Wr: 8 independent FMA chains, 2 LDS streams.
__device__ __forceinline__ void dot128x2(const float* Wr, const float* X0,
                                         const float* X1, float& o0, float& o1) {
  float a0 = 0.f, a1 = 0.f, a2 = 0.f, a3 = 0.f;
  float b0 = 0.f, b1 = 0.f, b2 = 0.f, b3 = 0.f;
#pragma unroll
  for (int j = 0; j < 32; ++j) {
    const float4 x = *(const float4*)(X0 + j * 4);
    const float4 y = *(const float4*)(X1 + j * 4);
    a0 = fmaf(Wr[4 * j + 0], x.x, a0); b0 = fmaf(Wr[4 * j + 0], y.x, b0);
    a1 = fmaf(Wr[4 * j + 1], x.y, a1); b1 = fmaf(Wr[4 * j + 1], y.y, b1);
    a2 = fmaf(Wr[4 * j + 2], x.z, a2); b2 = fmaf(Wr[4 * j + 2], y.z, b2);
    a3 = fmaf(Wr[4 * j + 3], x.w, a3); b3 = fmaf(Wr[4 * j + 3], y.w, b3);
  }
  o0 = (a0 + a1) + (a2 + a3);
  o1 = (b0 + b1) + (b2 + b3);
}

__device__ __forceinline__ void wu128(const float* Wr, const float* ALG,
                                      const float* rb, int lane,
                                      float w[4], float u[4]) {
  w[0] = w[1] = w[2] = w[3] = 0.f;
  u[0] = u[1] = u[2] = u[3] = 0.f;
#pragma unroll
  for (int ii = 0; ii < 32; ii += 4) {
    const float4 rv = *(const float4*)(rb + ii);
#pragma unroll
    for (int di = 0; di < 4; ++di) {
      const int i = ii + di;
      const float rr = (di == 0) ? rv.x : (di == 1) ? rv.y : (di == 2) ? rv.z : rv.w;
      const float4 av = *(const float4*)(ALG + i * 128 + lane * 4);
      w[0] = fmaf(Wr[i * 4 + 0], rr, w[0]); u[0] = fmaf(av.x, rr, u[0]);
      w[1] = fmaf(Wr[i * 4 + 1], rr, w[1]); u[1] = fmaf(av.y, rr, u[1]);
      w[2] = fmaf(Wr[i * 4 + 2], rr, w[2]); u[2] = fmaf(av.z, rr, u[2]);
      w[3] = fmaf(Wr[i * 4 + 3], rr, w[3]); u[3] = fmaf(av.w, rr, u[3]);
    }
  }
}
// Two parents share the SAME ALG ds_read_b128 stream (2x FLOP per LDS read).
__device__ __forceinline__ void wu128x2(const float* Wr, const float* ALG,
                                        const float* rb0, const float* rb1, int lane,
                                        float w0[4], float u0[4],
                                        float w1[4], float u1[4]) {
#pragma unroll
  for (int l = 0; l < 4; ++l) { w0[l] = u0[l] = w1[l] = u1[l] = 0.f; }
#pragma unroll
  for (int ii = 0; ii < 32; ii += 4) {
    const float4 r0 = *(const float4*)(rb0 + ii);
    const float4 r1 = *(const float4*)(rb1 + ii);
#pragma unroll
    for (int di = 0; di < 4; ++di) {
      const int i = ii + di;
      const float q0 = (di == 0) ? r0.x : (di == 1) ? r0.y : (di == 2) ? r0.z : r0.w;
      const float q1 = (di == 0) ? r1.x : (di == 1) ? r1.y : (di == 2) ? r1.z : r1.w;
      const float4 av = *(const float4*)(ALG + i * 128 + lane * 4);
      w0[0] = fmaf(Wr[i * 4 + 0], q0, w0[0]); w1[0] = fmaf(Wr[i * 4 + 0], q1, w1[0]);
      u0[0] = fmaf(av.x, q0, u0[0]);          u1[0] = fmaf(av.x, q1, u1[0]);
      w0[1] = fmaf(Wr[i * 4 + 1], q0, w0[1]); w1[1] = fmaf(Wr[i * 4 + 1], q1, w1[1]);
      u0[1] = fmaf(av.y, q0, u0[1]);          u1[1] = fmaf(av.y, q1, u1[1]);
      w0[2] = fmaf(Wr[i * 4 + 2], q0, w0[2]); w1[2] = fmaf(Wr[i * 4 + 2], q1, w1[2]);
      u0[2] = fmaf(av.z, q0, u0[2]);          u1[2] = fmaf(av.z, q1, u1[2]);
      w0[3] = fmaf(Wr[i * 4 + 3], q0, w0[3]); w1[3] = fmaf(Wr[i * 4 + 3], q1, w1[3]);
      u0[3] = fmaf(av.w, q0, u0[3]);          u1[3] = fmaf(av.w, q1, u1[3]);
    }
  }
}
// Path walk: w only.
__device__ __forceinline__ void wonly128(const float* Wr, const float* rb,
                                         float w[4]) {
  w[0] = w[1] = w[2] = w[3] = 0.f;
#pragma unroll
  for (int ii = 0; ii < 32; ii += 4) {
    const float4 rv = *(const float4*)(rb + ii);
#pragma unroll
    for (int di = 0; di < 4; ++di) {
      const int i = ii + di;
      const float rr = (di == 0) ? rv.x : (di == 1) ? rv.y : (di == 2) ? rv.z : rv.w;
      w[0] = fmaf(Wr[i * 4 + 0], rr, w[0]);
      w[1] = fmaf(Wr[i * 4 + 1], rr, w[1]);
      w[2] = fmaf(Wr[i * 4 + 2], rr, w[2]);
      w[3] = fmaf(Wr[i * 4 + 3], rr, w[3]);
    }
  }
}

// ============================ k_up: phases 1-2 =============================
__global__ __launch_bounds__(256, 1) void k_up(const int* __restrict__ labels,
                                               const float* __restrict__ A,
                                               const float* __restrict__ B,
                                               const float* __restrict__ Pi,
                                               const float* __restrict__ SP,
                                               float* __restrict__ ws) {
  __shared__ __align__(16) float scr[4224];
  __shared__ __align__(16) float regB[4224];
  __shared__ __align__(16) float sPt[132];
  __shared__ int labs[425];
  const int t = threadIdx.x, lane = t & 31, grp = t >> 5;
  const int s = blockIdx.x;
  const float4* A4 = (const float4*)A;
  const float4* B4 = (const float4*)B;

  // ---------- phase 1: softmax tables (subset needed for up sweep) ----------
  const float sv0 = SP[0], sv1 = SP[1], sv2 = SP[2], sv3 = SP[3];
  const float sp0 = __expf(sv0), sp1 = __expf(sv1), sp2 = __expf(sv2), sp3 = __expf(sv3);
  const float spsum = sp0 + sp1 + sp2 + sp3;
  const float spinv = 1.f / spsum;
  float4 c4 = make_float4(0.f, 0.f, 0.f, 0.f);
  for (int i = 0; i < 32; ++i) {
    const float4 e = exp4f(A4[i * 32 + lane]);
    c4.x += e.x; c4.y += e.y; c4.z += e.z; c4.w += e.w;
  }
  const float4 inv4 = make_float4(sp0 * spinv / c4.x, sp1 * spinv / c4.y,
                                  sp2 * spinv / c4.z, sp3 * spinv / c4.w);
#pragma unroll
  for (int k = 0; k < 4; ++k) {  // asp (up layout, stride 132)
    const int i = grp * 4 + k;
    const float4 e = exp4f(A4[i * 32 + lane]);
    *(float4*)(scr + i * 132 + 4 * lane) =
        make_float4(e.x * inv4.x, e.y * inv4.y, e.z * inv4.z, e.w * inv4.w);
  }
#pragma unroll
  for (int rI = 0; rI < 4; ++rI) {  // smB^T
    const int i = grp + rI * 8;
    const float4 e = exp4f(B4[i * 32 + lane]);
    const float sinv = 1.f / rsum32(e.x + e.y + e.z + e.w);
    regB[(4 * lane + 0) * 33 + i] = e.x * sinv;
    regB[(4 * lane + 1) * 33 + i] = e.y * sinv;
    regB[(4 * lane + 2) * 33 + i] = e.z * sinv;
    regB[(4 * lane + 3) * 33 + i] = e.w * sinv;
  }
  if (grp < 4) {  // smPi^T
    const float e = __expf(Pi[lane * 4 + grp]);
    sPt[grp * 33 + lane] = e / rsum32(e);
  }
  if (t < 84) {  // subtree labels only
    int g, d;
    if (t < 4) { g = 341 + 4 * s + t; d = 341 + t; }
    else if (t < 20) { g = 1365 + 16 * s + (t - 4); d = 345 + (t - 4); }
    else { g = 5461 + 64 * s + (t - 20); d = 361 + (t - 20); }
    labs[d] = labels[g];
  }
  if (t == 84) labs[85 + (s & 255)] = labels[85 + s];  // own L4 label
  __syncthreads();
  float Wr[128];  // up orientation
#pragma unroll
  for (int j = 0; j < 32; ++j) {
    const float4 v = *(const float4*)(scr + lane * 132 + j * 4);
    Wr[4 * j] = v.x; Wr[4 * j + 1] = v.y; Wr[4 * j + 2] = v.z; Wr[4 * j + 3] = v.w;
  }
  __syncthreads();

  // ---------- phase 2: subtree up sweep ----------
#pragma unroll
  for (int h = 0; h < 2; ++h) {  // S1: 64 leaves, batches of 4
    const int q0 = grp + 32 * h, q1 = q0 + 8, q2 = q0 + 16, q3 = q0 + 24;
    float v0 = sPt[(q0 & 3) * 33 + lane] * regB[labs[361 + q0] * 33 + lane];
    float v1 = sPt[(q1 & 3) * 33 + lane] * regB[labs[361 + q1] * 33 + lane];
    float v2 = sPt[(q2 & 3) * 33 + lane] * regB[labs[361 + q2] * 33 + lane];
    float v3 = sPt[(q3 & 3) * 33 + lane] * regB[labs[361 + q3] * 33 + lane];
    float s0 = v0, s1 = v1, s2 = v2, s3 = v3;
    rsum32x4(s0, s1, s2, s3);
    scr[(q0 >> 2) * 128 + lane * 4 + (q0 & 3)] = v0 / s0;
    scr[(q1 >> 2) * 128 + lane * 4 + (q1 & 3)] = v1 / s1;
    scr[(q2 >> 2) * 128 + lane * 4 + (q2 & 3)] = v2 / s2;
    scr[(q3 >> 2) * 128 + lane * 4 + (q3 & 3)] = v3 / s3;
  }
  __syncthreads();
  {  // S2: 16 L6 parents, paired
    const int p0 = grp, p1 = grp + 8;
    float tb0, tb1;
    dot128x2(Wr, scr + p0 * 128, scr + p1 * 128, tb0, tb1);
    float bl0 = tb0 * regB[labs[345 + p0] * 33 + lane];
    float bl1 = tb1 * regB[labs[345 + p1] * 33 + lane];
    float s0 = bl0, s1 = bl1;
    rsum32x2(s0, s1);
    bl0 /= s0; bl1 /= s1;
    scr[2048 + (p0 >> 2) * 128 + lane * 4 + (p0 & 3)] = bl0;  // X6
    scr[2048 + (p1 >> 2) * 128 + lane * 4 + (p1 & 3)] = bl1;
  }
  __syncthreads();
  if (grp < 4) {  // S3: 4 L5 parents
    const float tb = dot128(Wr, scr + 2048 + grp * 128);
    float bl = tb * regB[labs[341 + grp] * 33 + lane];
    bl /= rsum32(bl);
    scr[2560 + lane * 4 + grp] = bl;  // X5
  }
  __syncthreads();
  if (grp == 0) {  // S4: own level-4 root; publish b4
    const float tb = dot128(Wr, scr + 2560);
    float bl = tb * regB[labs[85 + (s & 255)] * 33 + lane];
    bl /= rsum32(bl);
    ws[OFF_B4 + s * 32 + lane] = bl;
  }
}

// ==================== k_down: everything after the barrier =================
__global__ __launch_bounds__(256, 1) void k_down(const int* __restrict__ labels,
                                                 const float* __restrict__ A,
                                                 const float* __restrict__ B,
                                                 const float* __restrict__ Pi,
                                                 const float* __restrict__ SP,
                                                 float* __restrict__ ws,
                                                 float* __restrict__ out) {
  __shared__ __align__(16) float scr[4224];
  __shared__ __align__(16) float regB[4224];
  __shared__ __align__(16) float sPt[132];
  __shared__ __align__(16) float tbrT[2720];
  __shared__ __align__(16) float tbS[672];
  __shared__ __align__(16) float ownb[32];
  __shared__ __align__(16) float r_buf[512];
  __shared__ int labs[425];
  __shared__ int fin;
  const int t = threadIdx.x, lane = t & 31, grp = t >> 5;  // 8 groups
  const int s = blockIdx.x;
  int* wsi = (int*)ws;
  double* partd = (double*)(ws + OFF_PART);
  const float4* A4 = (const float4*)A;
  const float4* B4 = (const float4*)B;

  // ---------- phase 1: softmax tables ----------
  const float sv0 = SP[0], sv1 = SP[1], sv2 = SP[2], sv3 = SP[3];
  const float sp0 = __expf(sv0), sp1 = __expf(sv1), sp2 = __expf(sv2), sp3 = __expf(sv3);
  const float spsum = sp0 + sp1 + sp2 + sp3;
  const float spinv = 1.f / spsum;
  const float lss = __logf(spsum);
  float4 c4 = make_float4(0.f, 0.f, 0.f, 0.f);
  for (int i = 0; i < 32; ++i) {
    const float4 e = exp4f(A4[i * 32 + lane]);
    c4.x += e.x; c4.y += e.y; c4.z += e.z; c4.w += e.w;
  }
  const float4 inv4 = make_float4(sp0 * spinv / c4.x, sp1 * spinv / c4.y,
                                  sp2 * spinv / c4.z, sp3 * spinv / c4.w);
  const float4 sub4 = make_float4(__logf(c4.x) - (sv0 - lss), __logf(c4.y) - (sv1 - lss),
                                  __logf(c4.z) - (sv2 - lss), __logf(c4.w) - (sv3 - lss));
#pragma unroll
  for (int k = 0; k < 4; ++k) {  // asp (up layout, stride 132)
    const int i = grp * 4 + k;
    const float4 e = exp4f(A4[i * 32 + lane]);
    *(float4*)(scr + i * 132 + 4 * lane) =
        make_float4(e.x * inv4.x, e.y * inv4.y, e.z * inv4.z, e.w * inv4.w);
  }
#pragma unroll
  for (int rI = 0; rI < 4; ++rI) {  // smB^T
    const int i = grp + rI * 8;
    const float4 e = exp4f(B4[i * 32 + lane]);
    const float sinv = 1.f / rsum32(e.x + e.y + e.z + e.w);
    regB[(4 * lane + 0) * 33 + i] = e.x * sinv;
    regB[(4 * lane + 1) * 33 + i] = e.y * sinv;
    regB[(4 * lane + 2) * 33 + i] = e.z * sinv;
    regB[(4 * lane + 3) * 33 + i] = e.w * sinv;
  }
  if (grp < 4) {  // smPi^T
    const float e = __expf(Pi[lane * 4 + grp]);
    sPt[grp * 33 + lane] = e / rsum32(e);
  }
  for (int idx = t; idx < 341; idx += 256) labs[idx] = labels[idx];
  if (t < 84) {
    int g, d;
    if (t < 4) { g = 341 + 4 * s + t; d = 341 + t; }
    else if (t < 20) { g = 1365 + 16 * s + (t - 4); d = 345 + (t - 4); }
    else { g = 5461 + 64 * s + (t - 20); d = 361 + (t - 20); }
    labs[d] = labels[g];
  }
  __syncthreads();
  float Wr[128];  // up orientation
#pragma unroll
  for (int j = 0; j < 32; ++j) {
    const float4 v = *(const float4*)(scr + lane * 132 + j * 4);
    Wr[4 * j] = v.x; Wr[4 * j + 1] = v.y; Wr[4 * j + 2] = v.z; Wr[4 * j + 3] = v.w;
  }
  __syncthreads();

  // ---------- phase 2 (recompute): subtree up sweep, NO b4 write ----------
#pragma unroll
  for (int h = 0; h < 2; ++h) {  // S1: 64 leaves, batches of 4
    const int q0 = grp + 32 * h, q1 = q0 + 8, q2 = q0 + 16, q3 = q0 + 24;
    float v0 = sPt[(q0 & 3) * 33 + lane] * regB[labs[361 + q0] * 33 + lane];
    float v1 = sPt[(q1 & 3) * 33 + lane] * regB[labs[361 + q1] * 33 + lane];
    float v2 = sPt[(q2 & 3) * 33 + lane] * regB[labs[361 + q2] * 33 + lane];
    float v3 = sPt[(q3 & 3) * 33 + lane] * regB[labs[361 + q3] * 33 + lane];
    float s0 = v0, s1 = v1, s2 = v2, s3 = v3;
    rsum32x4(s0, s1, s2, s3);
    scr[(q0 >> 2) * 128 + lane * 4 + (q0 & 3)] = v0 / s0;
    scr[(q1 >> 2) * 128 + lane * 4 + (q1 & 3)] = v1 / s1;
    scr[(q2 >> 2) * 128 + lane * 4 + (q2 & 3)] = v2 / s2;
    scr[(q3 >> 2) * 128 + lane * 4 + (q3 & 3)] = v3 / s3;
  }
  __syncthreads();
  {  // S2: 16 L6 parents, paired
    const int p0 = grp, p1 = grp + 8;
    float tb0, tb1;
    dot128x2(Wr, scr + p0 * 128, scr + p1 * 128, tb0, tb1);
    float bl0 = tb0 * regB[labs[345 + p0] * 33 + lane];
    float bl1 = tb1 * regB[labs[345 + p1] * 33 + lane];
    float s0 = bl0, s1 = bl1;
    rsum32x2(s0, s1);
    bl0 /= s0; bl1 /= s1;
    tbS[(5 + p0) * 32 + lane] = tb0;
    tbS[(5 + p1) * 32 + lane] = tb1;
    scr[2048 + (p0 >> 2) * 128 + lane * 4 + (p0 & 3)] = bl0;  // X6
    scr[2048 + (p1 >> 2) * 128 + lane * 4 + (p1 & 3)] = bl1;
  }
  __syncthreads();
  if (grp < 4) {  // S3: 4 L5 parents
    const float tb = dot128(Wr, scr + 2048 + grp * 128);
    float bl = tb * regB[labs[341 + grp] * 33 + lane];
    bl /= rsum32(bl);
    tbS[(1 + grp) * 32 + lane] = tb;
    scr[2560 + lane * 4 + grp] = bl;  // X5
  }
  __syncthreads();
  if (grp == 0) {  // S4: own level-4 root (local only; b4 already in ws)
    const float tb = dot128(Wr, scr + 2560);
    float bl = tb * regB[labs[85 + s] * 33 + lane];
    bl /= rsum32(bl);
    tbS[lane] = tb;
    ownb[lane] = bl;
  }
  __syncthreads();

  // ---------- phase 3: top up sweep (redundant per block), paired ----------
#pragma unroll
  for (int k = 0; k < 4; ++k) {  // 64 L3 parents: 4 paired rounds
    const int p0 = grp + 16 * k, p1 = p0 + 8;
    float* st0 = scr + grp * 128;
    float* st1 = scr + 1024 + grp * 128;
#pragma unroll
    for (int l = 0; l < 4; ++l) {
      st0[lane * 4 + l] = ws[OFF_B4 + (p0 * 4 + l) * 32 + lane];
      st1[lane * 4 + l] = ws[OFF_B4 + (p1 * 4 + l) * 32 + lane];
    }
    float tb0, tb1;
    dot128x2(Wr, st0, st1, tb0, tb1);
    float bl0 = tb0 * regB[labs[21 + p0] * 33 + lane];
    float bl1 = tb1 * regB[labs[21 + p1] * 33 + lane];
    float s0 = bl0, s1 = bl1;
    rsum32x2(s0, s1);
    bl0 /= s0; bl1 /= s1;
    tbrT[(21 + p0) * 32 + lane] = tb0;
    tbrT[(21 + p1) * 32 + lane] = tb1;
    scr[2048 + (p0 >> 2) * 128 + lane * 4 + (p0 & 3)] = bl0;  // bX3
    scr[2048 + (p1 >> 2) * 128 + lane * 4 + (p1 & 3)] = bl1;
  }
  __syncthreads();
  {  // 16 L2 parents, paired
    const int p0 = grp, p1 = grp + 8;
    float tb0, tb1;
    dot128x2(Wr, scr + 2048 + p0 * 128, scr + 2048 + p1 * 128, tb0, tb1);
    float bl0 = tb0 * regB[labs[5 + p0] * 33 + lane];
    float bl1 = tb1 * regB[labs[5 + p1] * 33 + lane];
    float s0 = bl0, s1 = bl1;
    rsum32x2(s0, s1);
    bl0 /= s0; bl1 /= s1;
    tbrT[(5 + p0) * 32 + lane] = tb0;
    tbrT[(5 + p1) * 32 + lane] = tb1;
    scr[1024 + (p0 >> 2) * 128 + lane * 4 + (p0 & 3)] = bl0;  // bX2
    scr[1024 + (p1 >> 2) * 128 + lane * 4 + (p1 & 3)] = bl1;
  }
  __syncthreads();
  if (grp < 4) {  // 4 L1 parents
    const float tb = dot128(Wr, scr + 1024 + grp * 128);
    float bl = tb * regB[labs[1 + grp] * 33 + lane];
    bl /= rsum32(bl);
    tbrT[(1 + grp) * 32 + lane] = tb;
    scr[1536 + lane * 4 + grp] = bl;  // bX1
  }
  __syncthreads();
  if (grp == 0) tbrT[lane] = dot128(Wr, scr + 1536);  // root tb
  __syncthreads();

  // ---------- phase 4: transition to down tables ----------
  for (int idx = t; idx < 4224; idx += 256) regB[idx] = __logf(regB[idx]);
  if (t < 132) sPt[t] = __logf(sPt[t]);
#pragma unroll
  for (int i = 0; i < 32; ++i) {  // Wr -> down orient (lane=j); scr -> ALG
    const float4 av = A4[i * 32 + lane];
    const float4 e = exp4f(av);
    const float4 asp = make_float4(e.x * inv4.x, e.y * inv4.y, e.z * inv4.z, e.w * inv4.w);
    Wr[i * 4 + 0] = asp.x; Wr[i * 4 + 1] = asp.y;
    Wr[i * 4 + 2] = asp.z; Wr[i * 4 + 3] = asp.w;
    if (grp == (i >> 2))
      *(float4*)(scr + i * 128 + lane * 4) =
          make_float4(asp.x * (av.x - sub4.x), asp.y * (av.y - sub4.y),
                      asp.z * (av.z - sub4.z), asp.w * (av.w - sub4.w));
  }
  __syncthreads();

  // ---------- phase 5: top down, DISTRIBUTED owners (R13) ----------
  double ll = 0.0;
  float eps4own = 0.f;  // valid in grp 0
  if (grp < 4) {
    const int n1 = 1 + (s >> 6), n2 = 5 + (s >> 4), n3 = 21 + (s >> 2);
    const int a0 = s >> 6, a1 = (s >> 4) & 3, a2 = (s >> 2) & 3, a3 = s & 3;
    float w[4], uv[4];
    float* rb = r_buf + grp * 32;

    // ---- step 0: root (owner: block 0, grp 0) ----
    float tbv = tbrT[lane];
    float bcv = tbv * __expf(regB[labs[0] * 33 + lane]);
    bcv /= rsum32(bcv);
    rb[lane] = bcv / tbv;
    if (grp == 0 && s == 0) {
      ll += (double)(bcv * regB[labs[0] * 33 + lane]);  // root eps*logB
      wu128(Wr, scr, rb, lane, w, uv);
      const float lb0 = regB[labs[1] * 33 + lane], lb1 = regB[labs[2] * 33 + lane];
      const float lb2 = regB[labs[3] * 33 + lane], lb3 = regB[labs[4] * 33 + lane];
      float b0 = tbrT[1 * 32 + lane] * __expf(lb0);
      float b1 = tbrT[2 * 32 + lane] * __expf(lb1);
      float b2 = tbrT[3 * 32 + lane] * __expf(lb2);
      float b3 = tbrT[4 * 32 + lane] * __expf(lb3);
      float s0 = b0, s1 = b1, s2 = b2, s3 = b3;
      rsum32x4(s0, s1, s2, s3);
      b0 /= s0; b1 /= s1; b2 /= s2; b3 /= s3;
      ll += (double)(b0 * uv[0]) + (double)(b0 * w[0] * lb0);
      ll += (double)(b1 * uv[1]) + (double)(b1 * w[1] * lb1);
      ll += (double)(b2 * uv[2]) + (double)(b2 * w[2] * lb2);
      ll += (double)(b3 * uv[3]) + (double)(b3 * w[3] * lb3);
    } else {
      wonly128(Wr, rb, w);
    }

    // ---- step 1: node n1 (owner: s&63==0, grp 1) ----
    tbv = tbrT[n1 * 32 + lane];
    bcv = tbv * __expf(regB[labs[n1] * 33 + lane]);
    bcv /= rsum32(bcv);
    rb[lane] = (bcv * w[a0]) / tbv;
    if (grp == 1 && (s & 63) == 0) {
      wu128(Wr, scr, rb, lane, w, uv);
      const int cb = 5 + 4 * (s >> 6);
      const float lb0 = regB[labs[cb + 0] * 33 + lane], lb1 = regB[labs[cb + 1] * 33 + lane];
      const float lb2 = regB[labs[cb + 2] * 33 + lane], lb3 = regB[labs[cb + 3] * 33 + lane];
      float b0 = tbrT[(cb + 0) * 32 + lane] * __expf(lb0);
      float b1 = tbrT[(cb + 1) * 32 + lane] * __expf(lb1);
      float b2 = tbrT[(cb + 2) * 32 + lane] * __expf(lb2);
      float b3 = tbrT[(cb + 3) * 32 + lane] * __expf(lb3);
      float s0 = b0, s1 = b1, s2 = b2, s3 = b3;
      rsum32x4(s0, s1, s2, s3);
      b0 /= s0; b1 /= s1; b2 /= s2; b3 /= s3;
      ll += (double)(b0 * uv[0]) + (double)(b0 * w[0] * lb0);
      ll += (double)(b1 * uv[1]) + (double)(b1 * w[1] * lb1);
      ll += (double)(b2 * uv[2]) + (double)(b2 * w[2] * lb2);
      ll += (double)(b3 * uv[3]) + (double)(b3 * w[3] * lb3);
    } else {
      wonly128(Wr, rb, w);
    }

    // ---- step 2: node n2 (owner: s&15==0, grp 2) ----
    tbv = tbrT[n2 * 32 + lane];
    bcv = tbv * __expf(regB[labs[n2] * 33 + lane]);
    bcv /= rsum32(bcv);
    rb[lane] = (bcv * w[a1]) / tbv;
    if (grp == 2 && (s & 15) == 0) {
      wu128(Wr, scr, rb, lane, w, uv);
      const int cb = 21 + 4 * (s >> 4);
      const float lb0 = regB[labs[cb + 0] * 33 + lane], lb1 = regB[labs[cb + 1] * 33 + lane];
      const float lb2 = regB[labs[cb + 2] * 33 + lane], lb3 = regB[labs[cb + 3] * 33 + lane];
      float b0 = tbrT[(cb + 0) * 32 + lane] * __expf(lb0);
      float b1 = tbrT[(cb + 1) * 32 + lane] * __expf(lb1);
      float b2 = tbrT[(cb + 2) * 32 + lane] * __expf(lb2);
      float b3 = tbrT[(cb + 3) * 32 + lane] * __expf(lb3);
      float s0 = b0, s1 = b1, s2 = b2, s3 = b3;
      rsum32x4(s0, s1, s2, s3);
      b0 /= s0; b1 /= s1; b2 /= s2; b3 /= s3;
      ll += (double)(b0 * uv[0]) + (double)(b0 * w[0] * lb0);
      ll += (double)(b1 * uv[1]) + (double)(b1 * w[1] * lb1);
      ll += (double)(b2 * uv[2]) + (double)(b2 * w[2] * lb2);
      ll += (double)(b3 * uv[3]) + (double)(b3 * w[3] * lb3);
    } else {
      wonly128(Wr, rb, w);
    }

    // ---- step 3: node n3 (owner: s&3==0, grp 3); children are L4 (b4) ----
    tbv = tbrT[n3 * 32 + lane];
    bcv = tbv * __expf(regB[labs[n3] * 33 + lane]);
    bcv /= rsum32(bcv);
    rb[lane] = (bcv * w[a2]) / tbv;
    if (grp == 3 && (s & 3) == 0) {
      wu128(Wr, scr, rb, lane, w, uv);
      const int cb = s & ~3;  // 4*(s>>2)
#pragma unroll
      for (int l = 0; l < 4; ++l) {
        const int ci = cb + l;
        const float bc = ws[OFF_B4 + ci * 32 + lane];
        const float e = bc * w[l];
        ll += (double)(bc * uv[l]) + (double)(e * regB[labs[85 + ci] * 33 + lane]);
      }
    } else {
      wonly128(Wr, rb, w);
    }
    eps4own = ownb[lane] * w[a3];
  }
  __syncthreads();

  // ---------- phase 6: subtree down sweep ----------
  if (grp == 0) {  // d0: own L4 node -> L5 children
    r_buf[lane] = eps4own / tbS[lane];
    float w[4], u[4];
    wu128(Wr, scr, r_buf, lane, w, u);
#pragma unroll
    for (int l = 0; l < 4; ++l) {
      const int lab = labs[341 + l];
      const float tbv = tbS[(1 + l) * 32 + lane];
      float bcv = tbv * __expf(regB[lab * 33 + lane]);
      bcv /= rsum32(bcv);
      const float e = bcv * w[l];
      ll += (double)(bcv * u[l]) + (double)(e * regB[lab * 33 + lane]);
      tbS[(1 + l) * 32 + lane] = e / tbv;
    }
  }
  __syncthreads();
  if (grp < 4) {  // d1: 4 L5 parents -> L6 children
    const int p = grp;
    r_buf[p * 32 + lane] = tbS[(1 + p) * 32 + lane];
    float w[4], u[4];
    wu128(Wr, scr, r_buf + p * 32, lane, w, u);
#pragma unroll
    for (int l = 0; l < 4; ++l) {
      const int q = p * 4 + l;
      const int lab = labs[345 + q];
      const float tbv = tbS[(5 + q) * 32 + lane];
      float bcv = tbv * __expf(regB[lab * 33 + lane]);
      bcv /= rsum32(bcv);
      const float e = bcv * w[l];
      ll += (double)(bcv * u[l]) + (double)(e * regB[lab * 33 + lane]);
      tbS[(5 + q) * 32 + lane] = e / tbv;
    }
  }
  __syncthreads();
  {  // d2: 16 L6 parents -> leaves, paired
    const int p0 = grp, p1 = grp + 8;
    float* rb0 = r_buf + grp * 32;
    float* rb1 = r_buf + 256 + grp * 32;
    rb0[lane] = tbS[(5 + p0) * 32 + lane];
    rb1[lane] = tbS[(5 + p1) * 32 + lane];
    float w0[4], u0[4], w1[4], u1[4];
    wu128x2(Wr, scr, rb0, rb1, lane, w0, u0, w1, u1);
#pragma unroll
    for (int l = 0; l < 4; ++l) {
      const int q0 = p0 * 4 + l, q1 = p1 * 4 + l;
      const float lb0 = regB[labs[361 + q0] * 33 + lane];
      const float lb1 = regB[labs[361 + q1] * 33 + lane];
      const float lp = sPt[l * 33 + lane];
      float b0 = __expf(lp + lb0);
      float b1 = __expf(lp + lb1);
      float s0 = b0, s1 = b1;
      rsum32x2(s0, s1);
      b0 /= s0; b1 /= s1;
      const float e0 = b0 * w0[l], e1 = b1 * w1[l];
      ll += (double)(b0 * u0[l]) + (double)(e0 * lb0) + (double)(e0 * lp);
      ll += (double)(b1 * u1[l]) + (double)(e1 * lb1) + (double)(e1 * lp);
    }
  }

  // ---------- phase 7: partials + tree finalize (poll-free atomics) ----------
#pragma unroll
  for (int k = 32; k >= 1; k >>= 1) ll += __shfl_xor(ll, k);
  double* rbd = (double*)r_buf;
  __syncthreads();
  if ((t & 63) == 0) rbd[t >> 6] = ll;
  __syncthreads();
  if (t == 0) {
    partd[s] = (rbd[0] + rbd[1]) + (rbd[2] + rbd[3]);
    __threadfence();
    int f = 0;
    if (atomicAdd(&wsi[IC2 + 32 * (s >> 4)], 1) == 15)
      if (atomicAdd(&wsi[IROOT2], 1) == 15) f = 1;
    fin = f;
  }
  __syncthreads();
  if (fin) {  // last block: all partials visible (first-touch reads)
    __threadfence();
    if (t < 64) {
      double v = 0.0;
      for (int k = t; k < 256; k += 64) v += partd[k];
#pragma unroll
      for (int k = 32; k >= 1; k >>= 1) v += __shfl_xor(v, k);
      if (t == 0) out[0] = (float)v;
    }
  }
}

extern "C" void kernel_launch(void* const* d_in, const int* in_sizes, int n_in,
                              void* d_out, int out_size, void* d_ws, size_t ws_size,
                              hipStream_t stream) {
  (void)in_sizes; (void)n_in; (void)out_size; (void)ws_size;
  const int* labels = (const int*)d_in[0];
  const float* A = (const float*)d_in[1];
  const float* B = (const float*)d_in[2];
  const float* Pi = (const float*)d_in[3];
  const float* SP = (const float*)d_in[4];
  float* ws = (float*)d_ws;
  float* out = (float*)d_out;

  // zero the finalize counter region
  hipMemsetAsync((char*)d_ws + IC1 * 4, 0, (IROOT2 + 1 - IC1) * 4, stream);
  hipLaunchKernelGGL(k_up, dim3(256), dim3(256), 0, stream,
                     labels, A, B, Pi, SP, ws);
  hipLaunchKernelGGL(k_down, dim3(256), dim3(256), 0, stream,
                     labels, A, B, Pi, SP, ws, out);
}

// Round 4
// 109.532 us; speedup vs baseline: 1.3060x; 1.0642x over previous
//
#include <hip/hip_runtime.h>

// HTMM: C=32 states, L=4 fanout, M=128 symbols, DEPTH=7.
// Level starts: {0,1,5,21,85,341,1365,5461,21845}.
// R16: k_down widened 256->512 threads (8->16 lane-groups, 2 waves/SIMD).
// Evidence: R15 k_down = 46.5us with VALUBusy 17% (~8us issue) and 1 wave/
// SIMD (grid 256 = 1 block/CU, 4 waves/block) => all latency exposed, no TLP.
// 512 threads halves the latency-bound phases (tables, staging, S1; L3 rounds
// 4->2; L2 parallelism 8->16) and doubles wave overlap everywhere else.
// scr grows to 6144 floats: P3 staging rows 0..31 (0..4095), bX3 out rows
// 0..15 at 4096..6143 (disjoint per round, no intra-loop barrier needed).
// Also: hipMemsetAsync dispatch removed; k_up zeroes the 17 finalize
// counters (identical-value stores from all blocks, benign; kernel boundary
// publishes before k_down's atomics read them).
// k_up stays 256 threads (limits blast radius; it is off the critical cost).

static constexpr int OFF_B4   = 0;      // level-4 betas [s*32+i] (8192 f)
static constexpr int OFF_PART = 8192;   // 256 doubles (512 f)
static constexpr int IC2      = 9760;   // 16 finalize counters, stride 32 ints
static constexpr int IROOT2   = 10272;  // finalize root counter

__device__ __forceinline__ float rsum32(float v) {
#pragma unroll
  for (int k = 1; k <= 16; k <<= 1) v += __shfl_xor(v, k);
  return v;
}
__device__ __forceinline__ void rsum32x2(float& a, float& b) {
#pragma unroll
  for (int k = 1; k <= 16; k <<= 1) { a += __shfl_xor(a, k); b += __shfl_xor(b, k); }
}
__device__ __forceinline__ void rsum32x4(float& a, float& b, float& c, float& d) {
#pragma unroll
  for (int k = 1; k <= 16; k <<= 1) {
    a += __shfl_xor(a, k); b += __shfl_xor(b, k);
    c += __shfl_xor(c, k); d += __shfl_xor(d, k);
  }
}
__device__ __forceinline__ float4 exp4f(float4 v) {
  return make_float4(__expf(v.x), __expf(v.y), __expf(v.z), __expf(v.w));
}

__device__ __forceinline__ float dot128(const float* Wr, const float* X) {
  float t0 = 0.f, t1 = 0.f, t2 = 0.f, t3 = 0.f;
#pragma unroll
  for (int j = 0; j < 32; ++j) {
    const float4 x = *(const float4*)(X + j * 4);
    t0 = fmaf(Wr[4 * j + 0], x.x, t0);
    t1 = fmaf(Wr[4 * j + 1], x.y, t1);
    t2 = fmaf(Wr[4 * j + 2], x.z, t2);
    t3 = fmaf(Wr[4 * j + 3], x.w, t3);
  }
  return (t0 + t1) + (t2 + t3);
}
// Two parents, shared Wr: 8 independent FMA chains, 2 LDS streams.
__device__ __forceinline__ void dot128x2(const float* Wr, const float* X0,
                                         const float* X1, float& o0, float& o1) {
  float a0 = 0.f, a1 = 0.f, a2 = 0.f, a3 = 0.f;
  float b0 = 0.f, b1 = 0.f, b2 = 0.f, b3 = 0.f;
#pragma unroll
  for (int j = 0; j < 32; ++j) {
    const float4 x = *(const float4*)(X0 + j * 4);
    const float4 y = *(const float4*)(X1 + j * 4);
    a0 = fmaf(Wr[4 * j + 0], x.x, a0); b0 = fmaf(Wr[4 * j + 0], y.x, b0);
    a1 = fmaf(Wr[4 * j + 1], x.y, a1); b1 = fmaf(Wr[4 * j + 1], y.y, b1);
    a2 = fmaf(Wr[4 * j + 2], x.z, a2); b2 = fmaf(Wr[4 * j + 2], y.z, b2);
    a3 = fmaf(Wr[4 * j + 3], x.w, a3); b3 = fmaf(Wr[4 * j + 3], y.w, b3);
  }
  o0 = (a0 + a1) + (a2 + a3);
  o1 = (b0 + b1) + (b2 + b3);
}

__device__ __forceinline__ void wu128(const float* Wr, const float* ALG,
                                      const float* rb, int lane,
                                      float w[4], float u[4]) {
  w[0] = w[1] = w[2] = w[3] = 0.f;
  u[0] = u[1] = u[2] = u[3] = 0.f;
#pragma unroll
  for (int ii = 0; ii < 32; ii += 4) {
    const float4 rv = *(const float4*)(rb + ii);
#pragma unroll
    for (int di = 0; di < 4; ++di) {
      const int i = ii + di;
      const float rr = (di == 0) ? rv.x : (di == 1) ? rv.y : (di == 2) ? rv.z : rv.w;
      const float4 av = *(const float4*)(ALG + i * 128 + lane * 4);
      w[0] = fmaf(Wr[i * 4 + 0], rr, w[0]); u[0] = fmaf(av.x, rr, u[0]);
      w[1] = fmaf(Wr[i * 4 + 1], rr, w[1]); u[1] = fmaf(av.y, rr, u[1]);
      w[2] = fmaf(Wr[i * 4 + 2], rr, w[2]); u[2] = fmaf(av.z, rr, u[2]);
      w[3] = fmaf(Wr[i * 4 + 3], rr, w[3]); u[3] = fmaf(av.w, rr, u[3]);
    }
  }
}
// Two parents share the SAME ALG ds_read_b128 stream (2x FLOP per LDS read).
__device__ __forceinline__ void wu128x2(const float* Wr, const float* ALG,
                                        const float* rb0, const float* rb1, int lane,
                                        float w0[4], float u0[4],
                                        float w1[4], float u1[4]) {
#pragma unroll
  for (int l = 0; l < 4; ++l) { w0[l] = u0[l] = w1[l] = u1[l] = 0.f; }
#pragma unroll
  for (int ii = 0; ii < 32; ii += 4) {
    const float4 r0 = *(const float4*)(rb0 + ii);
    const float4 r1 = *(const float4*)(rb1 + ii);
#pragma unroll
    for (int di = 0; di < 4; ++di) {
      const int i = ii + di;
      const float q0 = (di == 0) ? r0.x : (di == 1) ? r0.y : (di == 2) ? r0.z : r0.w;
      const float q1 = (di == 0) ? r1.x : (di == 1) ? r1.y : (di == 2) ? r1.z : r1.w;
      const float4 av = *(const float4*)(ALG + i * 128 + lane * 4);
      w0[0] = fmaf(Wr[i * 4 + 0], q0, w0[0]); w1[0] = fmaf(Wr[i * 4 + 0], q1, w1[0]);
      u0[0] = fmaf(av.x, q0, u0[0]);          u1[0] = fmaf(av.x, q1, u1[0]);
      w0[1] = fmaf(Wr[i * 4 + 1], q0, w0[1]); w1[1] = fmaf(Wr[i * 4 + 1], q1, w1[1]);
      u0[1] = fmaf(av.y, q0, u0[1]);          u1[1] = fmaf(av.y, q1, u1[1]);
      w0[2] = fmaf(Wr[i * 4 + 2], q0, w0[2]); w1[2] = fmaf(Wr[i * 4 + 2], q1, w1[2]);
      u0[2] = fmaf(av.z, q0, u0[2]);          u1[2] = fmaf(av.z, q1, u1[2]);
      w0[3] = fmaf(Wr[i * 4 + 3], q0, w0[3]); w1[3] = fmaf(Wr[i * 4 + 3], q1, w1[3]);
      u0[3] = fmaf(av.w, q0, u0[3]);          u1[3] = fmaf(av.w, q1, u1[3]);
    }
  }
}
// Path walk: w only.
__device__ __forceinline__ void wonly128(const float* Wr, const float* rb,
                                         float w[4]) {
  w[0] = w[1] = w[2] = w[3] = 0.f;
#pragma unroll
  for (int ii = 0; ii < 32; ii += 4) {
    const float4 rv = *(const float4*)(rb + ii);
#pragma unroll
    for (int di = 0; di < 4; ++di) {
      const int i = ii + di;
      const float rr = (di == 0) ? rv.x : (di == 1) ? rv.y : (di == 2) ? rv.z : rv.w;
      w[0] = fmaf(Wr[i * 4 + 0], rr, w[0]);
      w[1] = fmaf(Wr[i * 4 + 1], rr, w[1]);
      w[2] = fmaf(Wr[i * 4 + 2], rr, w[2]);
      w[3] = fmaf(Wr[i * 4 + 3], rr, w[3]);
    }
  }
}

// ============================ k_up: phases 1-2 (256 thr) ====================
__global__ __launch_bounds__(256, 1) void k_up(const int* __restrict__ labels,
                                               const float* __restrict__ A,
                                               const float* __restrict__ B,
                                               const float* __restrict__ Pi,
                                               const float* __restrict__ SP,
                                               float* __restrict__ ws) {
  __shared__ __align__(16) float scr[4224];
  __shared__ __align__(16) float regB[4224];
  __shared__ __align__(16) float sPt[132];
  __shared__ int labs[425];
  const int t = threadIdx.x, lane = t & 31, grp = t >> 5;
  const int s = blockIdx.x;
  int* wsi = (int*)ws;
  const float4* A4 = (const float4*)A;
  const float4* B4 = (const float4*)B;

  // zero finalize counters (replaces host memset dispatch; benign same-value
  // stores from all blocks; kernel boundary publishes before k_down atomics)
  if (t < 16) wsi[IC2 + 32 * t] = 0;
  else if (t == 16) wsi[IROOT2] = 0;

  // ---------- phase 1: softmax tables (subset needed for up sweep) ----------
  const float sv0 = SP[0], sv1 = SP[1], sv2 = SP[2], sv3 = SP[3];
  const float sp0 = __expf(sv0), sp1 = __expf(sv1), sp2 = __expf(sv2), sp3 = __expf(sv3);
  const float spsum = sp0 + sp1 + sp2 + sp3;
  const float spinv = 1.f / spsum;
  float4 c4 = make_float4(0.f, 0.f, 0.f, 0.f);
  for (int i = 0; i < 32; ++i) {
    const float4 e = exp4f(A4[i * 32 + lane]);
    c4.x += e.x; c4.y += e.y; c4.z += e.z; c4.w += e.w;
  }
  const float4 inv4 = make_float4(sp0 * spinv / c4.x, sp1 * spinv / c4.y,
                                  sp2 * spinv / c4.z, sp3 * spinv / c4.w);
#pragma unroll
  for (int k = 0; k < 4; ++k) {  // asp (up layout, stride 132)
    const int i = grp * 4 + k;
    const float4 e = exp4f(A4[i * 32 + lane]);
    *(float4*)(scr + i * 132 + 4 * lane) =
        make_float4(e.x * inv4.x, e.y * inv4.y, e.z * inv4.z, e.w * inv4.w);
  }
#pragma unroll
  for (int rI = 0; rI < 4; ++rI) {  // smB^T
    const int i = grp + rI * 8;
    const float4 e = exp4f(B4[i * 32 + lane]);
    const float sinv = 1.f / rsum32(e.x + e.y + e.z + e.w);
    regB[(4 * lane + 0) * 33 + i] = e.x * sinv;
    regB[(4 * lane + 1) * 33 + i] = e.y * sinv;
    regB[(4 * lane + 2) * 33 + i] = e.z * sinv;
    regB[(4 * lane + 3) * 33 + i] = e.w * sinv;
  }
  if (grp < 4) {  // smPi^T
    const float e = __expf(Pi[lane * 4 + grp]);
    sPt[grp * 33 + lane] = e / rsum32(e);
  }
  if (t < 84) {  // subtree labels only
    int g, d;
    if (t < 4) { g = 341 + 4 * s + t; d = 341 + t; }
    else if (t < 20) { g = 1365 + 16 * s + (t - 4); d = 345 + (t - 4); }
    else { g = 5461 + 64 * s + (t - 20); d = 361 + (t - 20); }
    labs[d] = labels[g];
  }
  if (t == 84) labs[85 + (s & 255)] = labels[85 + s];  // own L4 label
  __syncthreads();
  float Wr[128];  // up orientation
#pragma unroll
  for (int j = 0; j < 32; ++j) {
    const float4 v = *(const float4*)(scr + lane * 132 + j * 4);
    Wr[4 * j] = v.x; Wr[4 * j + 1] = v.y; Wr[4 * j + 2] = v.z; Wr[4 * j + 3] = v.w;
  }
  __syncthreads();

  // ---------- phase 2: subtree up sweep ----------
#pragma unroll
  for (int h = 0; h < 2; ++h) {  // S1: 64 leaves, batches of 4
    const int q0 = grp + 32 * h, q1 = q0 + 8, q2 = q0 + 16, q3 = q0 + 24;
    float v0 = sPt[(q0 & 3) * 33 + lane] * regB[labs[361 + q0] * 33 + lane];
    float v1 = sPt[(q1 & 3) * 33 + lane] * regB[labs[361 + q1] * 33 + lane];
    float v2 = sPt[(q2 & 3) * 33 + lane] * regB[labs[361 + q2] * 33 + lane];
    float v3 = sPt[(q3 & 3) * 33 + lane] * regB[labs[361 + q3] * 33 + lane];
    float s0 = v0, s1 = v1, s2 = v2, s3 = v3;
    rsum32x4(s0, s1, s2, s3);
    scr[(q0 >> 2) * 128 + lane * 4 + (q0 & 3)] = v0 / s0;
    scr[(q1 >> 2) * 128 + lane * 4 + (q1 & 3)] = v1 / s1;
    scr[(q2 >> 2) * 128 + lane * 4 + (q2 & 3)] = v2 / s2;
    scr[(q3 >> 2) * 128 + lane * 4 + (q3 & 3)] = v3 / s3;
  }
  __syncthreads();
  {  // S2: 16 L6 parents, paired
    const int p0 = grp, p1 = grp + 8;
    float tb0, tb1;
    dot128x2(Wr, scr + p0 * 128, scr + p1 * 128, tb0, tb1);
    float bl0 = tb0 * regB[labs[345 + p0] * 33 + lane];
    float bl1 = tb1 * regB[labs[345 + p1] * 33 + lane];
    float s0 = bl0, s1 = bl1;
    rsum32x2(s0, s1);
    bl0 /= s0; bl1 /= s1;
    scr[2048 + (p0 >> 2) * 128 + lane * 4 + (p0 & 3)] = bl0;  // X6
    scr[2048 + (p1 >> 2) * 128 + lane * 4 + (p1 & 3)] = bl1;
  }
  __syncthreads();
  if (grp < 4) {  // S3: 4 L5 parents
    const float tb = dot128(Wr, scr + 2048 + grp * 128);
    float bl = tb * regB[labs[341 + grp] * 33 + lane];
    bl /= rsum32(bl);
    scr[2560 + lane * 4 + grp] = bl;  // X5
  }
  __syncthreads();
  if (grp == 0) {  // S4: own level-4 root; publish b4
    const float tb = dot128(Wr, scr + 2560);
    float bl = tb * regB[labs[85 + (s & 255)] * 33 + lane];
    bl /= rsum32(bl);
    ws[OFF_B4 + s * 32 + lane] = bl;
  }
}

// ==================== k_down: 512 threads, 16 lane-groups ==================
__global__ __launch_bounds__(512, 1) void k_down(const int* __restrict__ labels,
                                                 const float* __restrict__ A,
                                                 const float* __restrict__ B,
                                                 const float* __restrict__ Pi,
                                                 const float* __restrict__ SP,
                                                 float* __restrict__ ws,
                                                 float* __restrict__ out) {
  __shared__ __align__(16) float scr[6144];
  __shared__ __align__(16) float regB[4224];
  __shared__ __align__(16) float sPt[132];
  __shared__ __align__(16) float tbrT[2720];
  __shared__ __align__(16) float tbS[672];
  __shared__ __align__(16) float ownb[32];
  __shared__ __align__(16) float r_buf[512];
  __shared__ int labs[425];
  __shared__ int fin;
  const int t = threadIdx.x, lane = t & 31, grp = t >> 5;  // 16 groups
  const int s = blockIdx.x;
  int* wsi = (int*)ws;
  double* partd = (double*)(ws + OFF_PART);
  const float4* A4 = (const float4*)A;
  const float4* B4 = (const float4*)B;

  // ---------- phase 1: softmax tables ----------
  const float sv0 = SP[0], sv1 = SP[1], sv2 = SP[2], sv3 = SP[3];
  const float sp0 = __expf(sv0), sp1 = __expf(sv1), sp2 = __expf(sv2), sp3 = __expf(sv3);
  const float spsum = sp0 + sp1 + sp2 + sp3;
  const float spinv = 1.f / spsum;
  const float lss = __logf(spsum);
  float4 c4 = make_float4(0.f, 0.f, 0.f, 0.f);
  for (int i = 0; i < 32; ++i) {
    const float4 e = exp4f(A4[i * 32 + lane]);
    c4.x += e.x; c4.y += e.y; c4.z += e.z; c4.w += e.w;
  }
  const float4 inv4 = make_float4(sp0 * spinv / c4.x, sp1 * spinv / c4.y,
                                  sp2 * spinv / c4.z, sp3 * spinv / c4.w);
  const float4 sub4 = make_float4(__logf(c4.x) - (sv0 - lss), __logf(c4.y) - (sv1 - lss),
                                  __logf(c4.z) - (sv2 - lss), __logf(c4.w) - (sv3 - lss));
#pragma unroll
  for (int k = 0; k < 2; ++k) {  // asp (up layout, stride 132): 2 rows/group
    const int i = grp * 2 + k;
    const float4 e = exp4f(A4[i * 32 + lane]);
    *(float4*)(scr + i * 132 + 4 * lane) =
        make_float4(e.x * inv4.x, e.y * inv4.y, e.z * inv4.z, e.w * inv4.w);
  }
#pragma unroll
  for (int rI = 0; rI < 2; ++rI) {  // smB^T: 2 rows/group
    const int i = grp + rI * 16;
    const float4 e = exp4f(B4[i * 32 + lane]);
    const float sinv = 1.f / rsum32(e.x + e.y + e.z + e.w);
    regB[(4 * lane + 0) * 33 + i] = e.x * sinv;
    regB[(4 * lane + 1) * 33 + i] = e.y * sinv;
    regB[(4 * lane + 2) * 33 + i] = e.z * sinv;
    regB[(4 * lane + 3) * 33 + i] = e.w * sinv;
  }
  if (grp < 4) {  // smPi^T
    const float e = __expf(Pi[lane * 4 + grp]);
    sPt[grp * 33 + lane] = e / rsum32(e);
  }
  for (int idx = t; idx < 341; idx += 512) labs[idx] = labels[idx];
  if (t < 84) {
    int g, d;
    if (t < 4) { g = 341 + 4 * s + t; d = 341 + t; }
    else if (t < 20) { g = 1365 + 16 * s + (t - 4); d = 345 + (t - 4); }
    else { g = 5461 + 64 * s + (t - 20); d = 361 + (t - 20); }
    labs[d] = labels[g];
  }
  __syncthreads();
  float Wr[128];  // up orientation
#pragma unroll
  for (int j = 0; j < 32; ++j) {
    const float4 v = *(const float4*)(scr + lane * 132 + j * 4);
    Wr[4 * j] = v.x; Wr[4 * j + 1] = v.y; Wr[4 * j + 2] = v.z; Wr[4 * j + 3] = v.w;
  }
  __syncthreads();

  // ---------- phase 2 (recompute): subtree up sweep, NO b4 write ----------
  {  // S1: 64 leaves, 4 per group, single round
    const int q0 = grp, q1 = grp + 16, q2 = grp + 32, q3 = grp + 48;
    float v0 = sPt[(q0 & 3) * 33 + lane] * regB[labs[361 + q0] * 33 + lane];
    float v1 = sPt[(q1 & 3) * 33 + lane] * regB[labs[361 + q1] * 33 + lane];
    float v2 = sPt[(q2 & 3) * 33 + lane] * regB[labs[361 + q2] * 33 + lane];
    float v3 = sPt[(q3 & 3) * 33 + lane] * regB[labs[361 + q3] * 33 + lane];
    float s0 = v0, s1 = v1, s2 = v2, s3 = v3;
    rsum32x4(s0, s1, s2, s3);
    scr[(q0 >> 2) * 128 + lane * 4 + (q0 & 3)] = v0 / s0;
    scr[(q1 >> 2) * 128 + lane * 4 + (q1 & 3)] = v1 / s1;
    scr[(q2 >> 2) * 128 + lane * 4 + (q2 & 3)] = v2 / s2;
    scr[(q3 >> 2) * 128 + lane * 4 + (q3 & 3)] = v3 / s3;
  }
  __syncthreads();
  if (grp < 8) {  // S2: 16 L6 parents, paired (ALG-shared x2 keeps LDS low)
    const int p0 = grp, p1 = grp + 8;
    float tb0, tb1;
    dot128x2(Wr, scr + p0 * 128, scr + p1 * 128, tb0, tb1);
    float bl0 = tb0 * regB[labs[345 + p0] * 33 + lane];
    float bl1 = tb1 * regB[labs[345 + p1] * 33 + lane];
    float s0 = bl0, s1 = bl1;
    rsum32x2(s0, s1);
    bl0 /= s0; bl1 /= s1;
    tbS[(5 + p0) * 32 + lane] = tb0;
    tbS[(5 + p1) * 32 + lane] = tb1;
    scr[2048 + (p0 >> 2) * 128 + lane * 4 + (p0 & 3)] = bl0;  // X6
    scr[2048 + (p1 >> 2) * 128 + lane * 4 + (p1 & 3)] = bl1;
  }
  __syncthreads();
  if (grp < 4) {  // S3: 4 L5 parents
    const float tb = dot128(Wr, scr + 2048 + grp * 128);
    float bl = tb * regB[labs[341 + grp] * 33 + lane];
    bl /= rsum32(bl);
    tbS[(1 + grp) * 32 + lane] = tb;
    scr[2560 + lane * 4 + grp] = bl;  // X5
  }
  __syncthreads();
  if (grp == 0) {  // S4: own level-4 root (local only; b4 already in ws)
    const float tb = dot128(Wr, scr + 2560);
    float bl = tb * regB[labs[85 + s] * 33 + lane];
    bl /= rsum32(bl);
    tbS[lane] = tb;
    ownb[lane] = bl;
  }
  __syncthreads();

  // ---------- phase 3: top up sweep (redundant per block) ----------
  // L3: 64 parents, 16 groups x pair x 2 rounds. Staging rows 0..31
  // (scr 0..4095), bX3 out rows 0..15 at scr 4096..6143 — disjoint.
#pragma unroll
  for (int h = 0; h < 2; ++h) {
    const int p0 = grp + 32 * h, p1 = p0 + 16;
    float* st0 = scr + grp * 128;
    float* st1 = scr + 2048 + grp * 128;
#pragma unroll
    for (int l = 0; l < 4; ++l) {
      st0[lane * 4 + l] = ws[OFF_B4 + (p0 * 4 + l) * 32 + lane];
      st1[lane * 4 + l] = ws[OFF_B4 + (p1 * 4 + l) * 32 + lane];
    }
    float tb0, tb1;
    dot128x2(Wr, st0, st1, tb0, tb1);
    float bl0 = tb0 * regB[labs[21 + p0] * 33 + lane];
    float bl1 = tb1 * regB[labs[21 + p1] * 33 + lane];
    float s0 = bl0, s1 = bl1;
    rsum32x2(s0, s1);
    bl0 /= s0; bl1 /= s1;
    tbrT[(21 + p0) * 32 + lane] = tb0;
    tbrT[(21 + p1) * 32 + lane] = tb1;
    scr[4096 + (p0 >> 2) * 128 + lane * 4 + (p0 & 3)] = bl0;  // bX3
    scr[4096 + (p1 >> 2) * 128 + lane * 4 + (p1 & 3)] = bl1;
  }
  __syncthreads();
  {  // L2: 16 parents, one per group
    const int p = grp;
    const float tb = dot128(Wr, scr + 4096 + p * 128);
    float bl = tb * regB[labs[5 + p] * 33 + lane];
    bl /= rsum32(bl);
    tbrT[(5 + p) * 32 + lane] = tb;
    scr[(p >> 2) * 128 + lane * 4 + (p & 3)] = bl;  // bX2 rows 0..3
  }
  __syncthreads();
  if (grp < 4) {  // L1: 4 parents
    const float tb = dot128(Wr, scr + grp * 128);
    float bl = tb * regB[labs[1 + grp] * 33 + lane];
    bl /= rsum32(bl);
    tbrT[(1 + grp) * 32 + lane] = tb;
    scr[512 + lane * 4 + grp] = bl;  // bX1 (row 4)
  }
  __syncthreads();
  if (grp == 0) tbrT[lane] = dot128(Wr, scr + 512);  // root tb
  __syncthreads();

  // ---------- phase 4: transition to down tables ----------
  for (int idx = t; idx < 4224; idx += 512) regB[idx] = __logf(regB[idx]);
  if (t < 132) sPt[t] = __logf(sPt[t]);
#pragma unroll
  for (int i = 0; i < 32; ++i) {  // Wr -> down orient (lane=j); scr -> ALG
    const float4 av = A4[i * 32 + lane];
    const float4 e = exp4f(av);
    const float4 asp = make_float4(e.x * inv4.x, e.y * inv4.y, e.z * inv4.z, e.w * inv4.w);
    Wr[i * 4 + 0] = asp.x; Wr[i * 4 + 1] = asp.y;
    Wr[i * 4 + 2] = asp.z; Wr[i * 4 + 3] = asp.w;
    if (grp == (i >> 1))  // 2 rows per group
      *(float4*)(scr + i * 128 + lane * 4) =
          make_float4(asp.x * (av.x - sub4.x), asp.y * (av.y - sub4.y),
                      asp.z * (av.z - sub4.z), asp.w * (av.w - sub4.w));
  }
  __syncthreads();

  // ---------- phase 5: top down, DISTRIBUTED owners (R13) ----------
  double ll = 0.0;
  float eps4own = 0.f;  // valid in grp 0
  if (grp < 4) {
    const int n1 = 1 + (s >> 6), n2 = 5 + (s >> 4), n3 = 21 + (s >> 2);
    const int a0 = s >> 6, a1 = (s >> 4) & 3, a2 = (s >> 2) & 3, a3 = s & 3;
    float w[4], uv[4];
    float* rb = r_buf + grp * 32;

    // ---- step 0: root (owner: block 0, grp 0) ----
    float tbv = tbrT[lane];
    float bcv = tbv * __expf(regB[labs[0] * 33 + lane]);
    bcv /= rsum32(bcv);
    rb[lane] = bcv / tbv;
    if (grp == 0 && s == 0) {
      ll += (double)(bcv * regB[labs[0] * 33 + lane]);  // root eps*logB
      wu128(Wr, scr, rb, lane, w, uv);
      const float lb0 = regB[labs[1] * 33 + lane], lb1 = regB[labs[2] * 33 + lane];
      const float lb2 = regB[labs[3] * 33 + lane], lb3 = regB[labs[4] * 33 + lane];
      float b0 = tbrT[1 * 32 + lane] * __expf(lb0);
      float b1 = tbrT[2 * 32 + lane] * __expf(lb1);
      float b2 = tbrT[3 * 32 + lane] * __expf(lb2);
      float b3 = tbrT[4 * 32 + lane] * __expf(lb3);
      float s0 = b0, s1 = b1, s2 = b2, s3 = b3;
      rsum32x4(s0, s1, s2, s3);
      b0 /= s0; b1 /= s1; b2 /= s2; b3 /= s3;
      ll += (double)(b0 * uv[0]) + (double)(b0 * w[0] * lb0);
      ll += (double)(b1 * uv[1]) + (double)(b1 * w[1] * lb1);
      ll += (double)(b2 * uv[2]) + (double)(b2 * w[2] * lb2);
      ll += (double)(b3 * uv[3]) + (double)(b3 * w[3] * lb3);
    } else {
      wonly128(Wr, rb, w);
    }

    // ---- step 1: node n1 (owner: s&63==0, grp 1) ----
    tbv = tbrT[n1 * 32 + lane];
    bcv = tbv * __expf(regB[labs[n1] * 33 + lane]);
    bcv /= rsum32(bcv);
    rb[lane] = (bcv * w[a0]) / tbv;
    if (grp == 1 && (s & 63) == 0) {
      wu128(Wr, scr, rb, lane, w, uv);
      const int cb = 5 + 4 * (s >> 6);
      const float lb0 = regB[labs[cb + 0] * 33 + lane], lb1 = regB[labs[cb + 1] * 33 + lane];
      const float lb2 = regB[labs[cb + 2] * 33 + lane], lb3 = regB[labs[cb + 3] * 33 + lane];
      float b0 = tbrT[(cb + 0) * 32 + lane] * __expf(lb0);
      float b1 = tbrT[(cb + 1) * 32 + lane] * __expf(lb1);
      float b2 = tbrT[(cb + 2) * 32 + lane] * __expf(lb2);
      float b3 = tbrT[(cb + 3) * 32 + lane] * __expf(lb3);
      float s0 = b0, s1 = b1, s2 = b2, s3 = b3;
      rsum32x4(s0, s1, s2, s3);
      b0 /= s0; b1 /= s1; b2 /= s2; b3 /= s3;
      ll += (double)(b0 * uv[0]) + (double)(b0 * w[0] * lb0);
      ll += (double)(b1 * uv[1]) + (double)(b1 * w[1] * lb1);
      ll += (double)(b2 * uv[2]) + (double)(b2 * w[2] * lb2);
      ll += (double)(b3 * uv[3]) + (double)(b3 * w[3] * lb3);
    } else {
      wonly128(Wr, rb, w);
    }

    // ---- step 2: node n2 (owner: s&15==0, grp 2) ----
    tbv = tbrT[n2 * 32 + lane];
    bcv = tbv * __expf(regB[labs[n2] * 33 + lane]);
    bcv /= rsum32(bcv);
    rb[lane] = (bcv * w[a1]) / tbv;
    if (grp == 2 && (s & 15) == 0) {
      wu128(Wr, scr, rb, lane, w, uv);
      const int cb = 21 + 4 * (s >> 4);
      const float lb0 = regB[labs[cb + 0] * 33 + lane], lb1 = regB[labs[cb + 1] * 33 + lane];
      const float lb2 = regB[labs[cb + 2] * 33 + lane], lb3 = regB[labs[cb + 3] * 33 + lane];
      float b0 = tbrT[(cb + 0) * 32 + lane] * __expf(lb0);
      float b1 = tbrT[(cb + 1) * 32 + lane] * __expf(lb1);
      float b2 = tbrT[(cb + 2) * 32 + lane] * __expf(lb2);
      float b3 = tbrT[(cb + 3) * 32 + lane] * __expf(lb3);
      float s0 = b0, s1 = b1, s2 = b2, s3 = b3;
      rsum32x4(s0, s1, s2, s3);
      b0 /= s0; b1 /= s1; b2 /= s2; b3 /= s3;
      ll += (double)(b0 * uv[0]) + (double)(b0 * w[0] * lb0);
      ll += (double)(b1 * uv[1]) + (double)(b1 * w[1] * lb1);
      ll += (double)(b2 * uv[2]) + (double)(b2 * w[2] * lb2);
      ll += (double)(b3 * uv[3]) + (double)(b3 * w[3] * lb3);
    } else {
      wonly128(Wr, rb, w);
    }

    // ---- step 3: node n3 (owner: s&3==0, grp 3); children are L4 (b4) ----
    tbv = tbrT[n3 * 32 + lane];
    bcv = tbv * __expf(regB[labs[n3] * 33 + lane]);
    bcv /= rsum32(bcv);
    rb[lane] = (bcv * w[a2]) / tbv;
    if (grp == 3 && (s & 3) == 0) {
      wu128(Wr, scr, rb, lane, w, uv);
      const int cb = s & ~3;  // 4*(s>>2)
#pragma unroll
      for (int l = 0; l < 4; ++l) {
        const int ci = cb + l;
        const float bc = ws[OFF_B4 + ci * 32 + lane];
        const float e = bc * w[l];
        ll += (double)(bc * uv[l]) + (double)(e * regB[labs[85 + ci] * 33 + lane]);
      }
    } else {
      wonly128(Wr, rb, w);
    }
    eps4own = ownb[lane] * w[a3];
  }
  __syncthreads();

  // ---------- phase 6: subtree down sweep ----------
  if (grp == 0) {  // d0: own L4 node -> L5 children
    r_buf[lane] = eps4own / tbS[lane];
    float w[4], u[4];
    wu128(Wr, scr, r_buf, lane, w, u);
#pragma unroll
    for (int l = 0; l < 4; ++l) {
      const int lab = labs[341 + l];
      const float tbv = tbS[(1 + l) * 32 + lane];
      float bcv = tbv * __expf(regB[lab * 33 + lane]);
      bcv /= rsum32(bcv);
      const float e = bcv * w[l];
      ll += (double)(bcv * u[l]) + (double)(e * regB[lab * 33 + lane]);
      tbS[(1 + l) * 32 + lane] = e / tbv;
    }
  }
  __syncthreads();
  if (grp < 4) {  // d1: 4 L5 parents -> L6 children
    const int p = grp;
    r_buf[p * 32 + lane] = tbS[(1 + p) * 32 + lane];
    float w[4], u[4];
    wu128(Wr, scr, r_buf + p * 32, lane, w, u);
#pragma unroll
    for (int l = 0; l < 4; ++l) {
      const int q = p * 4 + l;
      const int lab = labs[345 + q];
      const float tbv = tbS[(5 + q) * 32 + lane];
      float bcv = tbv * __expf(regB[lab * 33 + lane]);
      bcv /= rsum32(bcv);
      const float e = bcv * w[l];
      ll += (double)(bcv * u[l]) + (double)(e * regB[lab * 33 + lane]);
      tbS[(5 + q) * 32 + lane] = e / tbv;
    }
  }
  __syncthreads();
  if (grp < 8) {  // d2: 16 L6 parents -> leaves, paired
    const int p0 = grp, p1 = grp + 8;
    float* rb0 = r_buf + grp * 32;
    float* rb1 = r_buf + 256 + grp * 32;
    rb0[lane] = tbS[(5 + p0) * 32 + lane];
    rb1[lane] = tbS[(5 + p1) * 32 + lane];
    float w0[4], u0[4], w1[4], u1[4];
    wu128x2(Wr, scr, rb0, rb1, lane, w0, u0, w1, u1);
#pragma unroll
    for (int l = 0; l < 4; ++l) {
      const int q0 = p0 * 4 + l, q1 = p1 * 4 + l;
      const float lb0 = regB[labs[361 + q0] * 33 + lane];
      const float lb1 = regB[labs[361 + q1] * 33 + lane];
      const float lp = sPt[l * 33 + lane];
      float b0 = __expf(lp + lb0);
      float b1 = __expf(lp + lb1);
      float s0 = b0, s1 = b1;
      rsum32x2(s0, s1);
      b0 /= s0; b1 /= s1;
      const float e0 = b0 * w0[l], e1 = b1 * w1[l];
      ll += (double)(b0 * u0[l]) + (double)(e0 * lb0) + (double)(e0 * lp);
      ll += (double)(b1 * u1[l]) + (double)(e1 * lb1) + (double)(e1 * lp);
    }
  }

  // ---------- phase 7: partials + tree finalize (poll-free atomics) ----------
#pragma unroll
  for (int k = 32; k >= 1; k >>= 1) ll += __shfl_xor(ll, k);
  double* rbd = (double*)r_buf;
  __syncthreads();
  if ((t & 63) == 0) rbd[t >> 6] = ll;  // 8 waves
  __syncthreads();
  if (t == 0) {
    partd[s] = ((rbd[0] + rbd[1]) + (rbd[2] + rbd[3])) +
               ((rbd[4] + rbd[5]) + (rbd[6] + rbd[7]));
    __threadfence();
    int f = 0;
    if (atomicAdd(&wsi[IC2 + 32 * (s >> 4)], 1) == 15)
      if (atomicAdd(&wsi[IROOT2], 1) == 15) f = 1;
    fin = f;
  }
  __syncthreads();
  if (fin) {  // last block: all partials visible (first-touch reads)
    __threadfence();
    if (t < 64) {
      double v = 0.0;
      for (int k = t; k < 256; k += 64) v += partd[k];
#pragma unroll
      for (int k = 32; k >= 1; k >>= 1) v += __shfl_xor(v, k);
      if (t == 0) out[0] = (float)v;
    }
  }
}

extern "C" void kernel_launch(void* const* d_in, const int* in_sizes, int n_in,
                              void* d_out, int out_size, void* d_ws, size_t ws_size,
                              hipStream_t stream) {
  (void)in_sizes; (void)n_in; (void)out_size; (void)ws_size;
  const int* labels = (const int*)d_in[0];
  const float* A = (const float*)d_in[1];
  const float* B = (const float*)d_in[2];
  const float* Pi = (const float*)d_in[3];
  const float* SP = (const float*)d_in[4];
  float* ws = (float*)d_ws;
  float* out = (float*)d_out;

  // no memset dispatch: k_up zeroes the finalize counters
  hipLaunchKernelGGL(k_up, dim3(256), dim3(256), 0, stream,
                     labels, A, B, Pi, SP, ws);
  hipLaunchKernelGGL(k_down, dim3(256), dim3(512), 0, stream,
                     labels, A, B, Pi, SP, ws, out);
}

// Round 5
// 107.433 us; speedup vs baseline: 1.3315x; 1.0195x over previous
//
#include <hip/hip_runtime.h>

// HTMM: C=32 states, L=4 fanout, M=128 symbols, DEPTH=7.
// Level starts: {0,1,5,21,85,341,1365,5461,21845}.
// R17 = R16 with ONE mechanism changed: kill the Wr[128] scratch spill.
// Evidence: fused R12 kernel = 252 VGPR (Wr in regs). Split k_down = 128/120
// VGPR (R15/R16) = the compiler's 4-waves/EU heuristic cap => the 128-float
// Wr array lives in SCRATCH, so every dot128/wu128 inner loop does 32 scratch
// vector-loads (~50-200cy, vmcnt-waited). That is the ~4-5x gap between the
// instruction model (~9us) and measured 44us, and why 2x waves (R16) gained
// only 5% (serial dependent chains + shared vector-mem path).
// Fix: __attribute__((amdgpu_waves_per_eu(2,2))) on k_down — truthful (512
// threads = 8 waves = exactly 2/EU at 1 block/CU) and unlocks 256 VGPR/wave.
// Bonus (VGPRs now plentiful): prefetch P3's 16 b4 floats into registers at
// kernel start — cross-XCD L2 latency (~600cy) hides under phases 1-2.
// Everything else byte-identical to R16.

static constexpr int OFF_B4   = 0;      // level-4 betas [s*32+i] (8192 f)
static constexpr int OFF_PART = 8192;   // 256 doubles (512 f)
static constexpr int IC2      = 9760;   // 16 finalize counters, stride 32 ints
static constexpr int IROOT2   = 10272;  // finalize root counter

__device__ __forceinline__ float rsum32(float v) {
#pragma unroll
  for (int k = 1; k <= 16; k <<= 1) v += __shfl_xor(v, k);
  return v;
}
__device__ __forceinline__ void rsum32x2(float& a, float& b) {
#pragma unroll
  for (int k = 1; k <= 16; k <<= 1) { a += __shfl_xor(a, k); b += __shfl_xor(b, k); }
}
__device__ __forceinline__ void rsum32x4(float& a, float& b, float& c, float& d) {
#pragma unroll
  for (int k = 1; k <= 16; k <<= 1) {
    a += __shfl_xor(a, k); b += __shfl_xor(b, k);
    c += __shfl_xor(c, k); d += __shfl_xor(d, k);
  }
}
__device__ __forceinline__ float4 exp4f(float4 v) {
  return make_float4(__expf(v.x), __expf(v.y), __expf(v.z), __expf(v.w));
}

__device__ __forceinline__ float dot128(const float* Wr, const float* X) {
  float t0 = 0.f, t1 = 0.f, t2 = 0.f, t3 = 0.f;
#pragma unroll
  for (int j = 0; j < 32; ++j) {
    const float4 x = *(const float4*)(X + j * 4);
    t0 = fmaf(Wr[4 * j + 0], x.x, t0);
    t1 = fmaf(Wr[4 * j + 1], x.y, t1);
    t2 = fmaf(Wr[4 * j + 2], x.z, t2);
    t3 = fmaf(Wr[4 * j + 3], x.w, t3);
  }
  return (t0 + t1) + (t2 + t3);
}
// Two parents, shared Wr: 8 independent FMA chains, 2 LDS streams.
__device__ __forceinline__ void dot128x2(const float* Wr, const float* X0,
                                         const float* X1, float& o0, float& o1) {
  float a0 = 0.f, a1 = 0.f, a2 = 0.f, a3 = 0.f;
  float b0 = 0.f, b1 = 0.f, b2 = 0.f, b3 = 0.f;
#pragma unroll
  for (int j = 0; j < 32; ++j) {
    const float4 x = *(const float4*)(X0 + j * 4);
    const float4 y = *(const float4*)(X1 + j * 4);
    a0 = fmaf(Wr[4 * j + 0], x.x, a0); b0 = fmaf(Wr[4 * j + 0], y.x, b0);
    a1 = fmaf(Wr[4 * j + 1], x.y, a1); b1 = fmaf(Wr[4 * j + 1], y.y, b1);
    a2 = fmaf(Wr[4 * j + 2], x.z, a2); b2 = fmaf(Wr[4 * j + 2], y.z, b2);
    a3 = fmaf(Wr[4 * j + 3], x.w, a3); b3 = fmaf(Wr[4 * j + 3], y.w, b3);
  }
  o0 = (a0 + a1) + (a2 + a3);
  o1 = (b0 + b1) + (b2 + b3);
}

__device__ __forceinline__ void wu128(const float* Wr, const float* ALG,
                                      const float* rb, int lane,
                                      float w[4], float u[4]) {
  w[0] = w[1] = w[2] = w[3] = 0.f;
  u[0] = u[1] = u[2] = u[3] = 0.f;
#pragma unroll
  for (int ii = 0; ii < 32; ii += 4) {
    const float4 rv = *(const float4*)(rb + ii);
#pragma unroll
    for (int di = 0; di < 4; ++di) {
      const int i = ii + di;
      const float rr = (di == 0) ? rv.x : (di == 1) ? rv.y : (di == 2) ? rv.z : rv.w;
      const float4 av = *(const float4*)(ALG + i * 128 + lane * 4);
      w[0] = fmaf(Wr[i * 4 + 0], rr, w[0]); u[0] = fmaf(av.x, rr, u[0]);
      w[1] = fmaf(Wr[i * 4 + 1], rr, w[1]); u[1] = fmaf(av.y, rr, u[1]);
      w[2] = fmaf(Wr[i * 4 + 2], rr, w[2]); u[2] = fmaf(av.z, rr, u[2]);
      w[3] = fmaf(Wr[i * 4 + 3], rr, w[3]); u[3] = fmaf(av.w, rr, u[3]);
    }
  }
}
// Two parents share the SAME ALG ds_read_b128 stream (2x FLOP per LDS read).
__device__ __forceinline__ void wu128x2(const float* Wr, const float* ALG,
                                        const float* rb0, const float* rb1, int lane,
                                        float w0[4], float u0[4],
                                        float w1[4], float u1[4]) {
#pragma unroll
  for (int l = 0; l < 4; ++l) { w0[l] = u0[l] = w1[l] = u1[l] = 0.f; }
#pragma unroll
  for (int ii = 0; ii < 32; ii += 4) {
    const float4 r0 = *(const float4*)(rb0 + ii);
    const float4 r1 = *(const float4*)(rb1 + ii);
#pragma unroll
    for (int di = 0; di < 4; ++di) {
      const int i = ii + di;
      const float q0 = (di == 0) ? r0.x : (di == 1) ? r0.y : (di == 2) ? r0.z : r0.w;
      const float q1 = (di == 0) ? r1.x : (di == 1) ? r1.y : (di == 2) ? r1.z : r1.w;
      const float4 av = *(const float4*)(ALG + i * 128 + lane * 4);
      w0[0] = fmaf(Wr[i * 4 + 0], q0, w0[0]); w1[0] = fmaf(Wr[i * 4 + 0], q1, w1[0]);
      u0[0] = fmaf(av.x, q0, u0[0]);          u1[0] = fmaf(av.x, q1, u1[0]);
      w0[1] = fmaf(Wr[i * 4 + 1], q0, w0[1]); w1[1] = fmaf(Wr[i * 4 + 1], q1, w1[1]);
      u0[1] = fmaf(av.y, q0, u0[1]);          u1[1] = fmaf(av.y, q1, u1[1]);
      w0[2] = fmaf(Wr[i * 4 + 2], q0, w0[2]); w1[2] = fmaf(Wr[i * 4 + 2], q1, w1[2]);
      u0[2] = fmaf(av.z, q0, u0[2]);          u1[2] = fmaf(av.z, q1, u1[2]);
      w0[3] = fmaf(Wr[i * 4 + 3], q0, w0[3]); w1[3] = fmaf(Wr[i * 4 + 3], q1, w1[3]);
      u0[3] = fmaf(av.w, q0, u0[3]);          u1[3] = fmaf(av.w, q1, u1[3]);
    }
  }
}
// Path walk: w only.
__device__ __forceinline__ void wonly128(const float* Wr, const float* rb,
                                         float w[4]) {
  w[0] = w[1] = w[2] = w[3] = 0.f;
#pragma unroll
  for (int ii = 0; ii < 32; ii += 4) {
    const float4 rv = *(const float4*)(rb + ii);
#pragma unroll
    for (int di = 0; di < 4; ++di) {
      const int i = ii + di;
      const float rr = (di == 0) ? rv.x : (di == 1) ? rv.y : (di == 2) ? rv.z : rv.w;
      w[0] = fmaf(Wr[i * 4 + 0], rr, w[0]);
      w[1] = fmaf(Wr[i * 4 + 1], rr, w[1]);
      w[2] = fmaf(Wr[i * 4 + 2], rr, w[2]);
      w[3] = fmaf(Wr[i * 4 + 3], rr, w[3]);
    }
  }
}

// ============================ k_up: phases 1-2 (256 thr) ====================
__global__ __launch_bounds__(256, 1) void k_up(const int* __restrict__ labels,
                                               const float* __restrict__ A,
                                               const float* __restrict__ B,
                                               const float* __restrict__ Pi,
                                               const float* __restrict__ SP,
                                               float* __restrict__ ws) {
  __shared__ __align__(16) float scr[4224];
  __shared__ __align__(16) float regB[4224];
  __shared__ __align__(16) float sPt[132];
  __shared__ int labs[425];
  const int t = threadIdx.x, lane = t & 31, grp = t >> 5;
  const int s = blockIdx.x;
  int* wsi = (int*)ws;
  const float4* A4 = (const float4*)A;
  const float4* B4 = (const float4*)B;

  // zero finalize counters (replaces host memset dispatch; benign same-value
  // stores from all blocks; kernel boundary publishes before k_down atomics)
  if (t < 16) wsi[IC2 + 32 * t] = 0;
  else if (t == 16) wsi[IROOT2] = 0;

  // ---------- phase 1: softmax tables (subset needed for up sweep) ----------
  const float sv0 = SP[0], sv1 = SP[1], sv2 = SP[2], sv3 = SP[3];
  const float sp0 = __expf(sv0), sp1 = __expf(sv1), sp2 = __expf(sv2), sp3 = __expf(sv3);
  const float spsum = sp0 + sp1 + sp2 + sp3;
  const float spinv = 1.f / spsum;
  float4 c4 = make_float4(0.f, 0.f, 0.f, 0.f);
  for (int i = 0; i < 32; ++i) {
    const float4 e = exp4f(A4[i * 32 + lane]);
    c4.x += e.x; c4.y += e.y; c4.z += e.z; c4.w += e.w;
  }
  const float4 inv4 = make_float4(sp0 * spinv / c4.x, sp1 * spinv / c4.y,
                                  sp2 * spinv / c4.z, sp3 * spinv / c4.w);
#pragma unroll
  for (int k = 0; k < 4; ++k) {  // asp (up layout, stride 132)
    const int i = grp * 4 + k;
    const float4 e = exp4f(A4[i * 32 + lane]);
    *(float4*)(scr + i * 132 + 4 * lane) =
        make_float4(e.x * inv4.x, e.y * inv4.y, e.z * inv4.z, e.w * inv4.w);
  }
#pragma unroll
  for (int rI = 0; rI < 4; ++rI) {  // smB^T
    const int i = grp + rI * 8;
    const float4 e = exp4f(B4[i * 32 + lane]);
    const float sinv = 1.f / rsum32(e.x + e.y + e.z + e.w);
    regB[(4 * lane + 0) * 33 + i] = e.x * sinv;
    regB[(4 * lane + 1) * 33 + i] = e.y * sinv;
    regB[(4 * lane + 2) * 33 + i] = e.z * sinv;
    regB[(4 * lane + 3) * 33 + i] = e.w * sinv;
  }
  if (grp < 4) {  // smPi^T
    const float e = __expf(Pi[lane * 4 + grp]);
    sPt[grp * 33 + lane] = e / rsum32(e);
  }
  if (t < 84) {  // subtree labels only
    int g, d;
    if (t < 4) { g = 341 + 4 * s + t; d = 341 + t; }
    else if (t < 20) { g = 1365 + 16 * s + (t - 4); d = 345 + (t - 4); }
    else { g = 5461 + 64 * s + (t - 20); d = 361 + (t - 20); }
    labs[d] = labels[g];
  }
  if (t == 84) labs[85 + (s & 255)] = labels[85 + s];  // own L4 label
  __syncthreads();
  float Wr[128];  // up orientation
#pragma unroll
  for (int j = 0; j < 32; ++j) {
    const float4 v = *(const float4*)(scr + lane * 132 + j * 4);
    Wr[4 * j] = v.x; Wr[4 * j + 1] = v.y; Wr[4 * j + 2] = v.z; Wr[4 * j + 3] = v.w;
  }
  __syncthreads();

  // ---------- phase 2: subtree up sweep ----------
#pragma unroll
  for (int h = 0; h < 2; ++h) {  // S1: 64 leaves, batches of 4
    const int q0 = grp + 32 * h, q1 = q0 + 8, q2 = q0 + 16, q3 = q0 + 24;
    float v0 = sPt[(q0 & 3) * 33 + lane] * regB[labs[361 + q0] * 33 + lane];
    float v1 = sPt[(q1 & 3) * 33 + lane] * regB[labs[361 + q1] * 33 + lane];
    float v2 = sPt[(q2 & 3) * 33 + lane] * regB[labs[361 + q2] * 33 + lane];
    float v3 = sPt[(q3 & 3) * 33 + lane] * regB[labs[361 + q3] * 33 + lane];
    float s0 = v0, s1 = v1, s2 = v2, s3 = v3;
    rsum32x4(s0, s1, s2, s3);
    scr[(q0 >> 2) * 128 + lane * 4 + (q0 & 3)] = v0 / s0;
    scr[(q1 >> 2) * 128 + lane * 4 + (q1 & 3)] = v1 / s1;
    scr[(q2 >> 2) * 128 + lane * 4 + (q2 & 3)] = v2 / s2;
    scr[(q3 >> 2) * 128 + lane * 4 + (q3 & 3)] = v3 / s3;
  }
  __syncthreads();
  {  // S2: 16 L6 parents, paired
    const int p0 = grp, p1 = grp + 8;
    float tb0, tb1;
    dot128x2(Wr, scr + p0 * 128, scr + p1 * 128, tb0, tb1);
    float bl0 = tb0 * regB[labs[345 + p0] * 33 + lane];
    float bl1 = tb1 * regB[labs[345 + p1] * 33 + lane];
    float s0 = bl0, s1 = bl1;
    rsum32x2(s0, s1);
    bl0 /= s0; bl1 /= s1;
    scr[2048 + (p0 >> 2) * 128 + lane * 4 + (p0 & 3)] = bl0;  // X6
    scr[2048 + (p1 >> 2) * 128 + lane * 4 + (p1 & 3)] = bl1;
  }
  __syncthreads();
  if (grp < 4) {  // S3: 4 L5 parents
    const float tb = dot128(Wr, scr + 2048 + grp * 128);
    float bl = tb * regB[labs[341 + grp] * 33 + lane];
    bl /= rsum32(bl);
    scr[2560 + lane * 4 + grp] = bl;  // X5
  }
  __syncthreads();
  if (grp == 0) {  // S4: own level-4 root; publish b4
    const float tb = dot128(Wr, scr + 2560);
    float bl = tb * regB[labs[85 + (s & 255)] * 33 + lane];
    bl /= rsum32(bl);
    ws[OFF_B4 + s * 32 + lane] = bl;
  }
}

// ==================== k_down: 512 threads, 16 lane-groups ==================
// amdgpu_waves_per_eu(2,2): truthful (8 waves/block, 1 block/CU => exactly
// 2 waves/EU) and unlocks 256 VGPR/wave so Wr[128] stays in registers.
__global__ __launch_bounds__(512)
__attribute__((amdgpu_waves_per_eu(2, 2)))
void k_down(const int* __restrict__ labels,
            const float* __restrict__ A,
            const float* __restrict__ B,
            const float* __restrict__ Pi,
            const float* __restrict__ SP,
            float* __restrict__ ws,
            float* __restrict__ out) {
  __shared__ __align__(16) float scr[6144];
  __shared__ __align__(16) float regB[4224];
  __shared__ __align__(16) float sPt[132];
  __shared__ __align__(16) float tbrT[2720];
  __shared__ __align__(16) float tbS[672];
  __shared__ __align__(16) float ownb[32];
  __shared__ __align__(16) float r_buf[512];
  __shared__ int labs[425];
  __shared__ int fin;
  const int t = threadIdx.x, lane = t & 31, grp = t >> 5;  // 16 groups
  const int s = blockIdx.x;
  int* wsi = (int*)ws;
  double* partd = (double*)(ws + OFF_PART);
  const float4* A4 = (const float4*)A;
  const float4* B4 = (const float4*)B;

  // ---------- P3 b4 prefetch: issue 16 global loads NOW, consume in P3 ----
  float pf0[8], pf1[8];
#pragma unroll
  for (int h = 0; h < 2; ++h) {
    const int p0 = grp + 32 * h, p1 = p0 + 16;
#pragma unroll
    for (int l = 0; l < 4; ++l) {
      pf0[h * 4 + l] = ws[OFF_B4 + (p0 * 4 + l) * 32 + lane];
      pf1[h * 4 + l] = ws[OFF_B4 + (p1 * 4 + l) * 32 + lane];
    }
  }

  // ---------- phase 1: softmax tables ----------
  const float sv0 = SP[0], sv1 = SP[1], sv2 = SP[2], sv3 = SP[3];
  const float sp0 = __expf(sv0), sp1 = __expf(sv1), sp2 = __expf(sv2), sp3 = __expf(sv3);
  const float spsum = sp0 + sp1 + sp2 + sp3;
  const float spinv = 1.f / spsum;
  const float lss = __logf(spsum);
  float4 c4 = make_float4(0.f, 0.f, 0.f, 0.f);
  for (int i = 0; i < 32; ++i) {
    const float4 e = exp4f(A4[i * 32 + lane]);
    c4.x += e.x; c4.y += e.y; c4.z += e.z; c4.w += e.w;
  }
  const float4 inv4 = make_float4(sp0 * spinv / c4.x, sp1 * spinv / c4.y,
                                  sp2 * spinv / c4.z, sp3 * spinv / c4.w);
  const float4 sub4 = make_float4(__logf(c4.x) - (sv0 - lss), __logf(c4.y) - (sv1 - lss),
                                  __logf(c4.z) - (sv2 - lss), __logf(c4.w) - (sv3 - lss));
#pragma unroll
  for (int k = 0; k < 2; ++k) {  // asp (up layout, stride 132): 2 rows/group
    const int i = grp * 2 + k;
    const float4 e = exp4f(A4[i * 32 + lane]);
    *(float4*)(scr + i * 132 + 4 * lane) =
        make_float4(e.x * inv4.x, e.y * inv4.y, e.z * inv4.z, e.w * inv4.w);
  }
#pragma unroll
  for (int rI = 0; rI < 2; ++rI) {  // smB^T: 2 rows/group
    const int i = grp + rI * 16;
    const float4 e = exp4f(B4[i * 32 + lane]);
    const float sinv = 1.f / rsum32(e.x + e.y + e.z + e.w);
    regB[(4 * lane + 0) * 33 + i] = e.x * sinv;
    regB[(4 * lane + 1) * 33 + i] = e.y * sinv;
    regB[(4 * lane + 2) * 33 + i] = e.z * sinv;
    regB[(4 * lane + 3) * 33 + i] = e.w * sinv;
  }
  if (grp < 4) {  // smPi^T
    const float e = __expf(Pi[lane * 4 + grp]);
    sPt[grp * 33 + lane] = e / rsum32(e);
  }
  for (int idx = t; idx < 341; idx += 512) labs[idx] = labels[idx];
  if (t < 84) {
    int g, d;
    if (t < 4) { g = 341 + 4 * s + t; d = 341 + t; }
    else if (t < 20) { g = 1365 + 16 * s + (t - 4); d = 345 + (t - 4); }
    else { g = 5461 + 64 * s + (t - 20); d = 361 + (t - 20); }
    labs[d] = labels[g];
  }
  __syncthreads();
  float Wr[128];  // up orientation
#pragma unroll
  for (int j = 0; j < 32; ++j) {
    const float4 v = *(const float4*)(scr + lane * 132 + j * 4);
    Wr[4 * j] = v.x; Wr[4 * j + 1] = v.y; Wr[4 * j + 2] = v.z; Wr[4 * j + 3] = v.w;
  }
  __syncthreads();

  // ---------- phase 2 (recompute): subtree up sweep, NO b4 write ----------
  {  // S1: 64 leaves, 4 per group, single round
    const int q0 = grp, q1 = grp + 16, q2 = grp + 32, q3 = grp + 48;
    float v0 = sPt[(q0 & 3) * 33 + lane] * regB[labs[361 + q0] * 33 + lane];
    float v1 = sPt[(q1 & 3) * 33 + lane] * regB[labs[361 + q1] * 33 + lane];
    float v2 = sPt[(q2 & 3) * 33 + lane] * regB[labs[361 + q2] * 33 + lane];
    float v3 = sPt[(q3 & 3) * 33 + lane] * regB[labs[361 + q3] * 33 + lane];
    float s0 = v0, s1 = v1, s2 = v2, s3 = v3;
    rsum32x4(s0, s1, s2, s3);
    scr[(q0 >> 2) * 128 + lane * 4 + (q0 & 3)] = v0 / s0;
    scr[(q1 >> 2) * 128 + lane * 4 + (q1 & 3)] = v1 / s1;
    scr[(q2 >> 2) * 128 + lane * 4 + (q2 & 3)] = v2 / s2;
    scr[(q3 >> 2) * 128 + lane * 4 + (q3 & 3)] = v3 / s3;
  }
  __syncthreads();
  if (grp < 8) {  // S2: 16 L6 parents, paired (ALG-shared x2 keeps LDS low)
    const int p0 = grp, p1 = grp + 8;
    float tb0, tb1;
    dot128x2(Wr, scr + p0 * 128, scr + p1 * 128, tb0, tb1);
    float bl0 = tb0 * regB[labs[345 + p0] * 33 + lane];
    float bl1 = tb1 * regB[labs[345 + p1] * 33 + lane];
    float s0 = bl0, s1 = bl1;
    rsum32x2(s0, s1);
    bl0 /= s0; bl1 /= s1;
    tbS[(5 + p0) * 32 + lane] = tb0;
    tbS[(5 + p1) * 32 + lane] = tb1;
    scr[2048 + (p0 >> 2) * 128 + lane * 4 + (p0 & 3)] = bl0;  // X6
    scr[2048 + (p1 >> 2) * 128 + lane * 4 + (p1 & 3)] = bl1;
  }
  __syncthreads();
  if (grp < 4) {  // S3: 4 L5 parents
    const float tb = dot128(Wr, scr + 2048 + grp * 128);
    float bl = tb * regB[labs[341 + grp] * 33 + lane];
    bl /= rsum32(bl);
    tbS[(1 + grp) * 32 + lane] = tb;
    scr[2560 + lane * 4 + grp] = bl;  // X5
  }
  __syncthreads();
  if (grp == 0) {  // S4: own level-4 root (local only; b4 already in ws)
    const float tb = dot128(Wr, scr + 2560);
    float bl = tb * regB[labs[85 + s] * 33 + lane];
    bl /= rsum32(bl);
    tbS[lane] = tb;
    ownb[lane] = bl;
  }
  __syncthreads();

  // ---------- phase 3: top up sweep (redundant per block) ----------
  // L3: 64 parents, 16 groups x pair x 2 rounds. Staging rows 0..31
  // (scr 0..4095), bX3 out rows 0..15 at 4096..6143 — disjoint.
#pragma unroll
  for (int h = 0; h < 2; ++h) {
    const int p0 = grp + 32 * h, p1 = p0 + 16;
    float* st0 = scr + grp * 128;
    float* st1 = scr + 2048 + grp * 128;
#pragma unroll
    for (int l = 0; l < 4; ++l) {
      st0[lane * 4 + l] = pf0[h * 4 + l];
      st1[lane * 4 + l] = pf1[h * 4 + l];
    }
    float tb0, tb1;
    dot128x2(Wr, st0, st1, tb0, tb1);
    float bl0 = tb0 * regB[labs[21 + p0] * 33 + lane];
    float bl1 = tb1 * regB[labs[21 + p1] * 33 + lane];
    float s0 = bl0, s1 = bl1;
    rsum32x2(s0, s1);
    bl0 /= s0; bl1 /= s1;
    tbrT[(21 + p0) * 32 + lane] = tb0;
    tbrT[(21 + p1) * 32 + lane] = tb1;
    scr[4096 + (p0 >> 2) * 128 + lane * 4 + (p0 & 3)] = bl0;  // bX3
    scr[4096 + (p1 >> 2) * 128 + lane * 4 + (p1 & 3)] = bl1;
  }
  __syncthreads();
  {  // L2: 16 parents, one per group
    const int p = grp;
    const float tb = dot128(Wr, scr + 4096 + p * 128);
    float bl = tb * regB[labs[5 + p] * 33 + lane];
    bl /= rsum32(bl);
    tbrT[(5 + p) * 32 + lane] = tb;
    scr[(p >> 2) * 128 + lane * 4 + (p & 3)] = bl;  // bX2 rows 0..3
  }
  __syncthreads();
  if (grp < 4) {  // L1: 4 parents
    const float tb = dot128(Wr, scr + grp * 128);
    float bl = tb * regB[labs[1 + grp] * 33 + lane];
    bl /= rsum32(bl);
    tbrT[(1 + grp) * 32 + lane] = tb;
    scr[512 + lane * 4 + grp] = bl;  // bX1 (row 4)
  }
  __syncthreads();
  if (grp == 0) tbrT[lane] = dot128(Wr, scr + 512);  // root tb
  __syncthreads();

  // ---------- phase 4: transition to down tables ----------
  for (int idx = t; idx < 4224; idx += 512) regB[idx] = __logf(regB[idx]);
  if (t < 132) sPt[t] = __logf(sPt[t]);
#pragma unroll
  for (int i = 0; i < 32; ++i) {  // Wr -> down orient (lane=j); scr -> ALG
    const float4 av = A4[i * 32 + lane];
    const float4 e = exp4f(av);
    const float4 asp = make_float4(e.x * inv4.x, e.y * inv4.y, e.z * inv4.z, e.w * inv4.w);
    Wr[i * 4 + 0] = asp.x; Wr[i * 4 + 1] = asp.y;
    Wr[i * 4 + 2] = asp.z; Wr[i * 4 + 3] = asp.w;
    if (grp == (i >> 1))  // 2 rows per group
      *(float4*)(scr + i * 128 + lane * 4) =
          make_float4(asp.x * (av.x - sub4.x), asp.y * (av.y - sub4.y),
                      asp.z * (av.z - sub4.z), asp.w * (av.w - sub4.w));
  }
  __syncthreads();

  // ---------- phase 5: top down, DISTRIBUTED owners (R13) ----------
  double ll = 0.0;
  float eps4own = 0.f;  // valid in grp 0
  if (grp < 4) {
    const int n1 = 1 + (s >> 6), n2 = 5 + (s >> 4), n3 = 21 + (s >> 2);
    const int a0 = s >> 6, a1 = (s >> 4) & 3, a2 = (s >> 2) & 3, a3 = s & 3;
    float w[4], uv[4];
    float* rb = r_buf + grp * 32;

    // ---- step 0: root (owner: block 0, grp 0) ----
    float tbv = tbrT[lane];
    float bcv = tbv * __expf(regB[labs[0] * 33 + lane]);
    bcv /= rsum32(bcv);
    rb[lane] = bcv / tbv;
    if (grp == 0 && s == 0) {
      ll += (double)(bcv * regB[labs[0] * 33 + lane]);  // root eps*logB
      wu128(Wr, scr, rb, lane, w, uv);
      const float lb0 = regB[labs[1] * 33 + lane], lb1 = regB[labs[2] * 33 + lane];
      const float lb2 = regB[labs[3] * 33 + lane], lb3 = regB[labs[4] * 33 + lane];
      float b0 = tbrT[1 * 32 + lane] * __expf(lb0);
      float b1 = tbrT[2 * 32 + lane] * __expf(lb1);
      float b2 = tbrT[3 * 32 + lane] * __expf(lb2);
      float b3 = tbrT[4 * 32 + lane] * __expf(lb3);
      float s0 = b0, s1 = b1, s2 = b2, s3 = b3;
      rsum32x4(s0, s1, s2, s3);
      b0 /= s0; b1 /= s1; b2 /= s2; b3 /= s3;
      ll += (double)(b0 * uv[0]) + (double)(b0 * w[0] * lb0);
      ll += (double)(b1 * uv[1]) + (double)(b1 * w[1] * lb1);
      ll += (double)(b2 * uv[2]) + (double)(b2 * w[2] * lb2);
      ll += (double)(b3 * uv[3]) + (double)(b3 * w[3] * lb3);
    } else {
      wonly128(Wr, rb, w);
    }

    // ---- step 1: node n1 (owner: s&63==0, grp 1) ----
    tbv = tbrT[n1 * 32 + lane];
    bcv = tbv * __expf(regB[labs[n1] * 33 + lane]);
    bcv /= rsum32(bcv);
    rb[lane] = (bcv * w[a0]) / tbv;
    if (grp == 1 && (s & 63) == 0) {
      wu128(Wr, scr, rb, lane, w, uv);
      const int cb = 5 + 4 * (s >> 6);
      const float lb0 = regB[labs[cb + 0] * 33 + lane], lb1 = regB[labs[cb + 1] * 33 + lane];
      const float lb2 = regB[labs[cb + 2] * 33 + lane], lb3 = regB[labs[cb + 3] * 33 + lane];
      float b0 = tbrT[(cb + 0) * 32 + lane] * __expf(lb0);
      float b1 = tbrT[(cb + 1) * 32 + lane] * __expf(lb1);
      float b2 = tbrT[(cb + 2) * 32 + lane] * __expf(lb2);
      float b3 = tbrT[(cb + 3) * 32 + lane] * __expf(lb3);
      float s0 = b0, s1 = b1, s2 = b2, s3 = b3;
      rsum32x4(s0, s1, s2, s3);
      b0 /= s0; b1 /= s1; b2 /= s2; b3 /= s3;
      ll += (double)(b0 * uv[0]) + (double)(b0 * w[0] * lb0);
      ll += (double)(b1 * uv[1]) + (double)(b1 * w[1] * lb1);
      ll += (double)(b2 * uv[2]) + (double)(b2 * w[2] * lb2);
      ll += (double)(b3 * uv[3]) + (double)(b3 * w[3] * lb3);
    } else {
      wonly128(Wr, rb, w);
    }

    // ---- step 2: node n2 (owner: s&15==0, grp 2) ----
    tbv = tbrT[n2 * 32 + lane];
    bcv = tbv * __expf(regB[labs[n2] * 33 + lane]);
    bcv /= rsum32(bcv);
    rb[lane] = (bcv * w[a1]) / tbv;
    if (grp == 2 && (s & 15) == 0) {
      wu128(Wr, scr, rb, lane, w, uv);
      const int cb = 21 + 4 * (s >> 4);
      const float lb0 = regB[labs[cb + 0] * 33 + lane], lb1 = regB[labs[cb + 1] * 33 + lane];
      const float lb2 = regB[labs[cb + 2] * 33 + lane], lb3 = regB[labs[cb + 3] * 33 + lane];
      float b0 = tbrT[(cb + 0) * 32 + lane] * __expf(lb0);
      float b1 = tbrT[(cb + 1) * 32 + lane] * __expf(lb1);
      float b2 = tbrT[(cb + 2) * 32 + lane] * __expf(lb2);
      float b3 = tbrT[(cb + 3) * 32 + lane] * __expf(lb3);
      float s0 = b0, s1 = b1, s2 = b2, s3 = b3;
      rsum32x4(s0, s1, s2, s3);
      b0 /= s0; b1 /= s1; b2 /= s2; b3 /= s3;
      ll += (double)(b0 * uv[0]) + (double)(b0 * w[0] * lb0);
      ll += (double)(b1 * uv[1]) + (double)(b1 * w[1] * lb1);
      ll += (double)(b2 * uv[2]) + (double)(b2 * w[2] * lb2);
      ll += (double)(b3 * uv[3]) + (double)(b3 * w[3] * lb3);
    } else {
      wonly128(Wr, rb, w);
    }

    // ---- step 3: node n3 (owner: s&3==0, grp 3); children are L4 (b4) ----
    tbv = tbrT[n3 * 32 + lane];
    bcv = tbv * __expf(regB[labs[n3] * 33 + lane]);
    bcv /= rsum32(bcv);
    rb[lane] = (bcv * w[a2]) / tbv;
    if (grp == 3 && (s & 3) == 0) {
      wu128(Wr, scr, rb, lane, w, uv);
      const int cb = s & ~3;  // 4*(s>>2)
#pragma unroll
      for (int l = 0; l < 4; ++l) {
        const int ci = cb + l;
        const float bc = ws[OFF_B4 + ci * 32 + lane];
        const float e = bc * w[l];
        ll += (double)(bc * uv[l]) + (double)(e * regB[labs[85 + ci] * 33 + lane]);
      }
    } else {
      wonly128(Wr, rb, w);
    }
    eps4own = ownb[lane] * w[a3];
  }
  __syncthreads();

  // ---------- phase 6: subtree down sweep ----------
  if (grp == 0) {  // d0: own L4 node -> L5 children
    r_buf[lane] = eps4own / tbS[lane];
    float w[4], u[4];
    wu128(Wr, scr, r_buf, lane, w, u);
#pragma unroll
    for (int l = 0; l < 4; ++l) {
      const int lab = labs[341 + l];
      const float tbv = tbS[(1 + l) * 32 + lane];
      float bcv = tbv * __expf(regB[lab * 33 + lane]);
      bcv /= rsum32(bcv);
      const float e = bcv * w[l];
      ll += (double)(bcv * u[l]) + (double)(e * regB[lab * 33 + lane]);
      tbS[(1 + l) * 32 + lane] = e / tbv;
    }
  }
  __syncthreads();
  if (grp < 4) {  // d1: 4 L5 parents -> L6 children
    const int p = grp;
    r_buf[p * 32 + lane] = tbS[(1 + p) * 32 + lane];
    float w[4], u[4];
    wu128(Wr, scr, r_buf + p * 32, lane, w, u);
#pragma unroll
    for (int l = 0; l < 4; ++l) {
      const int q = p * 4 + l;
      const int lab = labs[345 + q];
      const float tbv = tbS[(5 + q) * 32 + lane];
      float bcv = tbv * __expf(regB[lab * 33 + lane]);
      bcv /= rsum32(bcv);
      const float e = bcv * w[l];
      ll += (double)(bcv * u[l]) + (double)(e * regB[lab * 33 + lane]);
      tbS[(5 + q) * 32 + lane] = e / tbv;
    }
  }
  __syncthreads();
  if (grp < 8) {  // d2: 16 L6 parents -> leaves, paired
    const int p0 = grp, p1 = grp + 8;
    float* rb0 = r_buf + grp * 32;
    float* rb1 = r_buf + 256 + grp * 32;
    rb0[lane] = tbS[(5 + p0) * 32 + lane];
    rb1[lane] = tbS[(5 + p1) * 32 + lane];
    float w0[4], u0[4], w1[4], u1[4];
    wu128x2(Wr, scr, rb0, rb1, lane, w0, u0, w1, u1);
#pragma unroll
    for (int l = 0; l < 4; ++l) {
      const int q0 = p0 * 4 + l, q1 = p1 * 4 + l;
      const float lb0 = regB[labs[361 + q0] * 33 + lane];
      const float lb1 = regB[labs[361 + q1] * 33 + lane];
      const float lp = sPt[l * 33 + lane];
      float b0 = __expf(lp + lb0);
      float b1 = __expf(lp + lb1);
      float s0 = b0, s1 = b1;
      rsum32x2(s0, s1);
      b0 /= s0; b1 /= s1;
      const float e0 = b0 * w0[l], e1 = b1 * w1[l];
      ll += (double)(b0 * u0[l]) + (double)(e0 * lb0) + (double)(e0 * lp);
      ll += (double)(b1 * u1[l]) + (double)(e1 * lb1) + (double)(e1 * lp);
    }
  }

  // ---------- phase 7: partials + tree finalize (poll-free atomics) ----------
#pragma unroll
  for (int k = 32; k >= 1; k >>= 1) ll += __shfl_xor(ll, k);
  double* rbd = (double*)r_buf;
  __syncthreads();
  if ((t & 63) == 0) rbd[t >> 6] = ll;  // 8 waves
  __syncthreads();
  if (t == 0) {
    partd[s] = ((rbd[0] + rbd[1]) + (rbd[2] + rbd[3])) +
               ((rbd[4] + rbd[5]) + (rbd[6] + rbd[7]));
    __threadfence();
    int f = 0;
    if (atomicAdd(&wsi[IC2 + 32 * (s >> 4)], 1) == 15)
      if (atomicAdd(&wsi[IROOT2], 1) == 15) f = 1;
    fin = f;
  }
  __syncthreads();
  if (fin) {  // last block: all partials visible (first-touch reads)
    __threadfence();
    if (t < 64) {
      double v = 0.0;
      for (int k = t; k < 256; k += 64) v += partd[k];
#pragma unroll
      for (int k = 32; k >= 1; k >>= 1) v += __shfl_xor(v, k);
      if (t == 0) out[0] = (float)v;
    }
  }
}

extern "C" void kernel_launch(void* const* d_in, const int* in_sizes, int n_in,
                              void* d_out, int out_size, void* d_ws, size_t ws_size,
                              hipStream_t stream) {
  (void)in_sizes; (void)n_in; (void)out_size; (void)ws_size;
  const int* labels = (const int*)d_in[0];
  const float* A = (const float*)d_in[1];
  const float* B = (const float*)d_in[2];
  const float* Pi = (const float*)d_in[3];
  const float* SP = (const float*)d_in[4];
  float* ws = (float*)d_ws;
  float* out = (float*)d_out;

  // no memset dispatch: k_up zeroes the finalize counters
  hipLaunchKernelGGL(k_up, dim3(256), dim3(256), 0, stream,
                     labels, A, B, Pi, SP, ws);
  hipLaunchKernelGGL(k_down, dim3(256), dim3(512), 0, stream,
                     labels, A, B, Pi, SP, ws, out);
}

// Round 6
// 106.440 us; speedup vs baseline: 1.3439x; 1.0093x over previous
//
#include <hip/hip_runtime.h>

// HTMM: C=32 states, L=4 fanout, M=128 symbols, DEPTH=7.
// Level starts: {0,1,5,21,85,341,1365,5461,21845}.
// R18 = R17 with the Wr[128] ALLOCA ELIMINATED: 32 named float4 locals
// (Wr0..Wr31) + X-macro dot/wu kernels over those names.
// Evidence chain: R15/R16 k_down VGPR=128/120 with launch_bounds(512,1)
// (budget 512) => the allocator was never budget-capped; the 128-float array
// simply isn't promoted (AMDGPU promote-alloca declines it; fused R12 at 256
// thr DID promote: VGPR 252 = 124 + 128). Wr lives in scratch: 512thr x 512B
// = 256KB/CU working set (L1=32KB) -> every dot128/wu128 does 32 L2-latency
// round-trips; R17's waves_per_eu attr predictably changed nothing (VGPR 124).
// Named float4 locals are promoted by mem2reg unconditionally - no heuristic.
// Everything else (phases, LDS, barriers, b4 prefetch, launch) = R17.

static constexpr int OFF_B4   = 0;      // level-4 betas [s*32+i] (8192 f)
static constexpr int OFF_PART = 8192;   // 256 doubles (512 f)
static constexpr int IC2      = 9760;   // 16 finalize counters, stride 32 ints
static constexpr int IROOT2   = 10272;  // finalize root counter

__device__ __forceinline__ float rsum32(float v) {
#pragma unroll
  for (int k = 1; k <= 16; k <<= 1) v += __shfl_xor(v, k);
  return v;
}
__device__ __forceinline__ void rsum32x2(float& a, float& b) {
#pragma unroll
  for (int k = 1; k <= 16; k <<= 1) { a += __shfl_xor(a, k); b += __shfl_xor(b, k); }
}
__device__ __forceinline__ void rsum32x4(float& a, float& b, float& c, float& d) {
#pragma unroll
  for (int k = 1; k <= 16; k <<= 1) {
    a += __shfl_xor(a, k); b += __shfl_xor(b, k);
    c += __shfl_xor(c, k); d += __shfl_xor(d, k);
  }
}
__device__ __forceinline__ float4 exp4f(float4 v) {
  return make_float4(__expf(v.x), __expf(v.y), __expf(v.z), __expf(v.w));
}

// ---------------- register-file W matrix: 32 named float4 ----------------
#define W_DECL float4 Wr0, Wr1, Wr2, Wr3, Wr4, Wr5, Wr6, Wr7, Wr8, Wr9,     \
    Wr10, Wr11, Wr12, Wr13, Wr14, Wr15, Wr16, Wr17, Wr18, Wr19, Wr20, Wr21, \
    Wr22, Wr23, Wr24, Wr25, Wr26, Wr27, Wr28, Wr29, Wr30, Wr31;

#define REPW(X) X(0,Wr0) X(1,Wr1) X(2,Wr2) X(3,Wr3) X(4,Wr4) X(5,Wr5)       \
    X(6,Wr6) X(7,Wr7) X(8,Wr8) X(9,Wr9) X(10,Wr10) X(11,Wr11) X(12,Wr12)    \
    X(13,Wr13) X(14,Wr14) X(15,Wr15) X(16,Wr16) X(17,Wr17) X(18,Wr18)       \
    X(19,Wr19) X(20,Wr20) X(21,Wr21) X(22,Wr22) X(23,Wr23) X(24,Wr24)       \
    X(25,Wr25) X(26,Wr26) X(27,Wr27) X(28,Wr28) X(29,Wr29) X(30,Wr30)       \
    X(31,Wr31)

#define REPQ(X) X(0,Wr0,Wr1,Wr2,Wr3) X(1,Wr4,Wr5,Wr6,Wr7)                   \
    X(2,Wr8,Wr9,Wr10,Wr11) X(3,Wr12,Wr13,Wr14,Wr15) X(4,Wr16,Wr17,Wr18,Wr19)\
    X(5,Wr20,Wr21,Wr22,Wr23) X(6,Wr24,Wr25,Wr26,Wr27) X(7,Wr28,Wr29,Wr30,Wr31)

// load up-orientation row (lane) from scr (stride 132, 16B-aligned: 528B)
#define WLD_B(J, WJ) WJ = *(const float4*)(scrW_ + 4 * (J));
#define W_LOADUP { const float* scrW_ = scr + lane * 132; REPW(WLD_B) }

// tb = dot(W_row_lane, X[0..127])
#define DOT_B(J, WJ) { const float4 x_ = *(const float4*)(dXp_ + 4 * (J));   \
    dt0_ = fmaf(WJ.x, x_.x, dt0_); dt1_ = fmaf(WJ.y, x_.y, dt1_);            \
    dt2_ = fmaf(WJ.z, x_.z, dt2_); dt3_ = fmaf(WJ.w, x_.w, dt3_); }
#define DOT128M(OUT, XP) { const float* dXp_ = (XP);                         \
    float dt0_ = 0.f, dt1_ = 0.f, dt2_ = 0.f, dt3_ = 0.f;                    \
    REPW(DOT_B) (OUT) = (dt0_ + dt1_) + (dt2_ + dt3_); }

// two parents, shared W row
#define DOTX2_B(J, WJ) {                                                     \
    const float4 x_ = *(const float4*)(dXp0_ + 4 * (J));                     \
    const float4 y_ = *(const float4*)(dXp1_ + 4 * (J));                     \
    da0_ = fmaf(WJ.x, x_.x, da0_); db0_ = fmaf(WJ.x, y_.x, db0_);            \
    da1_ = fmaf(WJ.y, x_.y, da1_); db1_ = fmaf(WJ.y, y_.y, db1_);            \
    da2_ = fmaf(WJ.z, x_.z, da2_); db2_ = fmaf(WJ.z, y_.z, db2_);            \
    da3_ = fmaf(WJ.w, x_.w, da3_); db3_ = fmaf(WJ.w, y_.w, db3_); }
#define DOT128X2M(O0, O1, XP0, XP1) {                                        \
    const float* dXp0_ = (XP0); const float* dXp1_ = (XP1);                  \
    float da0_ = 0.f, da1_ = 0.f, da2_ = 0.f, da3_ = 0.f;                    \
    float db0_ = 0.f, db1_ = 0.f, db2_ = 0.f, db3_ = 0.f;                    \
    REPW(DOTX2_B) (O0) = (da0_ + da1_) + (da2_ + da3_);                      \
    (O1) = (db0_ + db1_) + (db2_ + db3_); }

// path walk: w only.  w_l += W[i].l * rb[i]
#define WO_B(Q, WA, WB, WC, WD) {                                            \
    const float4 rv_ = *(const float4*)(rbp_ + 4 * (Q));                     \
    ww0_ = fmaf(WA.x, rv_.x, ww0_); ww1_ = fmaf(WA.y, rv_.x, ww1_);          \
    ww2_ = fmaf(WA.z, rv_.x, ww2_); ww3_ = fmaf(WA.w, rv_.x, ww3_);          \
    ww0_ = fmaf(WB.x, rv_.y, ww0_); ww1_ = fmaf(WB.y, rv_.y, ww1_);          \
    ww2_ = fmaf(WB.z, rv_.y, ww2_); ww3_ = fmaf(WB.w, rv_.y, ww3_);          \
    ww0_ = fmaf(WC.x, rv_.z, ww0_); ww1_ = fmaf(WC.y, rv_.z, ww1_);          \
    ww2_ = fmaf(WC.z, rv_.z, ww2_); ww3_ = fmaf(WC.w, rv_.z, ww3_);          \
    ww0_ = fmaf(WD.x, rv_.w, ww0_); ww1_ = fmaf(WD.y, rv_.w, ww1_);          \
    ww2_ = fmaf(WD.z, rv_.w, ww2_); ww3_ = fmaf(WD.w, rv_.w, ww3_); }
#define WONLY128M(W, RBP) { const float* rbp_ = (RBP);                       \
    float ww0_ = 0.f, ww1_ = 0.f, ww2_ = 0.f, ww3_ = 0.f;                    \
    REPQ(WO_B) (W)[0] = ww0_; (W)[1] = ww1_; (W)[2] = ww2_; (W)[3] = ww3_; }

// w + u (u from ALG rows in scr)
#define WU_SUB(ROW, WX, RC) {                                                \
    const float4 av_ = *(const float4*)(ALGp_ + (ROW) * 128);                \
    ww0_ = fmaf(WX.x, RC, ww0_); uu0_ = fmaf(av_.x, RC, uu0_);               \
    ww1_ = fmaf(WX.y, RC, ww1_); uu1_ = fmaf(av_.y, RC, uu1_);               \
    ww2_ = fmaf(WX.z, RC, ww2_); uu2_ = fmaf(av_.z, RC, uu2_);               \
    ww3_ = fmaf(WX.w, RC, ww3_); uu3_ = fmaf(av_.w, RC, uu3_); }
#define WU_B(Q, WA, WB, WC, WD) {                                            \
    const float4 rv_ = *(const float4*)(rbp_ + 4 * (Q));                     \
    WU_SUB(4 * (Q) + 0, WA, rv_.x) WU_SUB(4 * (Q) + 1, WB, rv_.y)            \
    WU_SUB(4 * (Q) + 2, WC, rv_.z) WU_SUB(4 * (Q) + 3, WD, rv_.w) }
#define WU128M(W, U, RBP) { const float* rbp_ = (RBP);                       \
    const float* ALGp_ = scr + lane * 4;                                     \
    float ww0_ = 0.f, ww1_ = 0.f, ww2_ = 0.f, ww3_ = 0.f;                    \
    float uu0_ = 0.f, uu1_ = 0.f, uu2_ = 0.f, uu3_ = 0.f;                    \
    REPQ(WU_B) (W)[0] = ww0_; (W)[1] = ww1_; (W)[2] = ww2_; (W)[3] = ww3_;   \
    (U)[0] = uu0_; (U)[1] = uu1_; (U)[2] = uu2_; (U)[3] = uu3_; }

// two parents share the ALG read stream
#define WUX2_SUB(ROW, WX, RC0, RC1) {                                        \
    const float4 av_ = *(const float4*)(ALGp_ + (ROW) * 128);                \
    wa0_ = fmaf(WX.x, RC0, wa0_); wb0_ = fmaf(WX.x, RC1, wb0_);              \
    ua0_ = fmaf(av_.x, RC0, ua0_); ub0_ = fmaf(av_.x, RC1, ub0_);            \
    wa1_ = fmaf(WX.y, RC0, wa1_); wb1_ = fmaf(WX.y, RC1, wb1_);              \
    ua1_ = fmaf(av_.y, RC0, ua1_); ub1_ = fmaf(av_.y, RC1, ub1_);            \
    wa2_ = fmaf(WX.z, RC0, wa2_); wb2_ = fmaf(WX.z, RC1, wb2_);              \
    ua2_ = fmaf(av_.z, RC0, ua2_); ub2_ = fmaf(av_.z, RC1, ub2_);            \
    wa3_ = fmaf(WX.w, RC0, wa3_); wb3_ = fmaf(WX.w, RC1, wb3_);              \
    ua3_ = fmaf(av_.w, RC0, ua3_); ub3_ = fmaf(av_.w, RC1, ub3_); }
#define WUX2_B(Q, WA, WB, WC, WD) {                                          \
    const float4 rv0_ = *(const float4*)(rbp0_ + 4 * (Q));                   \
    const float4 rv1_ = *(const float4*)(rbp1_ + 4 * (Q));                   \
    WUX2_SUB(4 * (Q) + 0, WA, rv0_.x, rv1_.x)                                \
    WUX2_SUB(4 * (Q) + 1, WB, rv0_.y, rv1_.y)                                \
    WUX2_SUB(4 * (Q) + 2, WC, rv0_.z, rv1_.z)                                \
    WUX2_SUB(4 * (Q) + 3, WD, rv0_.w, rv1_.w) }
#define WU128X2M(W0, U0, W1, U1, RBP0, RBP1) {                               \
    const float* rbp0_ = (RBP0); const float* rbp1_ = (RBP1);                \
    const float* ALGp_ = scr + lane * 4;                                     \
    float wa0_ = 0.f, wa1_ = 0.f, wa2_ = 0.f, wa3_ = 0.f;                    \
    float ua0_ = 0.f, ua1_ = 0.f, ua2_ = 0.f, ua3_ = 0.f;                    \
    float wb0_ = 0.f, wb1_ = 0.f, wb2_ = 0.f, wb3_ = 0.f;                    \
    float ub0_ = 0.f, ub1_ = 0.f, ub2_ = 0.f, ub3_ = 0.f;                    \
    REPQ(WUX2_B)                                                             \
    (W0)[0] = wa0_; (W0)[1] = wa1_; (W0)[2] = wa2_; (W0)[3] = wa3_;          \
    (U0)[0] = ua0_; (U0)[1] = ua1_; (U0)[2] = ua2_; (U0)[3] = ua3_;          \
    (W1)[0] = wb0_; (W1)[1] = wb1_; (W1)[2] = wb2_; (W1)[3] = wb3_;          \
    (U1)[0] = ub0_; (U1)[1] = ub1_; (U1)[2] = ub2_; (U1)[3] = ub3_; }

// phase-4 rebuild: W -> down orientation; ALG rows into scr
#define WRD_B(J, WJ) { const float4 av = A4[(J) * 32 + lane];                \
    const float4 e = exp4f(av);                                              \
    const float4 asp = make_float4(e.x * inv4.x, e.y * inv4.y,               \
                                   e.z * inv4.z, e.w * inv4.w);              \
    WJ = asp;                                                                \
    if (grp == ((J) >> 1))                                                   \
      *(float4*)(scr + (J) * 128 + lane * 4) =                               \
          make_float4(asp.x * (av.x - sub4.x), asp.y * (av.y - sub4.y),      \
                      asp.z * (av.z - sub4.z), asp.w * (av.w - sub4.w)); }

// ============================ k_up: phases 1-2 (256 thr) ====================
__global__ __launch_bounds__(256, 1) void k_up(const int* __restrict__ labels,
                                               const float* __restrict__ A,
                                               const float* __restrict__ B,
                                               const float* __restrict__ Pi,
                                               const float* __restrict__ SP,
                                               float* __restrict__ ws) {
  __shared__ __align__(16) float scr[4224];
  __shared__ __align__(16) float regB[4224];
  __shared__ __align__(16) float sPt[132];
  __shared__ int labs[425];
  const int t = threadIdx.x, lane = t & 31, grp = t >> 5;
  const int s = blockIdx.x;
  int* wsi = (int*)ws;
  const float4* A4 = (const float4*)A;
  const float4* B4 = (const float4*)B;

  // zero finalize counters (replaces host memset dispatch)
  if (t < 16) wsi[IC2 + 32 * t] = 0;
  else if (t == 16) wsi[IROOT2] = 0;

  // ---------- phase 1: softmax tables (subset needed for up sweep) ----------
  const float sv0 = SP[0], sv1 = SP[1], sv2 = SP[2], sv3 = SP[3];
  const float sp0 = __expf(sv0), sp1 = __expf(sv1), sp2 = __expf(sv2), sp3 = __expf(sv3);
  const float spsum = sp0 + sp1 + sp2 + sp3;
  const float spinv = 1.f / spsum;
  float4 c4 = make_float4(0.f, 0.f, 0.f, 0.f);
  for (int i = 0; i < 32; ++i) {
    const float4 e = exp4f(A4[i * 32 + lane]);
    c4.x += e.x; c4.y += e.y; c4.z += e.z; c4.w += e.w;
  }
  const float4 inv4 = make_float4(sp0 * spinv / c4.x, sp1 * spinv / c4.y,
                                  sp2 * spinv / c4.z, sp3 * spinv / c4.w);
#pragma unroll
  for (int k = 0; k < 4; ++k) {  // asp (up layout, stride 132)
    const int i = grp * 4 + k;
    const float4 e = exp4f(A4[i * 32 + lane]);
    *(float4*)(scr + i * 132 + 4 * lane) =
        make_float4(e.x * inv4.x, e.y * inv4.y, e.z * inv4.z, e.w * inv4.w);
  }
#pragma unroll
  for (int rI = 0; rI < 4; ++rI) {  // smB^T
    const int i = grp + rI * 8;
    const float4 e = exp4f(B4[i * 32 + lane]);
    const float sinv = 1.f / rsum32(e.x + e.y + e.z + e.w);
    regB[(4 * lane + 0) * 33 + i] = e.x * sinv;
    regB[(4 * lane + 1) * 33 + i] = e.y * sinv;
    regB[(4 * lane + 2) * 33 + i] = e.z * sinv;
    regB[(4 * lane + 3) * 33 + i] = e.w * sinv;
  }
  if (grp < 4) {  // smPi^T
    const float e = __expf(Pi[lane * 4 + grp]);
    sPt[grp * 33 + lane] = e / rsum32(e);
  }
  if (t < 84) {  // subtree labels only
    int g, d;
    if (t < 4) { g = 341 + 4 * s + t; d = 341 + t; }
    else if (t < 20) { g = 1365 + 16 * s + (t - 4); d = 345 + (t - 4); }
    else { g = 5461 + 64 * s + (t - 20); d = 361 + (t - 20); }
    labs[d] = labels[g];
  }
  if (t == 84) labs[85 + (s & 255)] = labels[85 + s];  // own L4 label
  __syncthreads();
  W_DECL
  W_LOADUP
  __syncthreads();

  // ---------- phase 2: subtree up sweep ----------
#pragma unroll
  for (int h = 0; h < 2; ++h) {  // S1: 64 leaves, batches of 4
    const int q0 = grp + 32 * h, q1 = q0 + 8, q2 = q0 + 16, q3 = q0 + 24;
    float v0 = sPt[(q0 & 3) * 33 + lane] * regB[labs[361 + q0] * 33 + lane];
    float v1 = sPt[(q1 & 3) * 33 + lane] * regB[labs[361 + q1] * 33 + lane];
    float v2 = sPt[(q2 & 3) * 33 + lane] * regB[labs[361 + q2] * 33 + lane];
    float v3 = sPt[(q3 & 3) * 33 + lane] * regB[labs[361 + q3] * 33 + lane];
    float s0 = v0, s1 = v1, s2 = v2, s3 = v3;
    rsum32x4(s0, s1, s2, s3);
    scr[(q0 >> 2) * 128 + lane * 4 + (q0 & 3)] = v0 / s0;
    scr[(q1 >> 2) * 128 + lane * 4 + (q1 & 3)] = v1 / s1;
    scr[(q2 >> 2) * 128 + lane * 4 + (q2 & 3)] = v2 / s2;
    scr[(q3 >> 2) * 128 + lane * 4 + (q3 & 3)] = v3 / s3;
  }
  __syncthreads();
  {  // S2: 16 L6 parents, paired
    const int p0 = grp, p1 = grp + 8;
    float tb0, tb1;
    DOT128X2M(tb0, tb1, scr + p0 * 128, scr + p1 * 128)
    float bl0 = tb0 * regB[labs[345 + p0] * 33 + lane];
    float bl1 = tb1 * regB[labs[345 + p1] * 33 + lane];
    float s0 = bl0, s1 = bl1;
    rsum32x2(s0, s1);
    bl0 /= s0; bl1 /= s1;
    scr[2048 + (p0 >> 2) * 128 + lane * 4 + (p0 & 3)] = bl0;  // X6
    scr[2048 + (p1 >> 2) * 128 + lane * 4 + (p1 & 3)] = bl1;
  }
  __syncthreads();
  if (grp < 4) {  // S3: 4 L5 parents
    float tb;
    DOT128M(tb, scr + 2048 + grp * 128)
    float bl = tb * regB[labs[341 + grp] * 33 + lane];
    bl /= rsum32(bl);
    scr[2560 + lane * 4 + grp] = bl;  // X5
  }
  __syncthreads();
  if (grp == 0) {  // S4: own level-4 root; publish b4
    float tb;
    DOT128M(tb, scr + 2560)
    float bl = tb * regB[labs[85 + (s & 255)] * 33 + lane];
    bl /= rsum32(bl);
    ws[OFF_B4 + s * 32 + lane] = bl;
  }
}

// ==================== k_down: 512 threads, 16 lane-groups ==================
__global__ __launch_bounds__(512, 1)
void k_down(const int* __restrict__ labels,
            const float* __restrict__ A,
            const float* __restrict__ B,
            const float* __restrict__ Pi,
            const float* __restrict__ SP,
            float* __restrict__ ws,
            float* __restrict__ out) {
  __shared__ __align__(16) float scr[6144];
  __shared__ __align__(16) float regB[4224];
  __shared__ __align__(16) float sPt[132];
  __shared__ __align__(16) float tbrT[2720];
  __shared__ __align__(16) float tbS[672];
  __shared__ __align__(16) float ownb[32];
  __shared__ __align__(16) float r_buf[512];
  __shared__ int labs[425];
  __shared__ int fin;
  const int t = threadIdx.x, lane = t & 31, grp = t >> 5;  // 16 groups
  const int s = blockIdx.x;
  int* wsi = (int*)ws;
  double* partd = (double*)(ws + OFF_PART);
  const float4* A4 = (const float4*)A;
  const float4* B4 = (const float4*)B;

  // ---------- P3 b4 prefetch: issue 16 global loads NOW, consume in P3 ----
  float pf0[8], pf1[8];
#pragma unroll
  for (int h = 0; h < 2; ++h) {
    const int p0 = grp + 32 * h, p1 = p0 + 16;
#pragma unroll
    for (int l = 0; l < 4; ++l) {
      pf0[h * 4 + l] = ws[OFF_B4 + (p0 * 4 + l) * 32 + lane];
      pf1[h * 4 + l] = ws[OFF_B4 + (p1 * 4 + l) * 32 + lane];
    }
  }

  // ---------- phase 1: softmax tables ----------
  const float sv0 = SP[0], sv1 = SP[1], sv2 = SP[2], sv3 = SP[3];
  const float sp0 = __expf(sv0), sp1 = __expf(sv1), sp2 = __expf(sv2), sp3 = __expf(sv3);
  const float spsum = sp0 + sp1 + sp2 + sp3;
  const float spinv = 1.f / spsum;
  const float lss = __logf(spsum);
  float4 c4 = make_float4(0.f, 0.f, 0.f, 0.f);
  for (int i = 0; i < 32; ++i) {
    const float4 e = exp4f(A4[i * 32 + lane]);
    c4.x += e.x; c4.y += e.y; c4.z += e.z; c4.w += e.w;
  }
  const float4 inv4 = make_float4(sp0 * spinv / c4.x, sp1 * spinv / c4.y,
                                  sp2 * spinv / c4.z, sp3 * spinv / c4.w);
  const float4 sub4 = make_float4(__logf(c4.x) - (sv0 - lss), __logf(c4.y) - (sv1 - lss),
                                  __logf(c4.z) - (sv2 - lss), __logf(c4.w) - (sv3 - lss));
#pragma unroll
  for (int k = 0; k < 2; ++k) {  // asp (up layout, stride 132): 2 rows/group
    const int i = grp * 2 + k;
    const float4 e = exp4f(A4[i * 32 + lane]);
    *(float4*)(scr + i * 132 + 4 * lane) =
        make_float4(e.x * inv4.x, e.y * inv4.y, e.z * inv4.z, e.w * inv4.w);
  }
#pragma unroll
  for (int rI = 0; rI < 2; ++rI) {  // smB^T: 2 rows/group
    const int i = grp + rI * 16;
    const float4 e = exp4f(B4[i * 32 + lane]);
    const float sinv = 1.f / rsum32(e.x + e.y + e.z + e.w);
    regB[(4 * lane + 0) * 33 + i] = e.x * sinv;
    regB[(4 * lane + 1) * 33 + i] = e.y * sinv;
    regB[(4 * lane + 2) * 33 + i] = e.z * sinv;
    regB[(4 * lane + 3) * 33 + i] = e.w * sinv;
  }
  if (grp < 4) {  // smPi^T
    const float e = __expf(Pi[lane * 4 + grp]);
    sPt[grp * 33 + lane] = e / rsum32(e);
  }
  for (int idx = t; idx < 341; idx += 512) labs[idx] = labels[idx];
  if (t < 84) {
    int g, d;
    if (t < 4) { g = 341 + 4 * s + t; d = 341 + t; }
    else if (t < 20) { g = 1365 + 16 * s + (t - 4); d = 345 + (t - 4); }
    else { g = 5461 + 64 * s + (t - 20); d = 361 + (t - 20); }
    labs[d] = labels[g];
  }
  __syncthreads();
  W_DECL
  W_LOADUP
  __syncthreads();

  // ---------- phase 2 (recompute): subtree up sweep, NO b4 write ----------
  {  // S1: 64 leaves, 4 per group, single round
    const int q0 = grp, q1 = grp + 16, q2 = grp + 32, q3 = grp + 48;
    float v0 = sPt[(q0 & 3) * 33 + lane] * regB[labs[361 + q0] * 33 + lane];
    float v1 = sPt[(q1 & 3) * 33 + lane] * regB[labs[361 + q1] * 33 + lane];
    float v2 = sPt[(q2 & 3) * 33 + lane] * regB[labs[361 + q2] * 33 + lane];
    float v3 = sPt[(q3 & 3) * 33 + lane] * regB[labs[361 + q3] * 33 + lane];
    float s0 = v0, s1 = v1, s2 = v2, s3 = v3;
    rsum32x4(s0, s1, s2, s3);
    scr[(q0 >> 2) * 128 + lane * 4 + (q0 & 3)] = v0 / s0;
    scr[(q1 >> 2) * 128 + lane * 4 + (q1 & 3)] = v1 / s1;
    scr[(q2 >> 2) * 128 + lane * 4 + (q2 & 3)] = v2 / s2;
    scr[(q3 >> 2) * 128 + lane * 4 + (q3 & 3)] = v3 / s3;
  }
  __syncthreads();
  if (grp < 8) {  // S2: 16 L6 parents, paired
    const int p0 = grp, p1 = grp + 8;
    float tb0, tb1;
    DOT128X2M(tb0, tb1, scr + p0 * 128, scr + p1 * 128)
    float bl0 = tb0 * regB[labs[345 + p0] * 33 + lane];
    float bl1 = tb1 * regB[labs[345 + p1] * 33 + lane];
    float s0 = bl0, s1 = bl1;
    rsum32x2(s0, s1);
    bl0 /= s0; bl1 /= s1;
    tbS[(5 + p0) * 32 + lane] = tb0;
    tbS[(5 + p1) * 32 + lane] = tb1;
    scr[2048 + (p0 >> 2) * 128 + lane * 4 + (p0 & 3)] = bl0;  // X6
    scr[2048 + (p1 >> 2) * 128 + lane * 4 + (p1 & 3)] = bl1;
  }
  __syncthreads();
  if (grp < 4) {  // S3: 4 L5 parents
    float tb;
    DOT128M(tb, scr + 2048 + grp * 128)
    float bl = tb * regB[labs[341 + grp] * 33 + lane];
    bl /= rsum32(bl);
    tbS[(1 + grp) * 32 + lane] = tb;
    scr[2560 + lane * 4 + grp] = bl;  // X5
  }
  __syncthreads();
  if (grp == 0) {  // S4: own level-4 root (local only; b4 already in ws)
    float tb;
    DOT128M(tb, scr + 2560)
    float bl = tb * regB[labs[85 + s] * 33 + lane];
    bl /= rsum32(bl);
    tbS[lane] = tb;
    ownb[lane] = bl;
  }
  __syncthreads();

  // ---------- phase 3: top up sweep (redundant per block) ----------
#pragma unroll
  for (int h = 0; h < 2; ++h) {
    const int p0 = grp + 32 * h, p1 = p0 + 16;
    float* st0 = scr + grp * 128;
    float* st1 = scr + 2048 + grp * 128;
#pragma unroll
    for (int l = 0; l < 4; ++l) {
      st0[lane * 4 + l] = pf0[h * 4 + l];
      st1[lane * 4 + l] = pf1[h * 4 + l];
    }
    float tb0, tb1;
    DOT128X2M(tb0, tb1, st0, st1)
    float bl0 = tb0 * regB[labs[21 + p0] * 33 + lane];
    float bl1 = tb1 * regB[labs[21 + p1] * 33 + lane];
    float s0 = bl0, s1 = bl1;
    rsum32x2(s0, s1);
    bl0 /= s0; bl1 /= s1;
    tbrT[(21 + p0) * 32 + lane] = tb0;
    tbrT[(21 + p1) * 32 + lane] = tb1;
    scr[4096 + (p0 >> 2) * 128 + lane * 4 + (p0 & 3)] = bl0;  // bX3
    scr[4096 + (p1 >> 2) * 128 + lane * 4 + (p1 & 3)] = bl1;
  }
  __syncthreads();
  {  // L2: 16 parents, one per group
    const int p = grp;
    float tb;
    DOT128M(tb, scr + 4096 + p * 128)
    float bl = tb * regB[labs[5 + p] * 33 + lane];
    bl /= rsum32(bl);
    tbrT[(5 + p) * 32 + lane] = tb;
    scr[(p >> 2) * 128 + lane * 4 + (p & 3)] = bl;  // bX2 rows 0..3
  }
  __syncthreads();
  if (grp < 4) {  // L1: 4 parents
    float tb;
    DOT128M(tb, scr + grp * 128)
    float bl = tb * regB[labs[1 + grp] * 33 + lane];
    bl /= rsum32(bl);
    tbrT[(1 + grp) * 32 + lane] = tb;
    scr[512 + lane * 4 + grp] = bl;  // bX1 (row 4)
  }
  __syncthreads();
  if (grp == 0) { float tb; DOT128M(tb, scr + 512) tbrT[lane] = tb; }  // root
  __syncthreads();

  // ---------- phase 4: transition to down tables ----------
  for (int idx = t; idx < 4224; idx += 512) regB[idx] = __logf(regB[idx]);
  if (t < 132) sPt[t] = __logf(sPt[t]);
  REPW(WRD_B)
  __syncthreads();

  // ---------- phase 5: top down, DISTRIBUTED owners (R13) ----------
  double ll = 0.0;
  float eps4own = 0.f;  // valid in grp 0
  if (grp < 4) {
    const int n1 = 1 + (s >> 6), n2 = 5 + (s >> 4), n3 = 21 + (s >> 2);
    const int a0 = s >> 6, a1 = (s >> 4) & 3, a2 = (s >> 2) & 3, a3 = s & 3;
    float w[4], uv[4];
    float* rb = r_buf + grp * 32;

    // ---- step 0: root (owner: block 0, grp 0) ----
    float tbv = tbrT[lane];
    float bcv = tbv * __expf(regB[labs[0] * 33 + lane]);
    bcv /= rsum32(bcv);
    rb[lane] = bcv / tbv;
    if (grp == 0 && s == 0) {
      ll += (double)(bcv * regB[labs[0] * 33 + lane]);  // root eps*logB
      WU128M(w, uv, rb)
      const float lb0 = regB[labs[1] * 33 + lane], lb1 = regB[labs[2] * 33 + lane];
      const float lb2 = regB[labs[3] * 33 + lane], lb3 = regB[labs[4] * 33 + lane];
      float b0 = tbrT[1 * 32 + lane] * __expf(lb0);
      float b1 = tbrT[2 * 32 + lane] * __expf(lb1);
      float b2 = tbrT[3 * 32 + lane] * __expf(lb2);
      float b3 = tbrT[4 * 32 + lane] * __expf(lb3);
      float s0 = b0, s1 = b1, s2 = b2, s3 = b3;
      rsum32x4(s0, s1, s2, s3);
      b0 /= s0; b1 /= s1; b2 /= s2; b3 /= s3;
      ll += (double)(b0 * uv[0]) + (double)(b0 * w[0] * lb0);
      ll += (double)(b1 * uv[1]) + (double)(b1 * w[1] * lb1);
      ll += (double)(b2 * uv[2]) + (double)(b2 * w[2] * lb2);
      ll += (double)(b3 * uv[3]) + (double)(b3 * w[3] * lb3);
    } else {
      WONLY128M(w, rb)
    }

    // ---- step 1: node n1 (owner: s&63==0, grp 1) ----
    tbv = tbrT[n1 * 32 + lane];
    bcv = tbv * __expf(regB[labs[n1] * 33 + lane]);
    bcv /= rsum32(bcv);
    rb[lane] = (bcv * w[a0]) / tbv;
    if (grp == 1 && (s & 63) == 0) {
      WU128M(w, uv, rb)
      const int cb = 5 + 4 * (s >> 6);
      const float lb0 = regB[labs[cb + 0] * 33 + lane], lb1 = regB[labs[cb + 1] * 33 + lane];
      const float lb2 = regB[labs[cb + 2] * 33 + lane], lb3 = regB[labs[cb + 3] * 33 + lane];
      float b0 = tbrT[(cb + 0) * 32 + lane] * __expf(lb0);
      float b1 = tbrT[(cb + 1) * 32 + lane] * __expf(lb1);
      float b2 = tbrT[(cb + 2) * 32 + lane] * __expf(lb2);
      float b3 = tbrT[(cb + 3) * 32 + lane] * __expf(lb3);
      float s0 = b0, s1 = b1, s2 = b2, s3 = b3;
      rsum32x4(s0, s1, s2, s3);
      b0 /= s0; b1 /= s1; b2 /= s2; b3 /= s3;
      ll += (double)(b0 * uv[0]) + (double)(b0 * w[0] * lb0);
      ll += (double)(b1 * uv[1]) + (double)(b1 * w[1] * lb1);
      ll += (double)(b2 * uv[2]) + (double)(b2 * w[2] * lb2);
      ll += (double)(b3 * uv[3]) + (double)(b3 * w[3] * lb3);
    } else {
      WONLY128M(w, rb)
    }

    // ---- step 2: node n2 (owner: s&15==0, grp 2) ----
    tbv = tbrT[n2 * 32 + lane];
    bcv = tbv * __expf(regB[labs[n2] * 33 + lane]);
    bcv /= rsum32(bcv);
    rb[lane] = (bcv * w[a1]) / tbv;
    if (grp == 2 && (s & 15) == 0) {
      WU128M(w, uv, rb)
      const int cb = 21 + 4 * (s >> 4);
      const float lb0 = regB[labs[cb + 0] * 33 + lane], lb1 = regB[labs[cb + 1] * 33 + lane];
      const float lb2 = regB[labs[cb + 2] * 33 + lane], lb3 = regB[labs[cb + 3] * 33 + lane];
      float b0 = tbrT[(cb + 0) * 32 + lane] * __expf(lb0);
      float b1 = tbrT[(cb + 1) * 32 + lane] * __expf(lb1);
      float b2 = tbrT[(cb + 2) * 32 + lane] * __expf(lb2);
      float b3 = tbrT[(cb + 3) * 32 + lane] * __expf(lb3);
      float s0 = b0, s1 = b1, s2 = b2, s3 = b3;
      rsum32x4(s0, s1, s2, s3);
      b0 /= s0; b1 /= s1; b2 /= s2; b3 /= s3;
      ll += (double)(b0 * uv[0]) + (double)(b0 * w[0] * lb0);
      ll += (double)(b1 * uv[1]) + (double)(b1 * w[1] * lb1);
      ll += (double)(b2 * uv[2]) + (double)(b2 * w[2] * lb2);
      ll += (double)(b3 * uv[3]) + (double)(b3 * w[3] * lb3);
    } else {
      WONLY128M(w, rb)
    }

    // ---- step 3: node n3 (owner: s&3==0, grp 3); children are L4 (b4) ----
    tbv = tbrT[n3 * 32 + lane];
    bcv = tbv * __expf(regB[labs[n3] * 33 + lane]);
    bcv /= rsum32(bcv);
    rb[lane] = (bcv * w[a2]) / tbv;
    if (grp == 3 && (s & 3) == 0) {
      WU128M(w, uv, rb)
      const int cb = s & ~3;  // 4*(s>>2)
#pragma unroll
      for (int l = 0; l < 4; ++l) {
        const int ci = cb + l;
        const float bc = ws[OFF_B4 + ci * 32 + lane];
        const float e = bc * w[l];
        ll += (double)(bc * uv[l]) + (double)(e * regB[labs[85 + ci] * 33 + lane]);
      }
    } else {
      WONLY128M(w, rb)
    }
    eps4own = ownb[lane] * w[a3];
  }
  __syncthreads();

  // ---------- phase 6: subtree down sweep ----------
  if (grp == 0) {  // d0: own L4 node -> L5 children
    r_buf[lane] = eps4own / tbS[lane];
    float w[4], u[4];
    WU128M(w, u, r_buf)
#pragma unroll
    for (int l = 0; l < 4; ++l) {
      const int lab = labs[341 + l];
      const float tbv = tbS[(1 + l) * 32 + lane];
      float bcv = tbv * __expf(regB[lab * 33 + lane]);
      bcv /= rsum32(bcv);
      const float e = bcv * w[l];
      ll += (double)(bcv * u[l]) + (double)(e * regB[lab * 33 + lane]);
      tbS[(1 + l) * 32 + lane] = e / tbv;
    }
  }
  __syncthreads();
  if (grp < 4) {  // d1: 4 L5 parents -> L6 children
    const int p = grp;
    r_buf[p * 32 + lane] = tbS[(1 + p) * 32 + lane];
    float w[4], u[4];
    WU128M(w, u, r_buf + p * 32)
#pragma unroll
    for (int l = 0; l < 4; ++l) {
      const int q = p * 4 + l;
      const int lab = labs[345 + q];
      const float tbv = tbS[(5 + q) * 32 + lane];
      float bcv = tbv * __expf(regB[lab * 33 + lane]);
      bcv /= rsum32(bcv);
      const float e = bcv * w[l];
      ll += (double)(bcv * u[l]) + (double)(e * regB[lab * 33 + lane]);
      tbS[(5 + q) * 32 + lane] = e / tbv;
    }
  }
  __syncthreads();
  if (grp < 8) {  // d2: 16 L6 parents -> leaves, paired
    const int p0 = grp, p1 = grp + 8;
    float* rb0 = r_buf + grp * 32;
    float* rb1 = r_buf + 256 + grp * 32;
    rb0[lane] = tbS[(5 + p0) * 32 + lane];
    rb1[lane] = tbS[(5 + p1) * 32 + lane];
    float w0[4], u0[4], w1[4], u1[4];
    WU128X2M(w0, u0, w1, u1, rb0, rb1)
#pragma unroll
    for (int l = 0; l < 4; ++l) {
      const int q0 = p0 * 4 + l, q1 = p1 * 4 + l;
      const float lb0 = regB[labs[361 + q0] * 33 + lane];
      const float lb1 = regB[labs[361 + q1] * 33 + lane];
      const float lp = sPt[l * 33 + lane];
      float b0 = __expf(lp + lb0);
      float b1 = __expf(lp + lb1);
      float s0 = b0, s1 = b1;
      rsum32x2(s0, s1);
      b0 /= s0; b1 /= s1;
      const float e0 = b0 * w0[l], e1 = b1 * w1[l];
      ll += (double)(b0 * u0[l]) + (double)(e0 * lb0) + (double)(e0 * lp);
      ll += (double)(b1 * u1[l]) + (double)(e1 * lb1) + (double)(e1 * lp);
    }
  }

  // ---------- phase 7: partials + tree finalize (poll-free atomics) ----------
#pragma unroll
  for (int k = 32; k >= 1; k >>= 1) ll += __shfl_xor(ll, k);
  double* rbd = (double*)r_buf;
  __syncthreads();
  if ((t & 63) == 0) rbd[t >> 6] = ll;  // 8 waves
  __syncthreads();
  if (t == 0) {
    partd[s] = ((rbd[0] + rbd[1]) + (rbd[2] + rbd[3])) +
               ((rbd[4] + rbd[5]) + (rbd[6] + rbd[7]));
    __threadfence();
    int f = 0;
    if (atomicAdd(&wsi[IC2 + 32 * (s >> 4)], 1) == 15)
      if (atomicAdd(&wsi[IROOT2], 1) == 15) f = 1;
    fin = f;
  }
  __syncthreads();
  if (fin) {  // last block: all partials visible (first-touch reads)
    __threadfence();
    if (t < 64) {
      double v = 0.0;
      for (int k = t; k < 256; k += 64) v += partd[k];
#pragma unroll
      for (int k = 32; k >= 1; k >>= 1) v += __shfl_xor(v, k);
      if (t == 0) out[0] = (float)v;
    }
  }
}

extern "C" void kernel_launch(void* const* d_in, const int* in_sizes, int n_in,
                              void* d_out, int out_size, void* d_ws, size_t ws_size,
                              hipStream_t stream) {
  (void)in_sizes; (void)n_in; (void)out_size; (void)ws_size;
  const int* labels = (const int*)d_in[0];
  const float* A = (const float*)d_in[1];
  const float* B = (const float*)d_in[2];
  const float* Pi = (const float*)d_in[3];
  const float* SP = (const float*)d_in[4];
  float* ws = (float*)d_ws;
  float* out = (float*)d_out;

  // no memset dispatch: k_up zeroes the finalize counters
  hipLaunchKernelGGL(k_up, dim3(256), dim3(256), 0, stream,
                     labels, A, B, Pi, SP, ws);
  hipLaunchKernelGGL(k_down, dim3(256), dim3(512), 0, stream,
                     labels, A, B, Pi, SP, ws, out);
}

// Round 8
// 105.601 us; speedup vs baseline: 1.3546x; 1.0079x over previous
//
#include <hip/hip_runtime.h>

// HTMM: C=32 states, L=4 fanout, M=128 symbols, DEPTH=7.
// Level starts: {0,1,5,21,85,341,1365,5461,21845}.
// R20 = R19 with the ACTUAL BUG fixed + ws_size insurance.
// R19 post-mortem: NaN came from `if (t < 672) tbS[t] = ws[OFF_TBO..]` in a
// 512-thread block -> tbS[512..671] (rows 16-20) never staged; phase-6 d2
// reads rows 5..20 -> uninitialized LDS -> NaN in fresh contexts (graph
// replays saw benign stale LDS; launch_once didn't). Fix: strided loop.
// Insurance: R19 also grew ws usage 41KB->797KB on an unverified ws_size
// assumption. ws_size is a host argument, constant per session -> host
// branch is graph-capture-safe: ws_size >= NEED -> persist path (k_up_p/
// k_down_p); else fall back to the R18 kernels verbatim (proven 106.4us).
// Persist path: k_up computes tables (block 0 persists asp/smB/logB/logsPt/
// ALG, ~110KB) + per-block tbS (688KB); k_down = stage ~9KB -> P3 -> slim P4
// -> P5 -> P6 -> P7 (P1/P2/P4-recompute deleted from critical path).

static constexpr int OFF_B4   = 0;      // level-4 betas [s*32+i] (8192 f)
static constexpr int OFF_PART = 8192;   // 256 doubles (512 f)
static constexpr int IC2      = 9760;   // 16 finalize counters, stride 32 ints
static constexpr int IROOT2   = 10272;  // finalize root counter
static constexpr int OFF_ASP  = 10304;  // asp, stride-132 layout (4224 f)
static constexpr int OFF_RB   = 14528;  // smB^T linear (4224 f)
static constexpr int OFF_LRB  = 18752;  // log smB^T (4224 f)
static constexpr int OFF_LSP  = 22976;  // log sPt (132 f, +pad)
static constexpr int OFF_ALG  = 23120;  // ALG rows [J*128+lane*4] (4096 f)
static constexpr int OFF_TBO  = 27216;  // per-block tbS, stride 672 (172032 f)
static constexpr size_t WS_NEED_BYTES = (size_t)(OFF_TBO + 256 * 672) * 4;

__device__ __forceinline__ float rsum32(float v) {
#pragma unroll
  for (int k = 1; k <= 16; k <<= 1) v += __shfl_xor(v, k);
  return v;
}
__device__ __forceinline__ void rsum32x2(float& a, float& b) {
#pragma unroll
  for (int k = 1; k <= 16; k <<= 1) { a += __shfl_xor(a, k); b += __shfl_xor(b, k); }
}
__device__ __forceinline__ void rsum32x4(float& a, float& b, float& c, float& d) {
#pragma unroll
  for (int k = 1; k <= 16; k <<= 1) {
    a += __shfl_xor(a, k); b += __shfl_xor(b, k);
    c += __shfl_xor(c, k); d += __shfl_xor(d, k);
  }
}
__device__ __forceinline__ float4 exp4f(float4 v) {
  return make_float4(__expf(v.x), __expf(v.y), __expf(v.z), __expf(v.w));
}

// ---------------- register-file W matrix: 32 named float4 ----------------
#define W_DECL float4 Wr0, Wr1, Wr2, Wr3, Wr4, Wr5, Wr6, Wr7, Wr8, Wr9,     \
    Wr10, Wr11, Wr12, Wr13, Wr14, Wr15, Wr16, Wr17, Wr18, Wr19, Wr20, Wr21, \
    Wr22, Wr23, Wr24, Wr25, Wr26, Wr27, Wr28, Wr29, Wr30, Wr31;

#define REPW(X) X(0,Wr0) X(1,Wr1) X(2,Wr2) X(3,Wr3) X(4,Wr4) X(5,Wr5)       \
    X(6,Wr6) X(7,Wr7) X(8,Wr8) X(9,Wr9) X(10,Wr10) X(11,Wr11) X(12,Wr12)    \
    X(13,Wr13) X(14,Wr14) X(15,Wr15) X(16,Wr16) X(17,Wr17) X(18,Wr18)       \
    X(19,Wr19) X(20,Wr20) X(21,Wr21) X(22,Wr22) X(23,Wr23) X(24,Wr24)       \
    X(25,Wr25) X(26,Wr26) X(27,Wr27) X(28,Wr28) X(29,Wr29) X(30,Wr30)       \
    X(31,Wr31)

#define REPQ(X) X(0,Wr0,Wr1,Wr2,Wr3) X(1,Wr4,Wr5,Wr6,Wr7)                   \
    X(2,Wr8,Wr9,Wr10,Wr11) X(3,Wr12,Wr13,Wr14,Wr15) X(4,Wr16,Wr17,Wr18,Wr19)\
    X(5,Wr20,Wr21,Wr22,Wr23) X(6,Wr24,Wr25,Wr26,Wr27) X(7,Wr28,Wr29,Wr30,Wr31)

// load up-orientation row (lane) from scr (stride 132)
#define WLD_B(J, WJ) WJ = *(const float4*)(scrW_ + 4 * (J));
#define W_LOADUP { const float* scrW_ = scr + lane * 132; REPW(WLD_B) }

// load down-orientation from persisted asp table in ws (row J, cols 4lane..)
#define WLDDN_B(J, WJ) WJ = *(const float4*)(wsASP_ + (J) * 132 + lane * 4);

// tb = dot(W_row_lane, X[0..127])
#define DOT_B(J, WJ) { const float4 x_ = *(const float4*)(dXp_ + 4 * (J));   \
    dt0_ = fmaf(WJ.x, x_.x, dt0_); dt1_ = fmaf(WJ.y, x_.y, dt1_);            \
    dt2_ = fmaf(WJ.z, x_.z, dt2_); dt3_ = fmaf(WJ.w, x_.w, dt3_); }
#define DOT128M(OUT, XP) { const float* dXp_ = (XP);                         \
    float dt0_ = 0.f, dt1_ = 0.f, dt2_ = 0.f, dt3_ = 0.f;                    \
    REPW(DOT_B) (OUT) = (dt0_ + dt1_) + (dt2_ + dt3_); }

// two parents, shared W row
#define DOTX2_B(J, WJ) {                                                     \
    const float4 x_ = *(const float4*)(dXp0_ + 4 * (J));                     \
    const float4 y_ = *(const float4*)(dXp1_ + 4 * (J));                     \
    da0_ = fmaf(WJ.x, x_.x, da0_); db0_ = fmaf(WJ.x, y_.x, db0_);            \
    da1_ = fmaf(WJ.y, x_.y, da1_); db1_ = fmaf(WJ.y, y_.y, db1_);            \
    da2_ = fmaf(WJ.z, x_.z, da2_); db2_ = fmaf(WJ.z, y_.z, db2_);            \
    da3_ = fmaf(WJ.w, x_.w, da3_); db3_ = fmaf(WJ.w, y_.w, db3_); }
#define DOT128X2M(O0, O1, XP0, XP1) {                                        \
    const float* dXp0_ = (XP0); const float* dXp1_ = (XP1);                  \
    float da0_ = 0.f, da1_ = 0.f, da2_ = 0.f, da3_ = 0.f;                    \
    float db0_ = 0.f, db1_ = 0.f, db2_ = 0.f, db3_ = 0.f;                    \
    REPW(DOTX2_B) (O0) = (da0_ + da1_) + (da2_ + da3_);                      \
    (O1) = (db0_ + db1_) + (db2_ + db3_); }

// path walk: w only.  w_l += W[i].l * rb[i]
#define WO_B(Q, WA, WB, WC, WD) {                                            \
    const float4 rv_ = *(const float4*)(rbp_ + 4 * (Q));                     \
    ww0_ = fmaf(WA.x, rv_.x, ww0_); ww1_ = fmaf(WA.y, rv_.x, ww1_);          \
    ww2_ = fmaf(WA.z, rv_.x, ww2_); ww3_ = fmaf(WA.w, rv_.x, ww3_);          \
    ww0_ = fmaf(WB.x, rv_.y, ww0_); ww1_ = fmaf(WB.y, rv_.y, ww1_);          \
    ww2_ = fmaf(WB.z, rv_.y, ww2_); ww3_ = fmaf(WB.w, rv_.y, ww3_);          \
    ww0_ = fmaf(WC.x, rv_.z, ww0_); ww1_ = fmaf(WC.y, rv_.z, ww1_);          \
    ww2_ = fmaf(WC.z, rv_.z, ww2_); ww3_ = fmaf(WC.w, rv_.z, ww3_);          \
    ww0_ = fmaf(WD.x, rv_.w, ww0_); ww1_ = fmaf(WD.y, rv_.w, ww1_);          \
    ww2_ = fmaf(WD.z, rv_.w, ww2_); ww3_ = fmaf(WD.w, rv_.w, ww3_); }
#define WONLY128M(W, RBP) { const float* rbp_ = (RBP);                       \
    float ww0_ = 0.f, ww1_ = 0.f, ww2_ = 0.f, ww3_ = 0.f;                    \
    REPQ(WO_B) (W)[0] = ww0_; (W)[1] = ww1_; (W)[2] = ww2_; (W)[3] = ww3_; }

// w + u (u from ALG rows in scr)
#define WU_SUB(ROW, WX, RC) {                                                \
    const float4 av_ = *(const float4*)(ALGp_ + (ROW) * 128);                \
    ww0_ = fmaf(WX.x, RC, ww0_); uu0_ = fmaf(av_.x, RC, uu0_);               \
    ww1_ = fmaf(WX.y, RC, ww1_); uu1_ = fmaf(av_.y, RC, uu1_);               \
    ww2_ = fmaf(WX.z, RC, ww2_); uu2_ = fmaf(av_.z, RC, uu2_);               \
    ww3_ = fmaf(WX.w, RC, ww3_); uu3_ = fmaf(av_.w, RC, uu3_); }
#define WU_B(Q, WA, WB, WC, WD) {                                            \
    const float4 rv_ = *(const float4*)(rbp_ + 4 * (Q));                     \
    WU_SUB(4 * (Q) + 0, WA, rv_.x) WU_SUB(4 * (Q) + 1, WB, rv_.y)            \
    WU_SUB(4 * (Q) + 2, WC, rv_.z) WU_SUB(4 * (Q) + 3, WD, rv_.w) }
#define WU128M(W, U, RBP) { const float* rbp_ = (RBP);                       \
    const float* ALGp_ = scr + lane * 4;                                     \
    float ww0_ = 0.f, ww1_ = 0.f, ww2_ = 0.f, ww3_ = 0.f;                    \
    float uu0_ = 0.f, uu1_ = 0.f, uu2_ = 0.f, uu3_ = 0.f;                    \
    REPQ(WU_B) (W)[0] = ww0_; (W)[1] = ww1_; (W)[2] = ww2_; (W)[3] = ww3_;   \
    (U)[0] = uu0_; (U)[1] = uu1_; (U)[2] = uu2_; (U)[3] = uu3_; }

// two parents share the ALG read stream
#define WUX2_SUB(ROW, WX, RC0, RC1) {                                        \
    const float4 av_ = *(const float4*)(ALGp_ + (ROW) * 128);                \
    wa0_ = fmaf(WX.x, RC0, wa0_); wb0_ = fmaf(WX.x, RC1, wb0_);              \
    ua0_ = fmaf(av_.x, RC0, ua0_); ub0_ = fmaf(av_.x, RC1, ub0_);            \
    wa1_ = fmaf(WX.y, RC0, wa1_); wb1_ = fmaf(WX.y, RC1, wb1_);              \
    ua1_ = fmaf(av_.y, RC0, ua1_); ub1_ = fmaf(av_.y, RC1, ub1_);            \
    wa2_ = fmaf(WX.z, RC0, wa2_); wb2_ = fmaf(WX.z, RC1, wb2_);              \
    ua2_ = fmaf(av_.z, RC0, ua2_); ub2_ = fmaf(av_.z, RC1, ub2_);            \
    wa3_ = fmaf(WX.w, RC0, wa3_); wb3_ = fmaf(WX.w, RC1, wb3_);              \
    ua3_ = fmaf(av_.w, RC0, ua3_); ub3_ = fmaf(av_.w, RC1, ub3_); }
#define WUX2_B(Q, WA, WB, WC, WD) {                                          \
    const float4 rv0_ = *(const float4*)(rbp0_ + 4 * (Q));                   \
    const float4 rv1_ = *(const float4*)(rbp1_ + 4 * (Q));                   \
    WUX2_SUB(4 * (Q) + 0, WA, rv0_.x, rv1_.x)                                \
    WUX2_SUB(4 * (Q) + 1, WB, rv0_.y, rv1_.y)                                \
    WUX2_SUB(4 * (Q) + 2, WC, rv0_.z, rv1_.z)                                \
    WUX2_SUB(4 * (Q) + 3, WD, rv0_.w, rv1_.w) }
#define WU128X2M(W0, U0, W1, U1, RBP0, RBP1) {                               \
    const float* rbp0_ = (RBP0); const float* rbp1_ = (RBP1);                \
    const float* ALGp_ = scr + lane * 4;                                     \
    float wa0_ = 0.f, wa1_ = 0.f, wa2_ = 0.f, wa3_ = 0.f;                    \
    float ua0_ = 0.f, ua1_ = 0.f, ua2_ = 0.f, ua3_ = 0.f;                    \
    float wb0_ = 0.f, wb1_ = 0.f, wb2_ = 0.f, wb3_ = 0.f;                    \
    float ub0_ = 0.f, ub1_ = 0.f, ub2_ = 0.f, ub3_ = 0.f;                    \
    REPQ(WUX2_B)                                                             \
    (W0)[0] = wa0_; (W0)[1] = wa1_; (W0)[2] = wa2_; (W0)[3] = wa3_;          \
    (U0)[0] = ua0_; (U0)[1] = ua1_; (U0)[2] = ua2_; (U0)[3] = ua3_;          \
    (W1)[0] = wb0_; (W1)[1] = wb1_; (W1)[2] = wb2_; (W1)[3] = wb3_;          \
    (U1)[0] = ub0_; (U1)[1] = ub1_; (U1)[2] = ub2_; (U1)[3] = ub3_; }

// phase-4 rebuild (FALLBACK k_down only): W -> down orient; ALG into scr
#define WRD_B(J, WJ) { const float4 av = A4[(J) * 32 + lane];                \
    const float4 e = exp4f(av);                                              \
    const float4 asp = make_float4(e.x * inv4.x, e.y * inv4.y,               \
                                   e.z * inv4.z, e.w * inv4.w);              \
    WJ = asp;                                                                \
    if (grp == ((J) >> 1))                                                   \
      *(float4*)(scr + (J) * 128 + lane * 4) =                               \
          make_float4(asp.x * (av.x - sub4.x), asp.y * (av.y - sub4.y),      \
                      asp.z * (av.z - sub4.z), asp.w * (av.w - sub4.w)); }

// ======================================================================
// ===================== FALLBACK PATH (R18, proven) ====================
// ======================================================================
__global__ __launch_bounds__(256, 1) void k_up_f(const int* __restrict__ labels,
                                                 const float* __restrict__ A,
                                                 const float* __restrict__ B,
                                                 const float* __restrict__ Pi,
                                                 const float* __restrict__ SP,
                                                 float* __restrict__ ws) {
  __shared__ __align__(16) float scr[4224];
  __shared__ __align__(16) float regB[4224];
  __shared__ __align__(16) float sPt[132];
  __shared__ int labs[425];
  const int t = threadIdx.x, lane = t & 31, grp = t >> 5;
  const int s = blockIdx.x;
  int* wsi = (int*)ws;
  const float4* A4 = (const float4*)A;
  const float4* B4 = (const float4*)B;

  if (t < 16) wsi[IC2 + 32 * t] = 0;
  else if (t == 16) wsi[IROOT2] = 0;

  const float sv0 = SP[0], sv1 = SP[1], sv2 = SP[2], sv3 = SP[3];
  const float sp0 = __expf(sv0), sp1 = __expf(sv1), sp2 = __expf(sv2), sp3 = __expf(sv3);
  const float spsum = sp0 + sp1 + sp2 + sp3;
  const float spinv = 1.f / spsum;
  float4 c4 = make_float4(0.f, 0.f, 0.f, 0.f);
  for (int i = 0; i < 32; ++i) {
    const float4 e = exp4f(A4[i * 32 + lane]);
    c4.x += e.x; c4.y += e.y; c4.z += e.z; c4.w += e.w;
  }
  const float4 inv4 = make_float4(sp0 * spinv / c4.x, sp1 * spinv / c4.y,
                                  sp2 * spinv / c4.z, sp3 * spinv / c4.w);
#pragma unroll
  for (int k = 0; k < 4; ++k) {
    const int i = grp * 4 + k;
    const float4 e = exp4f(A4[i * 32 + lane]);
    *(float4*)(scr + i * 132 + 4 * lane) =
        make_float4(e.x * inv4.x, e.y * inv4.y, e.z * inv4.z, e.w * inv4.w);
  }
#pragma unroll
  for (int rI = 0; rI < 4; ++rI) {
    const int i = grp + rI * 8;
    const float4 e = exp4f(B4[i * 32 + lane]);
    const float sinv = 1.f / rsum32(e.x + e.y + e.z + e.w);
    regB[(4 * lane + 0) * 33 + i] = e.x * sinv;
    regB[(4 * lane + 1) * 33 + i] = e.y * sinv;
    regB[(4 * lane + 2) * 33 + i] = e.z * sinv;
    regB[(4 * lane + 3) * 33 + i] = e.w * sinv;
  }
  if (grp < 4) {
    const float e = __expf(Pi[lane * 4 + grp]);
    sPt[grp * 33 + lane] = e / rsum32(e);
  }
  if (t < 84) {
    int g, d;
    if (t < 4) { g = 341 + 4 * s + t; d = 341 + t; }
    else if (t < 20) { g = 1365 + 16 * s + (t - 4); d = 345 + (t - 4); }
    else { g = 5461 + 64 * s + (t - 20); d = 361 + (t - 20); }
    labs[d] = labels[g];
  }
  if (t == 84) labs[85 + (s & 255)] = labels[85 + s];
  __syncthreads();
  W_DECL
  W_LOADUP
  __syncthreads();

#pragma unroll
  for (int h = 0; h < 2; ++h) {
    const int q0 = grp + 32 * h, q1 = q0 + 8, q2 = q0 + 16, q3 = q0 + 24;
    float v0 = sPt[(q0 & 3) * 33 + lane] * regB[labs[361 + q0] * 33 + lane];
    float v1 = sPt[(q1 & 3) * 33 + lane] * regB[labs[361 + q1] * 33 + lane];
    float v2 = sPt[(q2 & 3) * 33 + lane] * regB[labs[361 + q2] * 33 + lane];
    float v3 = sPt[(q3 & 3) * 33 + lane] * regB[labs[361 + q3] * 33 + lane];
    float s0 = v0, s1 = v1, s2 = v2, s3 = v3;
    rsum32x4(s0, s1, s2, s3);
    scr[(q0 >> 2) * 128 + lane * 4 + (q0 & 3)] = v0 / s0;
    scr[(q1 >> 2) * 128 + lane * 4 + (q1 & 3)] = v1 / s1;
    scr[(q2 >> 2) * 128 + lane * 4 + (q2 & 3)] = v2 / s2;
    scr[(q3 >> 2) * 128 + lane * 4 + (q3 & 3)] = v3 / s3;
  }
  __syncthreads();
  {
    const int p0 = grp, p1 = grp + 8;
    float tb0, tb1;
    DOT128X2M(tb0, tb1, scr + p0 * 128, scr + p1 * 128)
    float bl0 = tb0 * regB[labs[345 + p0] * 33 + lane];
    float bl1 = tb1 * regB[labs[345 + p1] * 33 + lane];
    float s0 = bl0, s1 = bl1;
    rsum32x2(s0, s1);
    bl0 /= s0; bl1 /= s1;
    scr[2048 + (p0 >> 2) * 128 + lane * 4 + (p0 & 3)] = bl0;
    scr[2048 + (p1 >> 2) * 128 + lane * 4 + (p1 & 3)] = bl1;
  }
  __syncthreads();
  if (grp < 4) {
    float tb;
    DOT128M(tb, scr + 2048 + grp * 128)
    float bl = tb * regB[labs[341 + grp] * 33 + lane];
    bl /= rsum32(bl);
    scr[2560 + lane * 4 + grp] = bl;
  }
  __syncthreads();
  if (grp == 0) {
    float tb;
    DOT128M(tb, scr + 2560)
    float bl = tb * regB[labs[85 + (s & 255)] * 33 + lane];
    bl /= rsum32(bl);
    ws[OFF_B4 + s * 32 + lane] = bl;
  }
}

__global__ __launch_bounds__(512, 1)
void k_down_f(const int* __restrict__ labels,
              const float* __restrict__ A,
              const float* __restrict__ B,
              const float* __restrict__ Pi,
              const float* __restrict__ SP,
              float* __restrict__ ws,
              float* __restrict__ out) {
  __shared__ __align__(16) float scr[6144];
  __shared__ __align__(16) float regB[4224];
  __shared__ __align__(16) float sPt[132];
  __shared__ __align__(16) float tbrT[2720];
  __shared__ __align__(16) float tbS[672];
  __shared__ __align__(16) float ownb[32];
  __shared__ __align__(16) float r_buf[512];
  __shared__ int labs[425];
  __shared__ int fin;
  const int t = threadIdx.x, lane = t & 31, grp = t >> 5;
  const int s = blockIdx.x;
  int* wsi = (int*)ws;
  double* partd = (double*)(ws + OFF_PART);
  const float4* A4 = (const float4*)A;
  const float4* B4 = (const float4*)B;

  float pf0[8], pf1[8];
#pragma unroll
  for (int h = 0; h < 2; ++h) {
    const int p0 = grp + 32 * h, p1 = p0 + 16;
#pragma unroll
    for (int l = 0; l < 4; ++l) {
      pf0[h * 4 + l] = ws[OFF_B4 + (p0 * 4 + l) * 32 + lane];
      pf1[h * 4 + l] = ws[OFF_B4 + (p1 * 4 + l) * 32 + lane];
    }
  }

  const float sv0 = SP[0], sv1 = SP[1], sv2 = SP[2], sv3 = SP[3];
  const float sp0 = __expf(sv0), sp1 = __expf(sv1), sp2 = __expf(sv2), sp3 = __expf(sv3);
  const float spsum = sp0 + sp1 + sp2 + sp3;
  const float spinv = 1.f / spsum;
  const float lss = __logf(spsum);
  float4 c4 = make_float4(0.f, 0.f, 0.f, 0.f);
  for (int i = 0; i < 32; ++i) {
    const float4 e = exp4f(A4[i * 32 + lane]);
    c4.x += e.x; c4.y += e.y; c4.z += e.z; c4.w += e.w;
  }
  const float4 inv4 = make_float4(sp0 * spinv / c4.x, sp1 * spinv / c4.y,
                                  sp2 * spinv / c4.z, sp3 * spinv / c4.w);
  const float4 sub4 = make_float4(__logf(c4.x) - (sv0 - lss), __logf(c4.y) - (sv1 - lss),
                                  __logf(c4.z) - (sv2 - lss), __logf(c4.w) - (sv3 - lss));
#pragma unroll
  for (int k = 0; k < 2; ++k) {
    const int i = grp * 2 + k;
    const float4 e = exp4f(A4[i * 32 + lane]);
    *(float4*)(scr + i * 132 + 4 * lane) =
        make_float4(e.x * inv4.x, e.y * inv4.y, e.z * inv4.z, e.w * inv4.w);
  }
#pragma unroll
  for (int rI = 0; rI < 2; ++rI) {
    const int i = grp + rI * 16;
    const float4 e = exp4f(B4[i * 32 + lane]);
    const float sinv = 1.f / rsum32(e.x + e.y + e.z + e.w);
    regB[(4 * lane + 0) * 33 + i] = e.x * sinv;
    regB[(4 * lane + 1) * 33 + i] = e.y * sinv;
    regB[(4 * lane + 2) * 33 + i] = e.z * sinv;
    regB[(4 * lane + 3) * 33 + i] = e.w * sinv;
  }
  if (grp < 4) {
    const float e = __expf(Pi[lane * 4 + grp]);
    sPt[grp * 33 + lane] = e / rsum32(e);
  }
  for (int idx = t; idx < 341; idx += 512) labs[idx] = labels[idx];
  if (t < 84) {
    int g, d;
    if (t < 4) { g = 341 + 4 * s + t; d = 341 + t; }
    else if (t < 20) { g = 1365 + 16 * s + (t - 4); d = 345 + (t - 4); }
    else { g = 5461 + 64 * s + (t - 20); d = 361 + (t - 20); }
    labs[d] = labels[g];
  }
  __syncthreads();
  W_DECL
  W_LOADUP
  __syncthreads();

  {
    const int q0 = grp, q1 = grp + 16, q2 = grp + 32, q3 = grp + 48;
    float v0 = sPt[(q0 & 3) * 33 + lane] * regB[labs[361 + q0] * 33 + lane];
    float v1 = sPt[(q1 & 3) * 33 + lane] * regB[labs[361 + q1] * 33 + lane];
    float v2 = sPt[(q2 & 3) * 33 + lane] * regB[labs[361 + q2] * 33 + lane];
    float v3 = sPt[(q3 & 3) * 33 + lane] * regB[labs[361 + q3] * 33 + lane];
    float s0 = v0, s1 = v1, s2 = v2, s3 = v3;
    rsum32x4(s0, s1, s2, s3);
    scr[(q0 >> 2) * 128 + lane * 4 + (q0 & 3)] = v0 / s0;
    scr[(q1 >> 2) * 128 + lane * 4 + (q1 & 3)] = v1 / s1;
    scr[(q2 >> 2) * 128 + lane * 4 + (q2 & 3)] = v2 / s2;
    scr[(q3 >> 2) * 128 + lane * 4 + (q3 & 3)] = v3 / s3;
  }
  __syncthreads();
  if (grp < 8) {
    const int p0 = grp, p1 = grp + 8;
    float tb0, tb1;
    DOT128X2M(tb0, tb1, scr + p0 * 128, scr + p1 * 128)
    float bl0 = tb0 * regB[labs[345 + p0] * 33 + lane];
    float bl1 = tb1 * regB[labs[345 + p1] * 33 + lane];
    float s0 = bl0, s1 = bl1;
    rsum32x2(s0, s1);
    bl0 /= s0; bl1 /= s1;
    tbS[(5 + p0) * 32 + lane] = tb0;
    tbS[(5 + p1) * 32 + lane] = tb1;
    scr[2048 + (p0 >> 2) * 128 + lane * 4 + (p0 & 3)] = bl0;
    scr[2048 + (p1 >> 2) * 128 + lane * 4 + (p1 & 3)] = bl1;
  }
  __syncthreads();
  if (grp < 4) {
    float tb;
    DOT128M(tb, scr + 2048 + grp * 128)
    float bl = tb * regB[labs[341 + grp] * 33 + lane];
    bl /= rsum32(bl);
    tbS[(1 + grp) * 32 + lane] = tb;
    scr[2560 + lane * 4 + grp] = bl;
  }
  __syncthreads();
  if (grp == 0) {
    float tb;
    DOT128M(tb, scr + 2560)
    float bl = tb * regB[labs[85 + s] * 33 + lane];
    bl /= rsum32(bl);
    tbS[lane] = tb;
    ownb[lane] = bl;
  }
  __syncthreads();

#pragma unroll
  for (int h = 0; h < 2; ++h) {
    const int p0 = grp + 32 * h, p1 = p0 + 16;
    float* st0 = scr + grp * 128;
    float* st1 = scr + 2048 + grp * 128;
#pragma unroll
    for (int l = 0; l < 4; ++l) {
      st0[lane * 4 + l] = pf0[h * 4 + l];
      st1[lane * 4 + l] = pf1[h * 4 + l];
    }
    float tb0, tb1;
    DOT128X2M(tb0, tb1, st0, st1)
    float bl0 = tb0 * regB[labs[21 + p0] * 33 + lane];
    float bl1 = tb1 * regB[labs[21 + p1] * 33 + lane];
    float s0 = bl0, s1 = bl1;
    rsum32x2(s0, s1);
    bl0 /= s0; bl1 /= s1;
    tbrT[(21 + p0) * 32 + lane] = tb0;
    tbrT[(21 + p1) * 32 + lane] = tb1;
    scr[4096 + (p0 >> 2) * 128 + lane * 4 + (p0 & 3)] = bl0;
    scr[4096 + (p1 >> 2) * 128 + lane * 4 + (p1 & 3)] = bl1;
  }
  __syncthreads();
  {
    const int p = grp;
    float tb;
    DOT128M(tb, scr + 4096 + p * 128)
    float bl = tb * regB[labs[5 + p] * 33 + lane];
    bl /= rsum32(bl);
    tbrT[(5 + p) * 32 + lane] = tb;
    scr[(p >> 2) * 128 + lane * 4 + (p & 3)] = bl;
  }
  __syncthreads();
  if (grp < 4) {
    float tb;
    DOT128M(tb, scr + grp * 128)
    float bl = tb * regB[labs[1 + grp] * 33 + lane];
    bl /= rsum32(bl);
    tbrT[(1 + grp) * 32 + lane] = tb;
    scr[512 + lane * 4 + grp] = bl;
  }
  __syncthreads();
  if (grp == 0) { float tb; DOT128M(tb, scr + 512) tbrT[lane] = tb; }
  __syncthreads();

  for (int idx = t; idx < 4224; idx += 512) regB[idx] = __logf(regB[idx]);
  if (t < 132) sPt[t] = __logf(sPt[t]);
  REPW(WRD_B)
  __syncthreads();

  double ll = 0.0;
  float eps4own = 0.f;
  if (grp < 4) {
    const int n1 = 1 + (s >> 6), n2 = 5 + (s >> 4), n3 = 21 + (s >> 2);
    const int a0 = s >> 6, a1 = (s >> 4) & 3, a2 = (s >> 2) & 3, a3 = s & 3;
    float w[4], uv[4];
    float* rb = r_buf + grp * 32;

    float tbv = tbrT[lane];
    float bcv = tbv * __expf(regB[labs[0] * 33 + lane]);
    bcv /= rsum32(bcv);
    rb[lane] = bcv / tbv;
    if (grp == 0 && s == 0) {
      ll += (double)(bcv * regB[labs[0] * 33 + lane]);
      WU128M(w, uv, rb)
      const float lb0 = regB[labs[1] * 33 + lane], lb1 = regB[labs[2] * 33 + lane];
      const float lb2 = regB[labs[3] * 33 + lane], lb3 = regB[labs[4] * 33 + lane];
      float b0 = tbrT[1 * 32 + lane] * __expf(lb0);
      float b1 = tbrT[2 * 32 + lane] * __expf(lb1);
      float b2 = tbrT[3 * 32 + lane] * __expf(lb2);
      float b3 = tbrT[4 * 32 + lane] * __expf(lb3);
      float s0 = b0, s1 = b1, s2 = b2, s3 = b3;
      rsum32x4(s0, s1, s2, s3);
      b0 /= s0; b1 /= s1; b2 /= s2; b3 /= s3;
      ll += (double)(b0 * uv[0]) + (double)(b0 * w[0] * lb0);
      ll += (double)(b1 * uv[1]) + (double)(b1 * w[1] * lb1);
      ll += (double)(b2 * uv[2]) + (double)(b2 * w[2] * lb2);
      ll += (double)(b3 * uv[3]) + (double)(b3 * w[3] * lb3);
    } else {
      WONLY128M(w, rb)
    }

    tbv = tbrT[n1 * 32 + lane];
    bcv = tbv * __expf(regB[labs[n1] * 33 + lane]);
    bcv /= rsum32(bcv);
    rb[lane] = (bcv * w[a0]) / tbv;
    if (grp == 1 && (s & 63) == 0) {
      WU128M(w, uv, rb)
      const int cb = 5 + 4 * (s >> 6);
      const float lb0 = regB[labs[cb + 0] * 33 + lane], lb1 = regB[labs[cb + 1] * 33 + lane];
      const float lb2 = regB[labs[cb + 2] * 33 + lane], lb3 = regB[labs[cb + 3] * 33 + lane];
      float b0 = tbrT[(cb + 0) * 32 + lane] * __expf(lb0);
      float b1 = tbrT[(cb + 1) * 32 + lane] * __expf(lb1);
      float b2 = tbrT[(cb + 2) * 32 + lane] * __expf(lb2);
      float b3 = tbrT[(cb + 3) * 32 + lane] * __expf(lb3);
      float s0 = b0, s1 = b1, s2 = b2, s3 = b3;
      rsum32x4(s0, s1, s2, s3);
      b0 /= s0; b1 /= s1; b2 /= s2; b3 /= s3;
      ll += (double)(b0 * uv[0]) + (double)(b0 * w[0] * lb0);
      ll += (double)(b1 * uv[1]) + (double)(b1 * w[1] * lb1);
      ll += (double)(b2 * uv[2]) + (double)(b2 * w[2] * lb2);
      ll += (double)(b3 * uv[3]) + (double)(b3 * w[3] * lb3);
    } else {
      WONLY128M(w, rb)
    }

    tbv = tbrT[n2 * 32 + lane];
    bcv = tbv * __expf(regB[labs[n2] * 33 + lane]);
    bcv /= rsum32(bcv);
    rb[lane] = (bcv * w[a1]) / tbv;
    if (grp == 2 && (s & 15) == 0) {
      WU128M(w, uv, rb)
      const int cb = 21 + 4 * (s >> 4);
      const float lb0 = regB[labs[cb + 0] * 33 + lane], lb1 = regB[labs[cb + 1] * 33 + lane];
      const float lb2 = regB[labs[cb + 2] * 33 + lane], lb3 = regB[labs[cb + 3] * 33 + lane];
      float b0 = tbrT[(cb + 0) * 32 + lane] * __expf(lb0);
      float b1 = tbrT[(cb + 1) * 32 + lane] * __expf(lb1);
      float b2 = tbrT[(cb + 2) * 32 + lane] * __expf(lb2);
      float b3 = tbrT[(cb + 3) * 32 + lane] * __expf(lb3);
      float s0 = b0, s1 = b1, s2 = b2, s3 = b3;
      rsum32x4(s0, s1, s2, s3);
      b0 /= s0; b1 /= s1; b2 /= s2; b3 /= s3;
      ll += (double)(b0 * uv[0]) + (double)(b0 * w[0] * lb0);
      ll += (double)(b1 * uv[1]) + (double)(b1 * w[1] * lb1);
      ll += (double)(b2 * uv[2]) + (double)(b2 * w[2] * lb2);
      ll += (double)(b3 * uv[3]) + (double)(b3 * w[3] * lb3);
    } else {
      WONLY128M(w, rb)
    }

    tbv = tbrT[n3 * 32 + lane];
    bcv = tbv * __expf(regB[labs[n3] * 33 + lane]);
    bcv /= rsum32(bcv);
    rb[lane] = (bcv * w[a2]) / tbv;
    if (grp == 3 && (s & 3) == 0) {
      WU128M(w, uv, rb)
      const int cb = s & ~3;
#pragma unroll
      for (int l = 0; l < 4; ++l) {
        const int ci = cb + l;
        const float bc = ws[OFF_B4 + ci * 32 + lane];
        const float e = bc * w[l];
        ll += (double)(bc * uv[l]) + (double)(e * regB[labs[85 + ci] * 33 + lane]);
      }
    } else {
      WONLY128M(w, rb)
    }
    eps4own = ownb[lane] * w[a3];
  }
  __syncthreads();

  if (grp == 0) {
    r_buf[lane] = eps4own / tbS[lane];
    float w[4], u[4];
    WU128M(w, u, r_buf)
#pragma unroll
    for (int l = 0; l < 4; ++l) {
      const int lab = labs[341 + l];
      const float tbv = tbS[(1 + l) * 32 + lane];
      float bcv = tbv * __expf(regB[lab * 33 + lane]);
      bcv /= rsum32(bcv);
      const float e = bcv * w[l];
      ll += (double)(bcv * u[l]) + (double)(e * regB[lab * 33 + lane]);
      tbS[(1 + l) * 32 + lane] = e / tbv;
    }
  }
  __syncthreads();
  if (grp < 4) {
    const int p = grp;
    r_buf[p * 32 + lane] = tbS[(1 + p) * 32 + lane];
    float w[4], u[4];
    WU128M(w, u, r_buf + p * 32)
#pragma unroll
    for (int l = 0; l < 4; ++l) {
      const int q = p * 4 + l;
      const int lab = labs[345 + q];
      const float tbv = tbS[(5 + q) * 32 + lane];
      float bcv = tbv * __expf(regB[lab * 33 + lane]);
      bcv /= rsum32(bcv);
      const float e = bcv * w[l];
      ll += (double)(bcv * u[l]) + (double)(e * regB[lab * 33 + lane]);
      tbS[(5 + q) * 32 + lane] = e / tbv;
    }
  }
  __syncthreads();
  if (grp < 8) {
    const int p0 = grp, p1 = grp + 8;
    float* rb0 = r_buf + grp * 32;
    float* rb1 = r_buf + 256 + grp * 32;
    rb0[lane] = tbS[(5 + p0) * 32 + lane];
    rb1[lane] = tbS[(5 + p1) * 32 + lane];
    float w0[4], u0[4], w1[4], u1[4];
    WU128X2M(w0, u0, w1, u1, rb0, rb1)
#pragma unroll
    for (int l = 0; l < 4; ++l) {
      const int q0 = p0 * 4 + l, q1 = p1 * 4 + l;
      const float lb0 = regB[labs[361 + q0] * 33 + lane];
      const float lb1 = regB[labs[361 + q1] * 33 + lane];
      const float lp = sPt[l * 33 + lane];
      float b0 = __expf(lp + lb0);
      float b1 = __expf(lp + lb1);
      float s0 = b0, s1 = b1;
      rsum32x2(s0, s1);
      b0 /= s0; b1 /= s1;
      const float e0 = b0 * w0[l], e1 = b1 * w1[l];
      ll += (double)(b0 * u0[l]) + (double)(e0 * lb0) + (double)(e0 * lp);
      ll += (double)(b1 * u1[l]) + (double)(e1 * lb1) + (double)(e1 * lp);
    }
  }

#pragma unroll
  for (int k = 32; k >= 1; k >>= 1) ll += __shfl_xor(ll, k);
  double* rbd = (double*)r_buf;
  __syncthreads();
  if ((t & 63) == 0) rbd[t >> 6] = ll;
  __syncthreads();
  if (t == 0) {
    partd[s] = ((rbd[0] + rbd[1]) + (rbd[2] + rbd[3])) +
               ((rbd[4] + rbd[5]) + (rbd[6] + rbd[7]));
    __threadfence();
    int f = 0;
    if (atomicAdd(&wsi[IC2 + 32 * (s >> 4)], 1) == 15)
      if (atomicAdd(&wsi[IROOT2], 1) == 15) f = 1;
    fin = f;
  }
  __syncthreads();
  if (fin) {
    __threadfence();
    if (t < 64) {
      double v = 0.0;
      for (int k = t; k < 256; k += 64) v += partd[k];
#pragma unroll
      for (int k = 32; k >= 1; k >>= 1) v += __shfl_xor(v, k);
      if (t == 0) out[0] = (float)v;
    }
  }
}

// ======================================================================
// ================= PERSIST PATH (R19 design, fixed) ===================
// ======================================================================
__global__ __launch_bounds__(512, 1) void k_up_p(const int* __restrict__ labels,
                                                 const float* __restrict__ A,
                                                 const float* __restrict__ B,
                                                 const float* __restrict__ Pi,
                                                 const float* __restrict__ SP,
                                                 float* __restrict__ ws) {
  __shared__ __align__(16) float scr[4224];
  __shared__ __align__(16) float regB[4224];
  __shared__ __align__(16) float sPt[132];
  __shared__ int labs[425];
  const int t = threadIdx.x, lane = t & 31, grp = t >> 5;  // 16 groups
  const int s = blockIdx.x;
  int* wsi = (int*)ws;
  const float4* A4 = (const float4*)A;
  const float4* B4 = (const float4*)B;

  if (t < 16) wsi[IC2 + 32 * t] = 0;
  else if (t == 16) wsi[IROOT2] = 0;

  const float sv0 = SP[0], sv1 = SP[1], sv2 = SP[2], sv3 = SP[3];
  const float sp0 = __expf(sv0), sp1 = __expf(sv1), sp2 = __expf(sv2), sp3 = __expf(sv3);
  const float spsum = sp0 + sp1 + sp2 + sp3;
  const float spinv = 1.f / spsum;
  const float lss = __logf(spsum);
  float4 c4 = make_float4(0.f, 0.f, 0.f, 0.f);
  for (int i = 0; i < 32; ++i) {
    const float4 e = exp4f(A4[i * 32 + lane]);
    c4.x += e.x; c4.y += e.y; c4.z += e.z; c4.w += e.w;
  }
  const float4 inv4 = make_float4(sp0 * spinv / c4.x, sp1 * spinv / c4.y,
                                  sp2 * spinv / c4.z, sp3 * spinv / c4.w);
  const float4 sub4 = make_float4(__logf(c4.x) - (sv0 - lss), __logf(c4.y) - (sv1 - lss),
                                  __logf(c4.z) - (sv2 - lss), __logf(c4.w) - (sv3 - lss));
#pragma unroll
  for (int k = 0; k < 2; ++k) {
    const int i = grp * 2 + k;
    const float4 e = exp4f(A4[i * 32 + lane]);
    *(float4*)(scr + i * 132 + 4 * lane) =
        make_float4(e.x * inv4.x, e.y * inv4.y, e.z * inv4.z, e.w * inv4.w);
  }
#pragma unroll
  for (int rI = 0; rI < 2; ++rI) {
    const int i = grp + rI * 16;
    const float4 e = exp4f(B4[i * 32 + lane]);
    const float sinv = 1.f / rsum32(e.x + e.y + e.z + e.w);
    regB[(4 * lane + 0) * 33 + i] = e.x * sinv;
    regB[(4 * lane + 1) * 33 + i] = e.y * sinv;
    regB[(4 * lane + 2) * 33 + i] = e.z * sinv;
    regB[(4 * lane + 3) * 33 + i] = e.w * sinv;
  }
  if (grp < 4) {
    const float e = __expf(Pi[lane * 4 + grp]);
    sPt[grp * 33 + lane] = e / rsum32(e);
  } else if (grp == 4) {  // fill the 4 gap slots so persisted logs are finite
    if (lane < 4) sPt[lane * 33 + 32] = 1.f;
  }
  if (t < 84) {
    int g, d;
    if (t < 4) { g = 341 + 4 * s + t; d = 341 + t; }
    else if (t < 20) { g = 1365 + 16 * s + (t - 4); d = 345 + (t - 4); }
    else { g = 5461 + 64 * s + (t - 20); d = 361 + (t - 20); }
    labs[d] = labels[g];
  }
  if (t == 84) labs[85 + (s & 255)] = labels[85 + s];
  __syncthreads();

  // ---------- block 0: persist block-independent tables ----------
  if (s == 0) {
    for (int idx = t; idx < 4224; idx += 512) {
      ws[OFF_ASP + idx] = scr[idx];
      const float v = regB[idx];
      ws[OFF_RB + idx] = v;
      ws[OFF_LRB + idx] = __logf(v);
    }
    if (t < 132) ws[OFF_LSP + t] = __logf(sPt[t]);
#pragma unroll
    for (int k = 0; k < 2; ++k) {
      const int i = grp * 2 + k;
      const float4 av = A4[i * 32 + lane];
      const float4 e = exp4f(av);
      const float4 asp = make_float4(e.x * inv4.x, e.y * inv4.y,
                                     e.z * inv4.z, e.w * inv4.w);
      *(float4*)(ws + OFF_ALG + i * 128 + lane * 4) =
          make_float4(asp.x * (av.x - sub4.x), asp.y * (av.y - sub4.y),
                      asp.z * (av.z - sub4.z), asp.w * (av.w - sub4.w));
    }
  }
  W_DECL
  W_LOADUP
  __syncthreads();

  // ---------- phase 2: subtree up sweep; persist tbS rows + b4 ----------
  float* tbs = ws + OFF_TBO + s * 672;
  {
    const int q0 = grp, q1 = grp + 16, q2 = grp + 32, q3 = grp + 48;
    float v0 = sPt[(q0 & 3) * 33 + lane] * regB[labs[361 + q0] * 33 + lane];
    float v1 = sPt[(q1 & 3) * 33 + lane] * regB[labs[361 + q1] * 33 + lane];
    float v2 = sPt[(q2 & 3) * 33 + lane] * regB[labs[361 + q2] * 33 + lane];
    float v3 = sPt[(q3 & 3) * 33 + lane] * regB[labs[361 + q3] * 33 + lane];
    float s0 = v0, s1 = v1, s2 = v2, s3 = v3;
    rsum32x4(s0, s1, s2, s3);
    scr[(q0 >> 2) * 128 + lane * 4 + (q0 & 3)] = v0 / s0;
    scr[(q1 >> 2) * 128 + lane * 4 + (q1 & 3)] = v1 / s1;
    scr[(q2 >> 2) * 128 + lane * 4 + (q2 & 3)] = v2 / s2;
    scr[(q3 >> 2) * 128 + lane * 4 + (q3 & 3)] = v3 / s3;
  }
  __syncthreads();
  if (grp < 8) {
    const int p0 = grp, p1 = grp + 8;
    float tb0, tb1;
    DOT128X2M(tb0, tb1, scr + p0 * 128, scr + p1 * 128)
    float bl0 = tb0 * regB[labs[345 + p0] * 33 + lane];
    float bl1 = tb1 * regB[labs[345 + p1] * 33 + lane];
    float s0 = bl0, s1 = bl1;
    rsum32x2(s0, s1);
    bl0 /= s0; bl1 /= s1;
    tbs[(5 + p0) * 32 + lane] = tb0;
    tbs[(5 + p1) * 32 + lane] = tb1;
    scr[2048 + (p0 >> 2) * 128 + lane * 4 + (p0 & 3)] = bl0;
    scr[2048 + (p1 >> 2) * 128 + lane * 4 + (p1 & 3)] = bl1;
  }
  __syncthreads();
  if (grp < 4) {
    float tb;
    DOT128M(tb, scr + 2048 + grp * 128)
    float bl = tb * regB[labs[341 + grp] * 33 + lane];
    bl /= rsum32(bl);
    tbs[(1 + grp) * 32 + lane] = tb;
    scr[2560 + lane * 4 + grp] = bl;
  }
  __syncthreads();
  if (grp == 0) {
    float tb;
    DOT128M(tb, scr + 2560)
    float bl = tb * regB[labs[85 + (s & 255)] * 33 + lane];
    bl /= rsum32(bl);
    tbs[lane] = tb;
    ws[OFF_B4 + s * 32 + lane] = bl;
  }
}

__global__ __launch_bounds__(512, 1)
void k_down_p(const int* __restrict__ labels,
              const float* __restrict__ ws_c,
              float* __restrict__ ws,
              float* __restrict__ out) {
  __shared__ __align__(16) float scr[6144];
  __shared__ __align__(16) float regB[4224];
  __shared__ __align__(16) float sPt[132];
  __shared__ __align__(16) float tbrT[2720];
  __shared__ __align__(16) float tbS[672];
  __shared__ __align__(16) float ownb[32];
  __shared__ __align__(16) float r_buf[512];
  __shared__ int labs[425];
  __shared__ int fin;
  const int t = threadIdx.x, lane = t & 31, grp = t >> 5;  // 16 groups
  const int s = blockIdx.x;
  int* wsi = (int*)ws;
  double* partd = (double*)(ws + OFF_PART);
  (void)ws_c;

  // ---------- P3 b4 prefetch (issue early) ----------
  float pf0[8], pf1[8];
#pragma unroll
  for (int h = 0; h < 2; ++h) {
    const int p0 = grp + 32 * h, p1 = p0 + 16;
#pragma unroll
    for (int l = 0; l < 4; ++l) {
      pf0[h * 4 + l] = ws[OFF_B4 + (p0 * 4 + l) * 32 + lane];
      pf1[h * 4 + l] = ws[OFF_B4 + (p1 * 4 + l) * 32 + lane];
    }
  }

  // ---------- stage tables + per-block state from ws (strided loops!) ----
  for (int idx = t; idx < 4224; idx += 512) scr[idx] = ws[OFF_ASP + idx];
  for (int idx = t; idx < 4224; idx += 512) regB[idx] = ws[OFF_RB + idx];
  if (t < 132) sPt[t] = ws[OFF_LSP + t];             // log sPt
  for (int idx = t; idx < 672; idx += 512) tbS[idx] = ws[OFF_TBO + s * 672 + idx];
  if (t < 32) ownb[t] = ws[OFF_B4 + s * 32 + t];
  for (int idx = t; idx < 341; idx += 512) labs[idx] = labels[idx];
  if (t < 84) {
    int g, d;
    if (t < 4) { g = 341 + 4 * s + t; d = 341 + t; }
    else if (t < 20) { g = 1365 + 16 * s + (t - 4); d = 345 + (t - 4); }
    else { g = 5461 + 64 * s + (t - 20); d = 361 + (t - 20); }
    labs[d] = labels[g];
  }
  __syncthreads();
  W_DECL
  W_LOADUP
  __syncthreads();

  // ---------- phase 3: top up sweep (redundant per block) ----------
#pragma unroll
  for (int h = 0; h < 2; ++h) {
    const int p0 = grp + 32 * h, p1 = p0 + 16;
    float* st0 = scr + grp * 128;
    float* st1 = scr + 2048 + grp * 128;
#pragma unroll
    for (int l = 0; l < 4; ++l) {
      st0[lane * 4 + l] = pf0[h * 4 + l];
      st1[lane * 4 + l] = pf1[h * 4 + l];
    }
    float tb0, tb1;
    DOT128X2M(tb0, tb1, st0, st1)
    float bl0 = tb0 * regB[labs[21 + p0] * 33 + lane];
    float bl1 = tb1 * regB[labs[21 + p1] * 33 + lane];
    float s0 = bl0, s1 = bl1;
    rsum32x2(s0, s1);
    bl0 /= s0; bl1 /= s1;
    tbrT[(21 + p0) * 32 + lane] = tb0;
    tbrT[(21 + p1) * 32 + lane] = tb1;
    scr[4096 + (p0 >> 2) * 128 + lane * 4 + (p0 & 3)] = bl0;
    scr[4096 + (p1 >> 2) * 128 + lane * 4 + (p1 & 3)] = bl1;
  }
  __syncthreads();
  {
    const int p = grp;
    float tb;
    DOT128M(tb, scr + 4096 + p * 128)
    float bl = tb * regB[labs[5 + p] * 33 + lane];
    bl /= rsum32(bl);
    tbrT[(5 + p) * 32 + lane] = tb;
    scr[(p >> 2) * 128 + lane * 4 + (p & 3)] = bl;
  }
  __syncthreads();
  if (grp < 4) {
    float tb;
    DOT128M(tb, scr + grp * 128)
    float bl = tb * regB[labs[1 + grp] * 33 + lane];
    bl /= rsum32(bl);
    tbrT[(1 + grp) * 32 + lane] = tb;
    scr[512 + lane * 4 + grp] = bl;
  }
  __syncthreads();
  if (grp == 0) { float tb; DOT128M(tb, scr + 512) tbrT[lane] = tb; }
  __syncthreads();

  // ---------- phase 4 (slim): stage ALG + logB; W-down from asp table ----
  for (int idx = t; idx < 4096; idx += 512) scr[idx] = ws[OFF_ALG + idx];
  for (int idx = t; idx < 4224; idx += 512) regB[idx] = ws[OFF_LRB + idx];
  if (grp < 8) {
    const float* wsASP_ = ws + OFF_ASP;
    REPW(WLDDN_B)
  }
  __syncthreads();

  // ---------- phase 5: top down, DISTRIBUTED owners ----------
  double ll = 0.0;
  float eps4own = 0.f;
  if (grp < 4) {
    const int n1 = 1 + (s >> 6), n2 = 5 + (s >> 4), n3 = 21 + (s >> 2);
    const int a0 = s >> 6, a1 = (s >> 4) & 3, a2 = (s >> 2) & 3, a3 = s & 3;
    float w[4], uv[4];
    float* rb = r_buf + grp * 32;

    float tbv = tbrT[lane];
    float bcv = tbv * __expf(regB[labs[0] * 33 + lane]);
    bcv /= rsum32(bcv);
    rb[lane] = bcv / tbv;
    if (grp == 0 && s == 0) {
      ll += (double)(bcv * regB[labs[0] * 33 + lane]);
      WU128M(w, uv, rb)
      const float lb0 = regB[labs[1] * 33 + lane], lb1 = regB[labs[2] * 33 + lane];
      const float lb2 = regB[labs[3] * 33 + lane], lb3 = regB[labs[4] * 33 + lane];
      float b0 = tbrT[1 * 32 + lane] * __expf(lb0);
      float b1 = tbrT[2 * 32 + lane] * __expf(lb1);
      float b2 = tbrT[3 * 32 + lane] * __expf(lb2);
      float b3 = tbrT[4 * 32 + lane] * __expf(lb3);
      float s0 = b0, s1 = b1, s2 = b2, s3 = b3;
      rsum32x4(s0, s1, s2, s3);
      b0 /= s0; b1 /= s1; b2 /= s2; b3 /= s3;
      ll += (double)(b0 * uv[0]) + (double)(b0 * w[0] * lb0);
      ll += (double)(b1 * uv[1]) + (double)(b1 * w[1] * lb1);
      ll += (double)(b2 * uv[2]) + (double)(b2 * w[2] * lb2);
      ll += (double)(b3 * uv[3]) + (double)(b3 * w[3] * lb3);
    } else {
      WONLY128M(w, rb)
    }

    tbv = tbrT[n1 * 32 + lane];
    bcv = tbv * __expf(regB[labs[n1] * 33 + lane]);
    bcv /= rsum32(bcv);
    rb[lane] = (bcv * w[a0]) / tbv;
    if (grp == 1 && (s & 63) == 0) {
      WU128M(w, uv, rb)
      const int cb = 5 + 4 * (s >> 6);
      const float lb0 = regB[labs[cb + 0] * 33 + lane], lb1 = regB[labs[cb + 1] * 33 + lane];
      const float lb2 = regB[labs[cb + 2] * 33 + lane], lb3 = regB[labs[cb + 3] * 33 + lane];
      float b0 = tbrT[(cb + 0) * 32 + lane] * __expf(lb0);
      float b1 = tbrT[(cb + 1) * 32 + lane] * __expf(lb1);
      float b2 = tbrT[(cb + 2) * 32 + lane] * __expf(lb2);
      float b3 = tbrT[(cb + 3) * 32 + lane] * __expf(lb3);
      float s0 = b0, s1 = b1, s2 = b2, s3 = b3;
      rsum32x4(s0, s1, s2, s3);
      b0 /= s0; b1 /= s1; b2 /= s2; b3 /= s3;
      ll += (double)(b0 * uv[0]) + (double)(b0 * w[0] * lb0);
      ll += (double)(b1 * uv[1]) + (double)(b1 * w[1] * lb1);
      ll += (double)(b2 * uv[2]) + (double)(b2 * w[2] * lb2);
      ll += (double)(b3 * uv[3]) + (double)(b3 * w[3] * lb3);
    } else {
      WONLY128M(w, rb)
    }

    tbv = tbrT[n2 * 32 + lane];
    bcv = tbv * __expf(regB[labs[n2] * 33 + lane]);
    bcv /= rsum32(bcv);
    rb[lane] = (bcv * w[a1]) / tbv;
    if (grp == 2 && (s & 15) == 0) {
      WU128M(w, uv, rb)
      const int cb = 21 + 4 * (s >> 4);
      const float lb0 = regB[labs[cb + 0] * 33 + lane], lb1 = regB[labs[cb + 1] * 33 + lane];
      const float lb2 = regB[labs[cb + 2] * 33 + lane], lb3 = regB[labs[cb + 3] * 33 + lane];
      float b0 = tbrT[(cb + 0) * 32 + lane] * __expf(lb0);
      float b1 = tbrT[(cb + 1) * 32 + lane] * __expf(lb1);
      float b2 = tbrT[(cb + 2) * 32 + lane] * __expf(lb2);
      float b3 = tbrT[(cb + 3) * 32 + lane] * __expf(lb3);
      float s0 = b0, s1 = b1, s2 = b2, s3 = b3;
      rsum32x4(s0, s1, s2, s3);
      b0 /= s0; b1 /= s1; b2 /= s2; b3 /= s3;
      ll += (double)(b0 * uv[0]) + (double)(b0 * w[0] * lb0);
      ll += (double)(b1 * uv[1]) + (double)(b1 * w[1] * lb1);
      ll += (double)(b2 * uv[2]) + (double)(b2 * w[2] * lb2);
      ll += (double)(b3 * uv[3]) + (double)(b3 * w[3] * lb3);
    } else {
      WONLY128M(w, rb)
    }

    tbv = tbrT[n3 * 32 + lane];
    bcv = tbv * __expf(regB[labs[n3] * 33 + lane]);
    bcv /= rsum32(bcv);
    rb[lane] = (bcv * w[a2]) / tbv;
    if (grp == 3 && (s & 3) == 0) {
      WU128M(w, uv, rb)
      const int cb = s & ~3;
#pragma unroll
      for (int l = 0; l < 4; ++l) {
        const int ci = cb + l;
        const float bc = ws[OFF_B4 + ci * 32 + lane];
        const float e = bc * w[l];
        ll += (double)(bc * uv[l]) + (double)(e * regB[labs[85 + ci] * 33 + lane]);
      }
    } else {
      WONLY128M(w, rb)
    }
    eps4own = ownb[lane] * w[a3];
  }
  __syncthreads();

  // ---------- phase 6: subtree down sweep ----------
  if (grp == 0) {
    r_buf[lane] = eps4own / tbS[lane];
    float w[4], u[4];
    WU128M(w, u, r_buf)
#pragma unroll
    for (int l = 0; l < 4; ++l) {
      const int lab = labs[341 + l];
      const float tbv = tbS[(1 + l) * 32 + lane];
      float bcv = tbv * __expf(regB[lab * 33 + lane]);
      bcv /= rsum32(bcv);
      const float e = bcv * w[l];
      ll += (double)(bcv * u[l]) + (double)(e * regB[lab * 33 + lane]);
      tbS[(1 + l) * 32 + lane] = e / tbv;
    }
  }
  __syncthreads();
  if (grp < 4) {
    const int p = grp;
    r_buf[p * 32 + lane] = tbS[(1 + p) * 32 + lane];
    float w[4], u[4];
    WU128M(w, u, r_buf + p * 32)
#pragma unroll
    for (int l = 0; l < 4; ++l) {
      const int q = p * 4 + l;
      const int lab = labs[345 + q];
      const float tbv = tbS[(5 + q) * 32 + lane];
      float bcv = tbv * __expf(regB[lab * 33 + lane]);
      bcv /= rsum32(bcv);
      const float e = bcv * w[l];
      ll += (double)(bcv * u[l]) + (double)(e * regB[lab * 33 + lane]);
      tbS[(5 + q) * 32 + lane] = e / tbv;
    }
  }
  __syncthreads();
  if (grp < 8) {
    const int p0 = grp, p1 = grp + 8;
    float* rb0 = r_buf + grp * 32;
    float* rb1 = r_buf + 256 + grp * 32;
    rb0[lane] = tbS[(5 + p0) * 32 + lane];
    rb1[lane] = tbS[(5 + p1) * 32 + lane];
    float w0[4], u0[4], w1[4], u1[4];
    WU128X2M(w0, u0, w1, u1, rb0, rb1)
#pragma unroll
    for (int l = 0; l < 4; ++l) {
      const int q0 = p0 * 4 + l, q1 = p1 * 4 + l;
      const float lb0 = regB[labs[361 + q0] * 33 + lane];
      const float lb1 = regB[labs[361 + q1] * 33 + lane];
      const float lp = sPt[l * 33 + lane];
      float b0 = __expf(lp + lb0);
      float b1 = __expf(lp + lb1);
      float s0 = b0, s1 = b1;
      rsum32x2(s0, s1);
      b0 /= s0; b1 /= s1;
      const float e0 = b0 * w0[l], e1 = b1 * w1[l];
      ll += (double)(b0 * u0[l]) + (double)(e0 * lb0) + (double)(e0 * lp);
      ll += (double)(b1 * u1[l]) + (double)(e1 * lb1) + (double)(e1 * lp);
    }
  }

  // ---------- phase 7: partials + tree finalize ----------
#pragma unroll
  for (int k = 32; k >= 1; k >>= 1) ll += __shfl_xor(ll, k);
  double* rbd = (double*)r_buf;
  __syncthreads();
  if ((t & 63) == 0) rbd[t >> 6] = ll;
  __syncthreads();
  if (t == 0) {
    partd[s] = ((rbd[0] + rbd[1]) + (rbd[2] + rbd[3])) +
               ((rbd[4] + rbd[5]) + (rbd[6] + rbd[7]));
    __threadfence();
    int f = 0;
    if (atomicAdd(&wsi[IC2 + 32 * (s >> 4)], 1) == 15)
      if (atomicAdd(&wsi[IROOT2], 1) == 15) f = 1;
    fin = f;
  }
  __syncthreads();
  if (fin) {
    __threadfence();
    if (t < 64) {
      double v = 0.0;
      for (int k = t; k < 256; k += 64) v += partd[k];
#pragma unroll
      for (int k = 32; k >= 1; k >>= 1) v += __shfl_xor(v, k);
      if (t == 0) out[0] = (float)v;
    }
  }
}

extern "C" void kernel_launch(void* const* d_in, const int* in_sizes, int n_in,
                              void* d_out, int out_size, void* d_ws, size_t ws_size,
                              hipStream_t stream) {
  (void)in_sizes; (void)n_in; (void)out_size;
  const int* labels = (const int*)d_in[0];
  const float* A = (const float*)d_in[1];
  const float* B = (const float*)d_in[2];
  const float* Pi = (const float*)d_in[3];
  const float* SP = (const float*)d_in[4];
  float* ws = (float*)d_ws;
  float* out = (float*)d_out;

  // ws_size is constant across calls -> host branch is graph-capture-safe.
  if (ws_size >= WS_NEED_BYTES) {
    hipLaunchKernelGGL(k_up_p, dim3(256), dim3(512), 0, stream,
                       labels, A, B, Pi, SP, ws);
    hipLaunchKernelGGL(k_down_p, dim3(256), dim3(512), 0, stream,
                       labels, ws, ws, out);
  } else {
    hipLaunchKernelGGL(k_up_f, dim3(256), dim3(256), 0, stream,
                       labels, A, B, Pi, SP, ws);
    hipLaunchKernelGGL(k_down_f, dim3(256), dim3(512), 0, stream,
                       labels, A, B, Pi, SP, ws, out);
  }
}

// Round 9
// 100.437 us; speedup vs baseline: 1.4242x; 1.0514x over previous
//
#include <hip/hip_runtime.h>

// HTMM: C=32 states, L=4 fanout, M=128 symbols, DEPTH=7.
// Level starts: {0,1,5,21,85,341,1365,5461,21845}.
// R21 = R20 with three BITWISE-PRESERVING latency cuts (persist path only).
// R20 post-mortem: (1) persist path bought ~1us => k_down is latency-bound
// on its serial 11-stage dot chain, not work-bound. (2) top-5 dispatches are
// __amd_rocclr_fillBufferAligned: harness reset() fills the 268MB workspace
// (~40us @6.7TB/s) INSIDE the timed region every iteration -- the constant
// ~55us "overhead" = fill(40) + memsets/gaps(~15). Kernel envelope ~50us.
// R21 changes: (a) k_down_p prefetches P4's ALG+logB staging into registers
// at kernel start (5 float4/thread) -- hides the mid-chain cross-XCD L3
// stall under P3; (b) k_down_p d2 widened 8grp-X2 -> 16grp-X1 (waves 4-7
// were idle; per-parent FMA order identical => bitwise same, ll reorder
// absorbed by double accum); (c) k_up_p S2 same widening. absmax stays 0.

static constexpr int OFF_B4   = 0;      // level-4 betas [s*32+i] (8192 f)
static constexpr int OFF_PART = 8192;   // 256 doubles (512 f)
static constexpr int IC2      = 9760;   // 16 finalize counters, stride 32 ints
static constexpr int IROOT2   = 10272;  // finalize root counter
static constexpr int OFF_ASP  = 10304;  // asp, stride-132 layout (4224 f)
static constexpr int OFF_RB   = 14528;  // smB^T linear (4224 f)
static constexpr int OFF_LRB  = 18752;  // log smB^T (4224 f)
static constexpr int OFF_LSP  = 22976;  // log sPt (132 f, +pad)
static constexpr int OFF_ALG  = 23120;  // ALG rows [J*128+lane*4] (4096 f)
static constexpr int OFF_TBO  = 27216;  // per-block tbS, stride 672 (172032 f)
static constexpr size_t WS_NEED_BYTES = (size_t)(OFF_TBO + 256 * 672) * 4;

__device__ __forceinline__ float rsum32(float v) {
#pragma unroll
  for (int k = 1; k <= 16; k <<= 1) v += __shfl_xor(v, k);
  return v;
}
__device__ __forceinline__ void rsum32x2(float& a, float& b) {
#pragma unroll
  for (int k = 1; k <= 16; k <<= 1) { a += __shfl_xor(a, k); b += __shfl_xor(b, k); }
}
__device__ __forceinline__ void rsum32x4(float& a, float& b, float& c, float& d) {
#pragma unroll
  for (int k = 1; k <= 16; k <<= 1) {
    a += __shfl_xor(a, k); b += __shfl_xor(b, k);
    c += __shfl_xor(c, k); d += __shfl_xor(d, k);
  }
}
__device__ __forceinline__ float4 exp4f(float4 v) {
  return make_float4(__expf(v.x), __expf(v.y), __expf(v.z), __expf(v.w));
}

// ---------------- register-file W matrix: 32 named float4 ----------------
#define W_DECL float4 Wr0, Wr1, Wr2, Wr3, Wr4, Wr5, Wr6, Wr7, Wr8, Wr9,     \
    Wr10, Wr11, Wr12, Wr13, Wr14, Wr15, Wr16, Wr17, Wr18, Wr19, Wr20, Wr21, \
    Wr22, Wr23, Wr24, Wr25, Wr26, Wr27, Wr28, Wr29, Wr30, Wr31;

#define REPW(X) X(0,Wr0) X(1,Wr1) X(2,Wr2) X(3,Wr3) X(4,Wr4) X(5,Wr5)       \
    X(6,Wr6) X(7,Wr7) X(8,Wr8) X(9,Wr9) X(10,Wr10) X(11,Wr11) X(12,Wr12)    \
    X(13,Wr13) X(14,Wr14) X(15,Wr15) X(16,Wr16) X(17,Wr17) X(18,Wr18)       \
    X(19,Wr19) X(20,Wr20) X(21,Wr21) X(22,Wr22) X(23,Wr23) X(24,Wr24)       \
    X(25,Wr25) X(26,Wr26) X(27,Wr27) X(28,Wr28) X(29,Wr29) X(30,Wr30)       \
    X(31,Wr31)

#define REPQ(X) X(0,Wr0,Wr1,Wr2,Wr3) X(1,Wr4,Wr5,Wr6,Wr7)                   \
    X(2,Wr8,Wr9,Wr10,Wr11) X(3,Wr12,Wr13,Wr14,Wr15) X(4,Wr16,Wr17,Wr18,Wr19)\
    X(5,Wr20,Wr21,Wr22,Wr23) X(6,Wr24,Wr25,Wr26,Wr27) X(7,Wr28,Wr29,Wr30,Wr31)

// load up-orientation row (lane) from scr (stride 132)
#define WLD_B(J, WJ) WJ = *(const float4*)(scrW_ + 4 * (J));
#define W_LOADUP { const float* scrW_ = scr + lane * 132; REPW(WLD_B) }

// load down-orientation from persisted asp table in ws (row J, cols 4lane..)
#define WLDDN_B(J, WJ) WJ = *(const float4*)(wsASP_ + (J) * 132 + lane * 4);

// tb = dot(W_row_lane, X[0..127])
#define DOT_B(J, WJ) { const float4 x_ = *(const float4*)(dXp_ + 4 * (J));   \
    dt0_ = fmaf(WJ.x, x_.x, dt0_); dt1_ = fmaf(WJ.y, x_.y, dt1_);            \
    dt2_ = fmaf(WJ.z, x_.z, dt2_); dt3_ = fmaf(WJ.w, x_.w, dt3_); }
#define DOT128M(OUT, XP) { const float* dXp_ = (XP);                         \
    float dt0_ = 0.f, dt1_ = 0.f, dt2_ = 0.f, dt3_ = 0.f;                    \
    REPW(DOT_B) (OUT) = (dt0_ + dt1_) + (dt2_ + dt3_); }

// two parents, shared W row
#define DOTX2_B(J, WJ) {                                                     \
    const float4 x_ = *(const float4*)(dXp0_ + 4 * (J));                     \
    const float4 y_ = *(const float4*)(dXp1_ + 4 * (J));                     \
    da0_ = fmaf(WJ.x, x_.x, da0_); db0_ = fmaf(WJ.x, y_.x, db0_);            \
    da1_ = fmaf(WJ.y, x_.y, da1_); db1_ = fmaf(WJ.y, y_.y, db1_);            \
    da2_ = fmaf(WJ.z, x_.z, da2_); db2_ = fmaf(WJ.z, y_.z, db2_);            \
    da3_ = fmaf(WJ.w, x_.w, da3_); db3_ = fmaf(WJ.w, y_.w, db3_); }
#define DOT128X2M(O0, O1, XP0, XP1) {                                        \
    const float* dXp0_ = (XP0); const float* dXp1_ = (XP1);                  \
    float da0_ = 0.f, da1_ = 0.f, da2_ = 0.f, da3_ = 0.f;                    \
    float db0_ = 0.f, db1_ = 0.f, db2_ = 0.f, db3_ = 0.f;                    \
    REPW(DOTX2_B) (O0) = (da0_ + da1_) + (da2_ + da3_);                      \
    (O1) = (db0_ + db1_) + (db2_ + db3_); }

// path walk: w only.  w_l += W[i].l * rb[i]
#define WO_B(Q, WA, WB, WC, WD) {                                            \
    const float4 rv_ = *(const float4*)(rbp_ + 4 * (Q));                     \
    ww0_ = fmaf(WA.x, rv_.x, ww0_); ww1_ = fmaf(WA.y, rv_.x, ww1_);          \
    ww2_ = fmaf(WA.z, rv_.x, ww2_); ww3_ = fmaf(WA.w, rv_.x, ww3_);          \
    ww0_ = fmaf(WB.x, rv_.y, ww0_); ww1_ = fmaf(WB.y, rv_.y, ww1_);          \
    ww2_ = fmaf(WB.z, rv_.y, ww2_); ww3_ = fmaf(WB.w, rv_.y, ww3_);          \
    ww0_ = fmaf(WC.x, rv_.z, ww0_); ww1_ = fmaf(WC.y, rv_.z, ww1_);          \
    ww2_ = fmaf(WC.z, rv_.z, ww2_); ww3_ = fmaf(WC.w, rv_.z, ww3_);          \
    ww0_ = fmaf(WD.x, rv_.w, ww0_); ww1_ = fmaf(WD.y, rv_.w, ww1_);          \
    ww2_ = fmaf(WD.z, rv_.w, ww2_); ww3_ = fmaf(WD.w, rv_.w, ww3_); }
#define WONLY128M(W, RBP) { const float* rbp_ = (RBP);                       \
    float ww0_ = 0.f, ww1_ = 0.f, ww2_ = 0.f, ww3_ = 0.f;                    \
    REPQ(WO_B) (W)[0] = ww0_; (W)[1] = ww1_; (W)[2] = ww2_; (W)[3] = ww3_; }

// w + u (u from ALG rows in scr)
#define WU_SUB(ROW, WX, RC) {                                                \
    const float4 av_ = *(const float4*)(ALGp_ + (ROW) * 128);                \
    ww0_ = fmaf(WX.x, RC, ww0_); uu0_ = fmaf(av_.x, RC, uu0_);               \
    ww1_ = fmaf(WX.y, RC, ww1_); uu1_ = fmaf(av_.y, RC, uu1_);               \
    ww2_ = fmaf(WX.z, RC, ww2_); uu2_ = fmaf(av_.z, RC, uu2_);               \
    ww3_ = fmaf(WX.w, RC, ww3_); uu3_ = fmaf(av_.w, RC, uu3_); }
#define WU_B(Q, WA, WB, WC, WD) {                                            \
    const float4 rv_ = *(const float4*)(rbp_ + 4 * (Q));                     \
    WU_SUB(4 * (Q) + 0, WA, rv_.x) WU_SUB(4 * (Q) + 1, WB, rv_.y)            \
    WU_SUB(4 * (Q) + 2, WC, rv_.z) WU_SUB(4 * (Q) + 3, WD, rv_.w) }
#define WU128M(W, U, RBP) { const float* rbp_ = (RBP);                       \
    const float* ALGp_ = scr + lane * 4;                                     \
    float ww0_ = 0.f, ww1_ = 0.f, ww2_ = 0.f, ww3_ = 0.f;                    \
    float uu0_ = 0.f, uu1_ = 0.f, uu2_ = 0.f, uu3_ = 0.f;                    \
    REPQ(WU_B) (W)[0] = ww0_; (W)[1] = ww1_; (W)[2] = ww2_; (W)[3] = ww3_;   \
    (U)[0] = uu0_; (U)[1] = uu1_; (U)[2] = uu2_; (U)[3] = uu3_; }

// two parents share the ALG read stream
#define WUX2_SUB(ROW, WX, RC0, RC1) {                                        \
    const float4 av_ = *(const float4*)(ALGp_ + (ROW) * 128);                \
    wa0_ = fmaf(WX.x, RC0, wa0_); wb0_ = fmaf(WX.x, RC1, wb0_);              \
    ua0_ = fmaf(av_.x, RC0, ua0_); ub0_ = fmaf(av_.x, RC1, ub0_);            \
    wa1_ = fmaf(WX.y, RC0, wa1_); wb1_ = fmaf(WX.y, RC1, wb1_);              \
    ua1_ = fmaf(av_.y, RC0, ua1_); ub1_ = fmaf(av_.y, RC1, ub1_);            \
    wa2_ = fmaf(WX.z, RC0, wa2_); wb2_ = fmaf(WX.z, RC1, wb2_);              \
    ua2_ = fmaf(av_.z, RC0, ua2_); ub2_ = fmaf(av_.z, RC1, ub2_);            \
    wa3_ = fmaf(WX.w, RC0, wa3_); wb3_ = fmaf(WX.w, RC1, wb3_);              \
    ua3_ = fmaf(av_.w, RC0, ua3_); ub3_ = fmaf(av_.w, RC1, ub3_); }
#define WUX2_B(Q, WA, WB, WC, WD) {                                          \
    const float4 rv0_ = *(const float4*)(rbp0_ + 4 * (Q));                   \
    const float4 rv1_ = *(const float4*)(rbp1_ + 4 * (Q));                   \
    WUX2_SUB(4 * (Q) + 0, WA, rv0_.x, rv1_.x)                                \
    WUX2_SUB(4 * (Q) + 1, WB, rv0_.y, rv1_.y)                                \
    WUX2_SUB(4 * (Q) + 2, WC, rv0_.z, rv1_.z)                                \
    WUX2_SUB(4 * (Q) + 3, WD, rv0_.w, rv1_.w) }
#define WU128X2M(W0, U0, W1, U1, RBP0, RBP1) {                               \
    const float* rbp0_ = (RBP0); const float* rbp1_ = (RBP1);                \
    const float* ALGp_ = scr + lane * 4;                                     \
    float wa0_ = 0.f, wa1_ = 0.f, wa2_ = 0.f, wa3_ = 0.f;                    \
    float ua0_ = 0.f, ua1_ = 0.f, ua2_ = 0.f, ua3_ = 0.f;                    \
    float wb0_ = 0.f, wb1_ = 0.f, wb2_ = 0.f, wb3_ = 0.f;                    \
    float ub0_ = 0.f, ub1_ = 0.f, ub2_ = 0.f, ub3_ = 0.f;                    \
    REPQ(WUX2_B)                                                             \
    (W0)[0] = wa0_; (W0)[1] = wa1_; (W0)[2] = wa2_; (W0)[3] = wa3_;          \
    (U0)[0] = ua0_; (U0)[1] = ua1_; (U0)[2] = ua2_; (U0)[3] = ua3_;          \
    (W1)[0] = wb0_; (W1)[1] = wb1_; (W1)[2] = wb2_; (W1)[3] = wb3_;          \
    (U1)[0] = ub0_; (U1)[1] = ub1_; (U1)[2] = ub2_; (U1)[3] = ub3_; }

// phase-4 rebuild (FALLBACK k_down only): W -> down orient; ALG into scr
#define WRD_B(J, WJ) { const float4 av = A4[(J) * 32 + lane];                \
    const float4 e = exp4f(av);                                              \
    const float4 asp = make_float4(e.x * inv4.x, e.y * inv4.y,               \
                                   e.z * inv4.z, e.w * inv4.w);              \
    WJ = asp;                                                                \
    if (grp == ((J) >> 1))                                                   \
      *(float4*)(scr + (J) * 128 + lane * 4) =                               \
          make_float4(asp.x * (av.x - sub4.x), asp.y * (av.y - sub4.y),      \
                      asp.z * (av.z - sub4.z), asp.w * (av.w - sub4.w)); }

// ======================================================================
// ===================== FALLBACK PATH (R18, proven) ====================
// ======================================================================
__global__ __launch_bounds__(256, 1) void k_up_f(const int* __restrict__ labels,
                                                 const float* __restrict__ A,
                                                 const float* __restrict__ B,
                                                 const float* __restrict__ Pi,
                                                 const float* __restrict__ SP,
                                                 float* __restrict__ ws) {
  __shared__ __align__(16) float scr[4224];
  __shared__ __align__(16) float regB[4224];
  __shared__ __align__(16) float sPt[132];
  __shared__ int labs[425];
  const int t = threadIdx.x, lane = t & 31, grp = t >> 5;
  const int s = blockIdx.x;
  int* wsi = (int*)ws;
  const float4* A4 = (const float4*)A;
  const float4* B4 = (const float4*)B;

  if (t < 16) wsi[IC2 + 32 * t] = 0;
  else if (t == 16) wsi[IROOT2] = 0;

  const float sv0 = SP[0], sv1 = SP[1], sv2 = SP[2], sv3 = SP[3];
  const float sp0 = __expf(sv0), sp1 = __expf(sv1), sp2 = __expf(sv2), sp3 = __expf(sv3);
  const float spsum = sp0 + sp1 + sp2 + sp3;
  const float spinv = 1.f / spsum;
  float4 c4 = make_float4(0.f, 0.f, 0.f, 0.f);
  for (int i = 0; i < 32; ++i) {
    const float4 e = exp4f(A4[i * 32 + lane]);
    c4.x += e.x; c4.y += e.y; c4.z += e.z; c4.w += e.w;
  }
  const float4 inv4 = make_float4(sp0 * spinv / c4.x, sp1 * spinv / c4.y,
                                  sp2 * spinv / c4.z, sp3 * spinv / c4.w);
#pragma unroll
  for (int k = 0; k < 4; ++k) {
    const int i = grp * 4 + k;
    const float4 e = exp4f(A4[i * 32 + lane]);
    *(float4*)(scr + i * 132 + 4 * lane) =
        make_float4(e.x * inv4.x, e.y * inv4.y, e.z * inv4.z, e.w * inv4.w);
  }
#pragma unroll
  for (int rI = 0; rI < 4; ++rI) {
    const int i = grp + rI * 8;
    const float4 e = exp4f(B4[i * 32 + lane]);
    const float sinv = 1.f / rsum32(e.x + e.y + e.z + e.w);
    regB[(4 * lane + 0) * 33 + i] = e.x * sinv;
    regB[(4 * lane + 1) * 33 + i] = e.y * sinv;
    regB[(4 * lane + 2) * 33 + i] = e.z * sinv;
    regB[(4 * lane + 3) * 33 + i] = e.w * sinv;
  }
  if (grp < 4) {
    const float e = __expf(Pi[lane * 4 + grp]);
    sPt[grp * 33 + lane] = e / rsum32(e);
  }
  if (t < 84) {
    int g, d;
    if (t < 4) { g = 341 + 4 * s + t; d = 341 + t; }
    else if (t < 20) { g = 1365 + 16 * s + (t - 4); d = 345 + (t - 4); }
    else { g = 5461 + 64 * s + (t - 20); d = 361 + (t - 20); }
    labs[d] = labels[g];
  }
  if (t == 84) labs[85 + (s & 255)] = labels[85 + s];
  __syncthreads();
  W_DECL
  W_LOADUP
  __syncthreads();

#pragma unroll
  for (int h = 0; h < 2; ++h) {
    const int q0 = grp + 32 * h, q1 = q0 + 8, q2 = q0 + 16, q3 = q0 + 24;
    float v0 = sPt[(q0 & 3) * 33 + lane] * regB[labs[361 + q0] * 33 + lane];
    float v1 = sPt[(q1 & 3) * 33 + lane] * regB[labs[361 + q1] * 33 + lane];
    float v2 = sPt[(q2 & 3) * 33 + lane] * regB[labs[361 + q2] * 33 + lane];
    float v3 = sPt[(q3 & 3) * 33 + lane] * regB[labs[361 + q3] * 33 + lane];
    float s0 = v0, s1 = v1, s2 = v2, s3 = v3;
    rsum32x4(s0, s1, s2, s3);
    scr[(q0 >> 2) * 128 + lane * 4 + (q0 & 3)] = v0 / s0;
    scr[(q1 >> 2) * 128 + lane * 4 + (q1 & 3)] = v1 / s1;
    scr[(q2 >> 2) * 128 + lane * 4 + (q2 & 3)] = v2 / s2;
    scr[(q3 >> 2) * 128 + lane * 4 + (q3 & 3)] = v3 / s3;
  }
  __syncthreads();
  {
    const int p0 = grp, p1 = grp + 8;
    float tb0, tb1;
    DOT128X2M(tb0, tb1, scr + p0 * 128, scr + p1 * 128)
    float bl0 = tb0 * regB[labs[345 + p0] * 33 + lane];
    float bl1 = tb1 * regB[labs[345 + p1] * 33 + lane];
    float s0 = bl0, s1 = bl1;
    rsum32x2(s0, s1);
    bl0 /= s0; bl1 /= s1;
    scr[2048 + (p0 >> 2) * 128 + lane * 4 + (p0 & 3)] = bl0;
    scr[2048 + (p1 >> 2) * 128 + lane * 4 + (p1 & 3)] = bl1;
  }
  __syncthreads();
  if (grp < 4) {
    float tb;
    DOT128M(tb, scr + 2048 + grp * 128)
    float bl = tb * regB[labs[341 + grp] * 33 + lane];
    bl /= rsum32(bl);
    scr[2560 + lane * 4 + grp] = bl;
  }
  __syncthreads();
  if (grp == 0) {
    float tb;
    DOT128M(tb, scr + 2560)
    float bl = tb * regB[labs[85 + (s & 255)] * 33 + lane];
    bl /= rsum32(bl);
    ws[OFF_B4 + s * 32 + lane] = bl;
  }
}

__global__ __launch_bounds__(512, 1)
void k_down_f(const int* __restrict__ labels,
              const float* __restrict__ A,
              const float* __restrict__ B,
              const float* __restrict__ Pi,
              const float* __restrict__ SP,
              float* __restrict__ ws,
              float* __restrict__ out) {
  __shared__ __align__(16) float scr[6144];
  __shared__ __align__(16) float regB[4224];
  __shared__ __align__(16) float sPt[132];
  __shared__ __align__(16) float tbrT[2720];
  __shared__ __align__(16) float tbS[672];
  __shared__ __align__(16) float ownb[32];
  __shared__ __align__(16) float r_buf[512];
  __shared__ int labs[425];
  __shared__ int fin;
  const int t = threadIdx.x, lane = t & 31, grp = t >> 5;
  const int s = blockIdx.x;
  int* wsi = (int*)ws;
  double* partd = (double*)(ws + OFF_PART);
  const float4* A4 = (const float4*)A;
  const float4* B4 = (const float4*)B;

  float pf0[8], pf1[8];
#pragma unroll
  for (int h = 0; h < 2; ++h) {
    const int p0 = grp + 32 * h, p1 = p0 + 16;
#pragma unroll
    for (int l = 0; l < 4; ++l) {
      pf0[h * 4 + l] = ws[OFF_B4 + (p0 * 4 + l) * 32 + lane];
      pf1[h * 4 + l] = ws[OFF_B4 + (p1 * 4 + l) * 32 + lane];
    }
  }

  const float sv0 = SP[0], sv1 = SP[1], sv2 = SP[2], sv3 = SP[3];
  const float sp0 = __expf(sv0), sp1 = __expf(sv1), sp2 = __expf(sv2), sp3 = __expf(sv3);
  const float spsum = sp0 + sp1 + sp2 + sp3;
  const float spinv = 1.f / spsum;
  const float lss = __logf(spsum);
  float4 c4 = make_float4(0.f, 0.f, 0.f, 0.f);
  for (int i = 0; i < 32; ++i) {
    const float4 e = exp4f(A4[i * 32 + lane]);
    c4.x += e.x; c4.y += e.y; c4.z += e.z; c4.w += e.w;
  }
  const float4 inv4 = make_float4(sp0 * spinv / c4.x, sp1 * spinv / c4.y,
                                  sp2 * spinv / c4.z, sp3 * spinv / c4.w);
  const float4 sub4 = make_float4(__logf(c4.x) - (sv0 - lss), __logf(c4.y) - (sv1 - lss),
                                  __logf(c4.z) - (sv2 - lss), __logf(c4.w) - (sv3 - lss));
#pragma unroll
  for (int k = 0; k < 2; ++k) {
    const int i = grp * 2 + k;
    const float4 e = exp4f(A4[i * 32 + lane]);
    *(float4*)(scr + i * 132 + 4 * lane) =
        make_float4(e.x * inv4.x, e.y * inv4.y, e.z * inv4.z, e.w * inv4.w);
  }
#pragma unroll
  for (int rI = 0; rI < 2; ++rI) {
    const int i = grp + rI * 16;
    const float4 e = exp4f(B4[i * 32 + lane]);
    const float sinv = 1.f / rsum32(e.x + e.y + e.z + e.w);
    regB[(4 * lane + 0) * 33 + i] = e.x * sinv;
    regB[(4 * lane + 1) * 33 + i] = e.y * sinv;
    regB[(4 * lane + 2) * 33 + i] = e.z * sinv;
    regB[(4 * lane + 3) * 33 + i] = e.w * sinv;
  }
  if (grp < 4) {
    const float e = __expf(Pi[lane * 4 + grp]);
    sPt[grp * 33 + lane] = e / rsum32(e);
  }
  for (int idx = t; idx < 341; idx += 512) labs[idx] = labels[idx];
  if (t < 84) {
    int g, d;
    if (t < 4) { g = 341 + 4 * s + t; d = 341 + t; }
    else if (t < 20) { g = 1365 + 16 * s + (t - 4); d = 345 + (t - 4); }
    else { g = 5461 + 64 * s + (t - 20); d = 361 + (t - 20); }
    labs[d] = labels[g];
  }
  __syncthreads();
  W_DECL
  W_LOADUP
  __syncthreads();

  {
    const int q0 = grp, q1 = grp + 16, q2 = grp + 32, q3 = grp + 48;
    float v0 = sPt[(q0 & 3) * 33 + lane] * regB[labs[361 + q0] * 33 + lane];
    float v1 = sPt[(q1 & 3) * 33 + lane] * regB[labs[361 + q1] * 33 + lane];
    float v2 = sPt[(q2 & 3) * 33 + lane] * regB[labs[361 + q2] * 33 + lane];
    float v3 = sPt[(q3 & 3) * 33 + lane] * regB[labs[361 + q3] * 33 + lane];
    float s0 = v0, s1 = v1, s2 = v2, s3 = v3;
    rsum32x4(s0, s1, s2, s3);
    scr[(q0 >> 2) * 128 + lane * 4 + (q0 & 3)] = v0 / s0;
    scr[(q1 >> 2) * 128 + lane * 4 + (q1 & 3)] = v1 / s1;
    scr[(q2 >> 2) * 128 + lane * 4 + (q2 & 3)] = v2 / s2;
    scr[(q3 >> 2) * 128 + lane * 4 + (q3 & 3)] = v3 / s3;
  }
  __syncthreads();
  if (grp < 8) {
    const int p0 = grp, p1 = grp + 8;
    float tb0, tb1;
    DOT128X2M(tb0, tb1, scr + p0 * 128, scr + p1 * 128)
    float bl0 = tb0 * regB[labs[345 + p0] * 33 + lane];
    float bl1 = tb1 * regB[labs[345 + p1] * 33 + lane];
    float s0 = bl0, s1 = bl1;
    rsum32x2(s0, s1);
    bl0 /= s0; bl1 /= s1;
    tbS[(5 + p0) * 32 + lane] = tb0;
    tbS[(5 + p1) * 32 + lane] = tb1;
    scr[2048 + (p0 >> 2) * 128 + lane * 4 + (p0 & 3)] = bl0;
    scr[2048 + (p1 >> 2) * 128 + lane * 4 + (p1 & 3)] = bl1;
  }
  __syncthreads();
  if (grp < 4) {
    float tb;
    DOT128M(tb, scr + 2048 + grp * 128)
    float bl = tb * regB[labs[341 + grp] * 33 + lane];
    bl /= rsum32(bl);
    tbS[(1 + grp) * 32 + lane] = tb;
    scr[2560 + lane * 4 + grp] = bl;
  }
  __syncthreads();
  if (grp == 0) {
    float tb;
    DOT128M(tb, scr + 2560)
    float bl = tb * regB[labs[85 + s] * 33 + lane];
    bl /= rsum32(bl);
    tbS[lane] = tb;
    ownb[lane] = bl;
  }
  __syncthreads();

#pragma unroll
  for (int h = 0; h < 2; ++h) {
    const int p0 = grp + 32 * h, p1 = p0 + 16;
    float* st0 = scr + grp * 128;
    float* st1 = scr + 2048 + grp * 128;
#pragma unroll
    for (int l = 0; l < 4; ++l) {
      st0[lane * 4 + l] = pf0[h * 4 + l];
      st1[lane * 4 + l] = pf1[h * 4 + l];
    }
    float tb0, tb1;
    DOT128X2M(tb0, tb1, st0, st1)
    float bl0 = tb0 * regB[labs[21 + p0] * 33 + lane];
    float bl1 = tb1 * regB[labs[21 + p1] * 33 + lane];
    float s0 = bl0, s1 = bl1;
    rsum32x2(s0, s1);
    bl0 /= s0; bl1 /= s1;
    tbrT[(21 + p0) * 32 + lane] = tb0;
    tbrT[(21 + p1) * 32 + lane] = tb1;
    scr[4096 + (p0 >> 2) * 128 + lane * 4 + (p0 & 3)] = bl0;
    scr[4096 + (p1 >> 2) * 128 + lane * 4 + (p1 & 3)] = bl1;
  }
  __syncthreads();
  {
    const int p = grp;
    float tb;
    DOT128M(tb, scr + 4096 + p * 128)
    float bl = tb * regB[labs[5 + p] * 33 + lane];
    bl /= rsum32(bl);
    tbrT[(5 + p) * 32 + lane] = tb;
    scr[(p >> 2) * 128 + lane * 4 + (p & 3)] = bl;
  }
  __syncthreads();
  if (grp < 4) {
    float tb;
    DOT128M(tb, scr + grp * 128)
    float bl = tb * regB[labs[1 + grp] * 33 + lane];
    bl /= rsum32(bl);
    tbrT[(1 + grp) * 32 + lane] = tb;
    scr[512 + lane * 4 + grp] = bl;
  }
  __syncthreads();
  if (grp == 0) { float tb; DOT128M(tb, scr + 512) tbrT[lane] = tb; }
  __syncthreads();

  for (int idx = t; idx < 4224; idx += 512) regB[idx] = __logf(regB[idx]);
  if (t < 132) sPt[t] = __logf(sPt[t]);
  REPW(WRD_B)
  __syncthreads();

  double ll = 0.0;
  float eps4own = 0.f;
  if (grp < 4) {
    const int n1 = 1 + (s >> 6), n2 = 5 + (s >> 4), n3 = 21 + (s >> 2);
    const int a0 = s >> 6, a1 = (s >> 4) & 3, a2 = (s >> 2) & 3, a3 = s & 3;
    float w[4], uv[4];
    float* rb = r_buf + grp * 32;

    float tbv = tbrT[lane];
    float bcv = tbv * __expf(regB[labs[0] * 33 + lane]);
    bcv /= rsum32(bcv);
    rb[lane] = bcv / tbv;
    if (grp == 0 && s == 0) {
      ll += (double)(bcv * regB[labs[0] * 33 + lane]);
      WU128M(w, uv, rb)
      const float lb0 = regB[labs[1] * 33 + lane], lb1 = regB[labs[2] * 33 + lane];
      const float lb2 = regB[labs[3] * 33 + lane], lb3 = regB[labs[4] * 33 + lane];
      float b0 = tbrT[1 * 32 + lane] * __expf(lb0);
      float b1 = tbrT[2 * 32 + lane] * __expf(lb1);
      float b2 = tbrT[3 * 32 + lane] * __expf(lb2);
      float b3 = tbrT[4 * 32 + lane] * __expf(lb3);
      float s0 = b0, s1 = b1, s2 = b2, s3 = b3;
      rsum32x4(s0, s1, s2, s3);
      b0 /= s0; b1 /= s1; b2 /= s2; b3 /= s3;
      ll += (double)(b0 * uv[0]) + (double)(b0 * w[0] * lb0);
      ll += (double)(b1 * uv[1]) + (double)(b1 * w[1] * lb1);
      ll += (double)(b2 * uv[2]) + (double)(b2 * w[2] * lb2);
      ll += (double)(b3 * uv[3]) + (double)(b3 * w[3] * lb3);
    } else {
      WONLY128M(w, rb)
    }

    tbv = tbrT[n1 * 32 + lane];
    bcv = tbv * __expf(regB[labs[n1] * 33 + lane]);
    bcv /= rsum32(bcv);
    rb[lane] = (bcv * w[a0]) / tbv;
    if (grp == 1 && (s & 63) == 0) {
      WU128M(w, uv, rb)
      const int cb = 5 + 4 * (s >> 6);
      const float lb0 = regB[labs[cb + 0] * 33 + lane], lb1 = regB[labs[cb + 1] * 33 + lane];
      const float lb2 = regB[labs[cb + 2] * 33 + lane], lb3 = regB[labs[cb + 3] * 33 + lane];
      float b0 = tbrT[(cb + 0) * 32 + lane] * __expf(lb0);
      float b1 = tbrT[(cb + 1) * 32 + lane] * __expf(lb1);
      float b2 = tbrT[(cb + 2) * 32 + lane] * __expf(lb2);
      float b3 = tbrT[(cb + 3) * 32 + lane] * __expf(lb3);
      float s0 = b0, s1 = b1, s2 = b2, s3 = b3;
      rsum32x4(s0, s1, s2, s3);
      b0 /= s0; b1 /= s1; b2 /= s2; b3 /= s3;
      ll += (double)(b0 * uv[0]) + (double)(b0 * w[0] * lb0);
      ll += (double)(b1 * uv[1]) + (double)(b1 * w[1] * lb1);
      ll += (double)(b2 * uv[2]) + (double)(b2 * w[2] * lb2);
      ll += (double)(b3 * uv[3]) + (double)(b3 * w[3] * lb3);
    } else {
      WONLY128M(w, rb)
    }

    tbv = tbrT[n2 * 32 + lane];
    bcv = tbv * __expf(regB[labs[n2] * 33 + lane]);
    bcv /= rsum32(bcv);
    rb[lane] = (bcv * w[a1]) / tbv;
    if (grp == 2 && (s & 15) == 0) {
      WU128M(w, uv, rb)
      const int cb = 21 + 4 * (s >> 4);
      const float lb0 = regB[labs[cb + 0] * 33 + lane], lb1 = regB[labs[cb + 1] * 33 + lane];
      const float lb2 = regB[labs[cb + 2] * 33 + lane], lb3 = regB[labs[cb + 3] * 33 + lane];
      float b0 = tbrT[(cb + 0) * 32 + lane] * __expf(lb0);
      float b1 = tbrT[(cb + 1) * 32 + lane] * __expf(lb1);
      float b2 = tbrT[(cb + 2) * 32 + lane] * __expf(lb2);
      float b3 = tbrT[(cb + 3) * 32 + lane] * __expf(lb3);
      float s0 = b0, s1 = b1, s2 = b2, s3 = b3;
      rsum32x4(s0, s1, s2, s3);
      b0 /= s0; b1 /= s1; b2 /= s2; b3 /= s3;
      ll += (double)(b0 * uv[0]) + (double)(b0 * w[0] * lb0);
      ll += (double)(b1 * uv[1]) + (double)(b1 * w[1] * lb1);
      ll += (double)(b2 * uv[2]) + (double)(b2 * w[2] * lb2);
      ll += (double)(b3 * uv[3]) + (double)(b3 * w[3] * lb3);
    } else {
      WONLY128M(w, rb)
    }

    tbv = tbrT[n3 * 32 + lane];
    bcv = tbv * __expf(regB[labs[n3] * 33 + lane]);
    bcv /= rsum32(bcv);
    rb[lane] = (bcv * w[a2]) / tbv;
    if (grp == 3 && (s & 3) == 0) {
      WU128M(w, uv, rb)
      const int cb = s & ~3;
#pragma unroll
      for (int l = 0; l < 4; ++l) {
        const int ci = cb + l;
        const float bc = ws[OFF_B4 + ci * 32 + lane];
        const float e = bc * w[l];
        ll += (double)(bc * uv[l]) + (double)(e * regB[labs[85 + ci] * 33 + lane]);
      }
    } else {
      WONLY128M(w, rb)
    }
    eps4own = ownb[lane] * w[a3];
  }
  __syncthreads();

  if (grp == 0) {
    r_buf[lane] = eps4own / tbS[lane];
    float w[4], u[4];
    WU128M(w, u, r_buf)
#pragma unroll
    for (int l = 0; l < 4; ++l) {
      const int lab = labs[341 + l];
      const float tbv = tbS[(1 + l) * 32 + lane];
      float bcv = tbv * __expf(regB[lab * 33 + lane]);
      bcv /= rsum32(bcv);
      const float e = bcv * w[l];
      ll += (double)(bcv * u[l]) + (double)(e * regB[lab * 33 + lane]);
      tbS[(1 + l) * 32 + lane] = e / tbv;
    }
  }
  __syncthreads();
  if (grp < 4) {
    const int p = grp;
    r_buf[p * 32 + lane] = tbS[(1 + p) * 32 + lane];
    float w[4], u[4];
    WU128M(w, u, r_buf + p * 32)
#pragma unroll
    for (int l = 0; l < 4; ++l) {
      const int q = p * 4 + l;
      const int lab = labs[345 + q];
      const float tbv = tbS[(5 + q) * 32 + lane];
      float bcv = tbv * __expf(regB[lab * 33 + lane]);
      bcv /= rsum32(bcv);
      const float e = bcv * w[l];
      ll += (double)(bcv * u[l]) + (double)(e * regB[lab * 33 + lane]);
      tbS[(5 + q) * 32 + lane] = e / tbv;
    }
  }
  __syncthreads();
  if (grp < 8) {
    const int p0 = grp, p1 = grp + 8;
    float* rb0 = r_buf + grp * 32;
    float* rb1 = r_buf + 256 + grp * 32;
    rb0[lane] = tbS[(5 + p0) * 32 + lane];
    rb1[lane] = tbS[(5 + p1) * 32 + lane];
    float w0[4], u0[4], w1[4], u1[4];
    WU128X2M(w0, u0, w1, u1, rb0, rb1)
#pragma unroll
    for (int l = 0; l < 4; ++l) {
      const int q0 = p0 * 4 + l, q1 = p1 * 4 + l;
      const float lb0 = regB[labs[361 + q0] * 33 + lane];
      const float lb1 = regB[labs[361 + q1] * 33 + lane];
      const float lp = sPt[l * 33 + lane];
      float b0 = __expf(lp + lb0);
      float b1 = __expf(lp + lb1);
      float s0 = b0, s1 = b1;
      rsum32x2(s0, s1);
      b0 /= s0; b1 /= s1;
      const float e0 = b0 * w0[l], e1 = b1 * w1[l];
      ll += (double)(b0 * u0[l]) + (double)(e0 * lb0) + (double)(e0 * lp);
      ll += (double)(b1 * u1[l]) + (double)(e1 * lb1) + (double)(e1 * lp);
    }
  }

#pragma unroll
  for (int k = 32; k >= 1; k >>= 1) ll += __shfl_xor(ll, k);
  double* rbd = (double*)r_buf;
  __syncthreads();
  if ((t & 63) == 0) rbd[t >> 6] = ll;
  __syncthreads();
  if (t == 0) {
    partd[s] = ((rbd[0] + rbd[1]) + (rbd[2] + rbd[3])) +
               ((rbd[4] + rbd[5]) + (rbd[6] + rbd[7]));
    __threadfence();
    int f = 0;
    if (atomicAdd(&wsi[IC2 + 32 * (s >> 4)], 1) == 15)
      if (atomicAdd(&wsi[IROOT2], 1) == 15) f = 1;
    fin = f;
  }
  __syncthreads();
  if (fin) {
    __threadfence();
    if (t < 64) {
      double v = 0.0;
      for (int k = t; k < 256; k += 64) v += partd[k];
#pragma unroll
      for (int k = 32; k >= 1; k >>= 1) v += __shfl_xor(v, k);
      if (t == 0) out[0] = (float)v;
    }
  }
}

// ======================================================================
// ================= PERSIST PATH (R20 design + R21 cuts) ===============
// ======================================================================
__global__ __launch_bounds__(512, 1) void k_up_p(const int* __restrict__ labels,
                                                 const float* __restrict__ A,
                                                 const float* __restrict__ B,
                                                 const float* __restrict__ Pi,
                                                 const float* __restrict__ SP,
                                                 float* __restrict__ ws) {
  __shared__ __align__(16) float scr[4224];
  __shared__ __align__(16) float regB[4224];
  __shared__ __align__(16) float sPt[132];
  __shared__ int labs[425];
  const int t = threadIdx.x, lane = t & 31, grp = t >> 5;  // 16 groups
  const int s = blockIdx.x;
  int* wsi = (int*)ws;
  const float4* A4 = (const float4*)A;
  const float4* B4 = (const float4*)B;

  if (t < 16) wsi[IC2 + 32 * t] = 0;
  else if (t == 16) wsi[IROOT2] = 0;

  const float sv0 = SP[0], sv1 = SP[1], sv2 = SP[2], sv3 = SP[3];
  const float sp0 = __expf(sv0), sp1 = __expf(sv1), sp2 = __expf(sv2), sp3 = __expf(sv3);
  const float spsum = sp0 + sp1 + sp2 + sp3;
  const float spinv = 1.f / spsum;
  const float lss = __logf(spsum);
  float4 c4 = make_float4(0.f, 0.f, 0.f, 0.f);
  for (int i = 0; i < 32; ++i) {
    const float4 e = exp4f(A4[i * 32 + lane]);
    c4.x += e.x; c4.y += e.y; c4.z += e.z; c4.w += e.w;
  }
  const float4 inv4 = make_float4(sp0 * spinv / c4.x, sp1 * spinv / c4.y,
                                  sp2 * spinv / c4.z, sp3 * spinv / c4.w);
  const float4 sub4 = make_float4(__logf(c4.x) - (sv0 - lss), __logf(c4.y) - (sv1 - lss),
                                  __logf(c4.z) - (sv2 - lss), __logf(c4.w) - (sv3 - lss));
#pragma unroll
  for (int k = 0; k < 2; ++k) {
    const int i = grp * 2 + k;
    const float4 e = exp4f(A4[i * 32 + lane]);
    *(float4*)(scr + i * 132 + 4 * lane) =
        make_float4(e.x * inv4.x, e.y * inv4.y, e.z * inv4.z, e.w * inv4.w);
  }
#pragma unroll
  for (int rI = 0; rI < 2; ++rI) {
    const int i = grp + rI * 16;
    const float4 e = exp4f(B4[i * 32 + lane]);
    const float sinv = 1.f / rsum32(e.x + e.y + e.z + e.w);
    regB[(4 * lane + 0) * 33 + i] = e.x * sinv;
    regB[(4 * lane + 1) * 33 + i] = e.y * sinv;
    regB[(4 * lane + 2) * 33 + i] = e.z * sinv;
    regB[(4 * lane + 3) * 33 + i] = e.w * sinv;
  }
  if (grp < 4) {
    const float e = __expf(Pi[lane * 4 + grp]);
    sPt[grp * 33 + lane] = e / rsum32(e);
  } else if (grp == 4) {  // fill the 4 gap slots so persisted logs are finite
    if (lane < 4) sPt[lane * 33 + 32] = 1.f;
  }
  if (t < 84) {
    int g, d;
    if (t < 4) { g = 341 + 4 * s + t; d = 341 + t; }
    else if (t < 20) { g = 1365 + 16 * s + (t - 4); d = 345 + (t - 4); }
    else { g = 5461 + 64 * s + (t - 20); d = 361 + (t - 20); }
    labs[d] = labels[g];
  }
  if (t == 84) labs[85 + (s & 255)] = labels[85 + s];
  __syncthreads();

  // ---------- block 0: persist block-independent tables ----------
  if (s == 0) {
    for (int idx = t; idx < 4224; idx += 512) {
      ws[OFF_ASP + idx] = scr[idx];
      const float v = regB[idx];
      ws[OFF_RB + idx] = v;
      ws[OFF_LRB + idx] = __logf(v);
    }
    if (t < 132) ws[OFF_LSP + t] = __logf(sPt[t]);
#pragma unroll
    for (int k = 0; k < 2; ++k) {
      const int i = grp * 2 + k;
      const float4 av = A4[i * 32 + lane];
      const float4 e = exp4f(av);
      const float4 asp = make_float4(e.x * inv4.x, e.y * inv4.y,
                                     e.z * inv4.z, e.w * inv4.w);
      *(float4*)(ws + OFF_ALG + i * 128 + lane * 4) =
          make_float4(asp.x * (av.x - sub4.x), asp.y * (av.y - sub4.y),
                      asp.z * (av.z - sub4.z), asp.w * (av.w - sub4.w));
    }
  }
  W_DECL
  W_LOADUP
  __syncthreads();

  // ---------- phase 2: subtree up sweep; persist tbS rows + b4 ----------
  float* tbs = ws + OFF_TBO + s * 672;
  {
    const int q0 = grp, q1 = grp + 16, q2 = grp + 32, q3 = grp + 48;
    float v0 = sPt[(q0 & 3) * 33 + lane] * regB[labs[361 + q0] * 33 + lane];
    float v1 = sPt[(q1 & 3) * 33 + lane] * regB[labs[361 + q1] * 33 + lane];
    float v2 = sPt[(q2 & 3) * 33 + lane] * regB[labs[361 + q2] * 33 + lane];
    float v3 = sPt[(q3 & 3) * 33 + lane] * regB[labs[361 + q3] * 33 + lane];
    float s0 = v0, s1 = v1, s2 = v2, s3 = v3;
    rsum32x4(s0, s1, s2, s3);
    scr[(q0 >> 2) * 128 + lane * 4 + (q0 & 3)] = v0 / s0;
    scr[(q1 >> 2) * 128 + lane * 4 + (q1 & 3)] = v1 / s1;
    scr[(q2 >> 2) * 128 + lane * 4 + (q2 & 3)] = v2 / s2;
    scr[(q3 >> 2) * 128 + lane * 4 + (q3 & 3)] = v3 / s3;
  }
  __syncthreads();
  {  // S2 (R21): 16 L6 parents, ONE per group (was 8 groups x paired X2)
    const int p = grp;
    float tb;
    DOT128M(tb, scr + p * 128)
    float bl = tb * regB[labs[345 + p] * 33 + lane];
    bl /= rsum32(bl);
    tbs[(5 + p) * 32 + lane] = tb;
    scr[2048 + (p >> 2) * 128 + lane * 4 + (p & 3)] = bl;  // X6
  }
  __syncthreads();
  if (grp < 4) {
    float tb;
    DOT128M(tb, scr + 2048 + grp * 128)
    float bl = tb * regB[labs[341 + grp] * 33 + lane];
    bl /= rsum32(bl);
    tbs[(1 + grp) * 32 + lane] = tb;
    scr[2560 + lane * 4 + grp] = bl;
  }
  __syncthreads();
  if (grp == 0) {
    float tb;
    DOT128M(tb, scr + 2560)
    float bl = tb * regB[labs[85 + (s & 255)] * 33 + lane];
    bl /= rsum32(bl);
    tbs[lane] = tb;
    ws[OFF_B4 + s * 32 + lane] = bl;
  }
}

__global__ __launch_bounds__(512, 1)
void k_down_p(const int* __restrict__ labels,
              const float* __restrict__ ws_c,
              float* __restrict__ ws,
              float* __restrict__ out) {
  __shared__ __align__(16) float scr[6144];
  __shared__ __align__(16) float regB[4224];
  __shared__ __align__(16) float sPt[132];
  __shared__ __align__(16) float tbrT[2720];
  __shared__ __align__(16) float tbS[672];
  __shared__ __align__(16) float ownb[32];
  __shared__ __align__(16) float r_buf[512];
  __shared__ int labs[425];
  __shared__ int fin;
  const int t = threadIdx.x, lane = t & 31, grp = t >> 5;  // 16 groups
  const int s = blockIdx.x;
  int* wsi = (int*)ws;
  double* partd = (double*)(ws + OFF_PART);
  (void)ws_c;

  // ---------- early prefetch: P3's b4 children ----------
  float pf0[8], pf1[8];
#pragma unroll
  for (int h = 0; h < 2; ++h) {
    const int p0 = grp + 32 * h, p1 = p0 + 16;
#pragma unroll
    for (int l = 0; l < 4; ++l) {
      pf0[h * 4 + l] = ws[OFF_B4 + (p0 * 4 + l) * 32 + lane];
      pf1[h * 4 + l] = ws[OFF_B4 + (p1 * 4 + l) * 32 + lane];
    }
  }
  // ---------- early prefetch (R21): P4's ALG + logB tables into regs ----
  // Hides the mid-chain cross-XCD L3 staging stall under P3.
  const float4* wsALG4 = (const float4*)(ws + OFF_ALG);   // 1024 float4
  const float4* wsLRB4 = (const float4*)(ws + OFF_LRB);   // 1056 float4
  float4 pfA0 = wsALG4[t];
  float4 pfA1 = wsALG4[t + 512];
  float4 pfL0 = wsLRB4[t];
  float4 pfL1 = wsLRB4[t + 512];
  float4 pfL2 = make_float4(0.f, 0.f, 0.f, 0.f);
  if (t < 32) pfL2 = wsLRB4[t + 1024];

  // ---------- stage tables + per-block state from ws ----------
  for (int idx = t; idx < 4224; idx += 512) scr[idx] = ws[OFF_ASP + idx];
  for (int idx = t; idx < 4224; idx += 512) regB[idx] = ws[OFF_RB + idx];
  if (t < 132) sPt[t] = ws[OFF_LSP + t];             // log sPt
  for (int idx = t; idx < 672; idx += 512) tbS[idx] = ws[OFF_TBO + s * 672 + idx];
  if (t < 32) ownb[t] = ws[OFF_B4 + s * 32 + t];
  for (int idx = t; idx < 341; idx += 512) labs[idx] = labels[idx];
  if (t < 84) {
    int g, d;
    if (t < 4) { g = 341 + 4 * s + t; d = 341 + t; }
    else if (t < 20) { g = 1365 + 16 * s + (t - 4); d = 345 + (t - 4); }
    else { g = 5461 + 64 * s + (t - 20); d = 361 + (t - 20); }
    labs[d] = labels[g];
  }
  __syncthreads();
  W_DECL
  W_LOADUP
  __syncthreads();

  // ---------- phase 3: top up sweep (redundant per block) ----------
#pragma unroll
  for (int h = 0; h < 2; ++h) {
    const int p0 = grp + 32 * h, p1 = p0 + 16;
    float* st0 = scr + grp * 128;
    float* st1 = scr + 2048 + grp * 128;
#pragma unroll
    for (int l = 0; l < 4; ++l) {
      st0[lane * 4 + l] = pf0[h * 4 + l];
      st1[lane * 4 + l] = pf1[h * 4 + l];
    }
    float tb0, tb1;
    DOT128X2M(tb0, tb1, st0, st1)
    float bl0 = tb0 * regB[labs[21 + p0] * 33 + lane];
    float bl1 = tb1 * regB[labs[21 + p1] * 33 + lane];
    float s0 = bl0, s1 = bl1;
    rsum32x2(s0, s1);
    bl0 /= s0; bl1 /= s1;
    tbrT[(21 + p0) * 32 + lane] = tb0;
    tbrT[(21 + p1) * 32 + lane] = tb1;
    scr[4096 + (p0 >> 2) * 128 + lane * 4 + (p0 & 3)] = bl0;
    scr[4096 + (p1 >> 2) * 128 + lane * 4 + (p1 & 3)] = bl1;
  }
  __syncthreads();
  {
    const int p = grp;
    float tb;
    DOT128M(tb, scr + 4096 + p * 128)
    float bl = tb * regB[labs[5 + p] * 33 + lane];
    bl /= rsum32(bl);
    tbrT[(5 + p) * 32 + lane] = tb;
    scr[(p >> 2) * 128 + lane * 4 + (p & 3)] = bl;
  }
  __syncthreads();
  if (grp < 4) {
    float tb;
    DOT128M(tb, scr + grp * 128)
    float bl = tb * regB[labs[1 + grp] * 33 + lane];
    bl /= rsum32(bl);
    tbrT[(1 + grp) * 32 + lane] = tb;
    scr[512 + lane * 4 + grp] = bl;
  }
  __syncthreads();
  if (grp == 0) { float tb; DOT128M(tb, scr + 512) tbrT[lane] = tb; }
  __syncthreads();

  // ---------- phase 4 (slim): write prefetched ALG + logB; reload W ------
  ((float4*)scr)[t] = pfA0;
  ((float4*)scr)[t + 512] = pfA1;
  ((float4*)regB)[t] = pfL0;
  ((float4*)regB)[t + 512] = pfL1;
  if (t < 32) ((float4*)regB)[t + 1024] = pfL2;
  if (grp < 8) {
    const float* wsASP_ = ws + OFF_ASP;
    REPW(WLDDN_B)
  }
  __syncthreads();

  // ---------- phase 5: top down, DISTRIBUTED owners ----------
  double ll = 0.0;
  float eps4own = 0.f;
  if (grp < 4) {
    const int n1 = 1 + (s >> 6), n2 = 5 + (s >> 4), n3 = 21 + (s >> 2);
    const int a0 = s >> 6, a1 = (s >> 4) & 3, a2 = (s >> 2) & 3, a3 = s & 3;
    float w[4], uv[4];
    float* rb = r_buf + grp * 32;

    float tbv = tbrT[lane];
    float bcv = tbv * __expf(regB[labs[0] * 33 + lane]);
    bcv /= rsum32(bcv);
    rb[lane] = bcv / tbv;
    if (grp == 0 && s == 0) {
      ll += (double)(bcv * regB[labs[0] * 33 + lane]);
      WU128M(w, uv, rb)
      const float lb0 = regB[labs[1] * 33 + lane], lb1 = regB[labs[2] * 33 + lane];
      const float lb2 = regB[labs[3] * 33 + lane], lb3 = regB[labs[4] * 33 + lane];
      float b0 = tbrT[1 * 32 + lane] * __expf(lb0);
      float b1 = tbrT[2 * 32 + lane] * __expf(lb1);
      float b2 = tbrT[3 * 32 + lane] * __expf(lb2);
      float b3 = tbrT[4 * 32 + lane] * __expf(lb3);
      float s0 = b0, s1 = b1, s2 = b2, s3 = b3;
      rsum32x4(s0, s1, s2, s3);
      b0 /= s0; b1 /= s1; b2 /= s2; b3 /= s3;
      ll += (double)(b0 * uv[0]) + (double)(b0 * w[0] * lb0);
      ll += (double)(b1 * uv[1]) + (double)(b1 * w[1] * lb1);
      ll += (double)(b2 * uv[2]) + (double)(b2 * w[2] * lb2);
      ll += (double)(b3 * uv[3]) + (double)(b3 * w[3] * lb3);
    } else {
      WONLY128M(w, rb)
    }

    tbv = tbrT[n1 * 32 + lane];
    bcv = tbv * __expf(regB[labs[n1] * 33 + lane]);
    bcv /= rsum32(bcv);
    rb[lane] = (bcv * w[a0]) / tbv;
    if (grp == 1 && (s & 63) == 0) {
      WU128M(w, uv, rb)
      const int cb = 5 + 4 * (s >> 6);
      const float lb0 = regB[labs[cb + 0] * 33 + lane], lb1 = regB[labs[cb + 1] * 33 + lane];
      const float lb2 = regB[labs[cb + 2] * 33 + lane], lb3 = regB[labs[cb + 3] * 33 + lane];
      float b0 = tbrT[(cb + 0) * 32 + lane] * __expf(lb0);
      float b1 = tbrT[(cb + 1) * 32 + lane] * __expf(lb1);
      float b2 = tbrT[(cb + 2) * 32 + lane] * __expf(lb2);
      float b3 = tbrT[(cb + 3) * 32 + lane] * __expf(lb3);
      float s0 = b0, s1 = b1, s2 = b2, s3 = b3;
      rsum32x4(s0, s1, s2, s3);
      b0 /= s0; b1 /= s1; b2 /= s2; b3 /= s3;
      ll += (double)(b0 * uv[0]) + (double)(b0 * w[0] * lb0);
      ll += (double)(b1 * uv[1]) + (double)(b1 * w[1] * lb1);
      ll += (double)(b2 * uv[2]) + (double)(b2 * w[2] * lb2);
      ll += (double)(b3 * uv[3]) + (double)(b3 * w[3] * lb3);
    } else {
      WONLY128M(w, rb)
    }

    tbv = tbrT[n2 * 32 + lane];
    bcv = tbv * __expf(regB[labs[n2] * 33 + lane]);
    bcv /= rsum32(bcv);
    rb[lane] = (bcv * w[a1]) / tbv;
    if (grp == 2 && (s & 15) == 0) {
      WU128M(w, uv, rb)
      const int cb = 21 + 4 * (s >> 4);
      const float lb0 = regB[labs[cb + 0] * 33 + lane], lb1 = regB[labs[cb + 1] * 33 + lane];
      const float lb2 = regB[labs[cb + 2] * 33 + lane], lb3 = regB[labs[cb + 3] * 33 + lane];
      float b0 = tbrT[(cb + 0) * 32 + lane] * __expf(lb0);
      float b1 = tbrT[(cb + 1) * 32 + lane] * __expf(lb1);
      float b2 = tbrT[(cb + 2) * 32 + lane] * __expf(lb2);
      float b3 = tbrT[(cb + 3) * 32 + lane] * __expf(lb3);
      float s0 = b0, s1 = b1, s2 = b2, s3 = b3;
      rsum32x4(s0, s1, s2, s3);
      b0 /= s0; b1 /= s1; b2 /= s2; b3 /= s3;
      ll += (double)(b0 * uv[0]) + (double)(b0 * w[0] * lb0);
      ll += (double)(b1 * uv[1]) + (double)(b1 * w[1] * lb1);
      ll += (double)(b2 * uv[2]) + (double)(b2 * w[2] * lb2);
      ll += (double)(b3 * uv[3]) + (double)(b3 * w[3] * lb3);
    } else {
      WONLY128M(w, rb)
    }

    tbv = tbrT[n3 * 32 + lane];
    bcv = tbv * __expf(regB[labs[n3] * 33 + lane]);
    bcv /= rsum32(bcv);
    rb[lane] = (bcv * w[a2]) / tbv;
    if (grp == 3 && (s & 3) == 0) {
      WU128M(w, uv, rb)
      const int cb = s & ~3;
#pragma unroll
      for (int l = 0; l < 4; ++l) {
        const int ci = cb + l;
        const float bc = ws[OFF_B4 + ci * 32 + lane];
        const float e = bc * w[l];
        ll += (double)(bc * uv[l]) + (double)(e * regB[labs[85 + ci] * 33 + lane]);
      }
    } else {
      WONLY128M(w, rb)
    }
    eps4own = ownb[lane] * w[a3];
  }
  __syncthreads();

  // ---------- phase 6: subtree down sweep ----------
  if (grp == 0) {
    r_buf[lane] = eps4own / tbS[lane];
    float w[4], u[4];
    WU128M(w, u, r_buf)
#pragma unroll
    for (int l = 0; l < 4; ++l) {
      const int lab = labs[341 + l];
      const float tbv = tbS[(1 + l) * 32 + lane];
      float bcv = tbv * __expf(regB[lab * 33 + lane]);
      bcv /= rsum32(bcv);
      const float e = bcv * w[l];
      ll += (double)(bcv * u[l]) + (double)(e * regB[lab * 33 + lane]);
      tbS[(1 + l) * 32 + lane] = e / tbv;
    }
  }
  __syncthreads();
  if (grp < 4) {
    const int p = grp;
    r_buf[p * 32 + lane] = tbS[(1 + p) * 32 + lane];
    float w[4], u[4];
    WU128M(w, u, r_buf + p * 32)
#pragma unroll
    for (int l = 0; l < 4; ++l) {
      const int q = p * 4 + l;
      const int lab = labs[345 + q];
      const float tbv = tbS[(5 + q) * 32 + lane];
      float bcv = tbv * __expf(regB[lab * 33 + lane]);
      bcv /= rsum32(bcv);
      const float e = bcv * w[l];
      ll += (double)(bcv * u[l]) + (double)(e * regB[lab * 33 + lane]);
      tbS[(5 + q) * 32 + lane] = e / tbv;
    }
  }
  __syncthreads();
  {  // d2 (R21): 16 L6 parents, ONE per group (was 8 groups x paired X2)
    const int p = grp;
    float* rb0 = r_buf + grp * 32;
    rb0[lane] = tbS[(5 + p) * 32 + lane];
    float w[4], u[4];
    WU128M(w, u, rb0)
#pragma unroll
    for (int l = 0; l < 4; ++l) {
      const int q = p * 4 + l;
      const float lb = regB[labs[361 + q] * 33 + lane];
      const float lp = sPt[l * 33 + lane];
      float b = __expf(lp + lb);
      b /= rsum32(b);
      const float e = b * w[l];
      ll += (double)(b * u[l]) + (double)(e * lb) + (double)(e * lp);
    }
  }

  // ---------- phase 7: partials + tree finalize ----------
#pragma unroll
  for (int k = 32; k >= 1; k >>= 1) ll += __shfl_xor(ll, k);
  double* rbd = (double*)r_buf;
  __syncthreads();
  if ((t & 63) == 0) rbd[t >> 6] = ll;
  __syncthreads();
  if (t == 0) {
    partd[s] = ((rbd[0] + rbd[1]) + (rbd[2] + rbd[3])) +
               ((rbd[4] + rbd[5]) + (rbd[6] + rbd[7]));
    __threadfence();
    int f = 0;
    if (atomicAdd(&wsi[IC2 + 32 * (s >> 4)], 1) == 15)
      if (atomicAdd(&wsi[IROOT2], 1) == 15) f = 1;
    fin = f;
  }
  __syncthreads();
  if (fin) {
    __threadfence();
    if (t < 64) {
      double v = 0.0;
      for (int k = t; k < 256; k += 64) v += partd[k];
#pragma unroll
      for (int k = 32; k >= 1; k >>= 1) v += __shfl_xor(v, k);
      if (t == 0) out[0] = (float)v;
    }
  }
}

extern "C" void kernel_launch(void* const* d_in, const int* in_sizes, int n_in,
                              void* d_out, int out_size, void* d_ws, size_t ws_size,
                              hipStream_t stream) {
  (void)in_sizes; (void)n_in; (void)out_size;
  const int* labels = (const int*)d_in[0];
  const float* A = (const float*)d_in[1];
  const float* B = (const float*)d_in[2];
  const float* Pi = (const float*)d_in[3];
  const float* SP = (const float*)d_in[4];
  float* ws = (float*)d_ws;
  float* out = (float*)d_out;

  // ws_size is constant across calls -> host branch is graph-capture-safe.
  if (ws_size >= WS_NEED_BYTES) {
    hipLaunchKernelGGL(k_up_p, dim3(256), dim3(512), 0, stream,
                       labels, A, B, Pi, SP, ws);
    hipLaunchKernelGGL(k_down_p, dim3(256), dim3(512), 0, stream,
                       labels, ws, ws, out);
  } else {
    hipLaunchKernelGGL(k_up_f, dim3(256), dim3(256), 0, stream,
                       labels, A, B, Pi, SP, ws);
    hipLaunchKernelGGL(k_down_f, dim3(256), dim3(512), 0, stream,
                       labels, A, B, Pi, SP, ws, out);
  }
}

// Round 10
// 95.105 us; speedup vs baseline: 1.5041x; 1.0561x over previous
//
#include <hip/hip_runtime.h>

// HTMM: C=32 states, L=4 fanout, M=128 symbols, DEPTH=7.
// Level starts: {0,1,5,21,85,341,1365,5461,21845}.
// R22 = R21 with three more BITWISE-PRESERVING latency cuts in k_down_p:
// (1) float4-vectorized LDS staging (asp/smB/tbS/sPt/ownb were scalar,
//     ~19 lgkm-queued loads/thread at the head of the serial chain);
// (2) P3's two L3 rounds de-serialized: disjoint staging rows (scr grown
//     to 10240 f, LDS 75KB < 160KB, still 1 block/CU) remove the false WAR
//     dependency -> both 32-step FMA chains interleave (~2x ILP);
// (3) P5 step gating: grp1 stops after step 1, grp2 after step 2 -- the
//     slowest (owner s&3==0) blocks' wave 1 no longer serializes grp2's
//     useless WONLY behind grp3's WU at step 3.
// All per-value FMA/rsum orders unchanged -> absmax stays 0.
// Bench decomposition (R20/R21 rocprof): harness workspace re-poison fill
// ~39.4us + fixed ~15us + kernels ~45us; this round attacks the kernels.

static constexpr int OFF_B4   = 0;      // level-4 betas [s*32+i] (8192 f)
static constexpr int OFF_PART = 8192;   // 256 doubles (512 f)
static constexpr int IC2      = 9760;   // 16 finalize counters, stride 32 ints
static constexpr int IROOT2   = 10272;  // finalize root counter
static constexpr int OFF_ASP  = 10304;  // asp, stride-132 layout (4224 f)
static constexpr int OFF_RB   = 14528;  // smB^T linear (4224 f)
static constexpr int OFF_LRB  = 18752;  // log smB^T (4224 f)
static constexpr int OFF_LSP  = 22976;  // log sPt (132 f, +pad)
static constexpr int OFF_ALG  = 23120;  // ALG rows [J*128+lane*4] (4096 f)
static constexpr int OFF_TBO  = 27216;  // per-block tbS, stride 672 (172032 f)
static constexpr size_t WS_NEED_BYTES = (size_t)(OFF_TBO + 256 * 672) * 4;

__device__ __forceinline__ float rsum32(float v) {
#pragma unroll
  for (int k = 1; k <= 16; k <<= 1) v += __shfl_xor(v, k);
  return v;
}
__device__ __forceinline__ void rsum32x2(float& a, float& b) {
#pragma unroll
  for (int k = 1; k <= 16; k <<= 1) { a += __shfl_xor(a, k); b += __shfl_xor(b, k); }
}
__device__ __forceinline__ void rsum32x4(float& a, float& b, float& c, float& d) {
#pragma unroll
  for (int k = 1; k <= 16; k <<= 1) {
    a += __shfl_xor(a, k); b += __shfl_xor(b, k);
    c += __shfl_xor(c, k); d += __shfl_xor(d, k);
  }
}
__device__ __forceinline__ float4 exp4f(float4 v) {
  return make_float4(__expf(v.x), __expf(v.y), __expf(v.z), __expf(v.w));
}

// ---------------- register-file W matrix: 32 named float4 ----------------
#define W_DECL float4 Wr0, Wr1, Wr2, Wr3, Wr4, Wr5, Wr6, Wr7, Wr8, Wr9,     \
    Wr10, Wr11, Wr12, Wr13, Wr14, Wr15, Wr16, Wr17, Wr18, Wr19, Wr20, Wr21, \
    Wr22, Wr23, Wr24, Wr25, Wr26, Wr27, Wr28, Wr29, Wr30, Wr31;

#define REPW(X) X(0,Wr0) X(1,Wr1) X(2,Wr2) X(3,Wr3) X(4,Wr4) X(5,Wr5)       \
    X(6,Wr6) X(7,Wr7) X(8,Wr8) X(9,Wr9) X(10,Wr10) X(11,Wr11) X(12,Wr12)    \
    X(13,Wr13) X(14,Wr14) X(15,Wr15) X(16,Wr16) X(17,Wr17) X(18,Wr18)       \
    X(19,Wr19) X(20,Wr20) X(21,Wr21) X(22,Wr22) X(23,Wr23) X(24,Wr24)       \
    X(25,Wr25) X(26,Wr26) X(27,Wr27) X(28,Wr28) X(29,Wr29) X(30,Wr30)       \
    X(31,Wr31)

#define REPQ(X) X(0,Wr0,Wr1,Wr2,Wr3) X(1,Wr4,Wr5,Wr6,Wr7)                   \
    X(2,Wr8,Wr9,Wr10,Wr11) X(3,Wr12,Wr13,Wr14,Wr15) X(4,Wr16,Wr17,Wr18,Wr19)\
    X(5,Wr20,Wr21,Wr22,Wr23) X(6,Wr24,Wr25,Wr26,Wr27) X(7,Wr28,Wr29,Wr30,Wr31)

// load up-orientation row (lane) from scr (stride 132)
#define WLD_B(J, WJ) WJ = *(const float4*)(scrW_ + 4 * (J));
#define W_LOADUP { const float* scrW_ = scr + lane * 132; REPW(WLD_B) }

// load down-orientation from persisted asp table in ws (row J, cols 4lane..)
#define WLDDN_B(J, WJ) WJ = *(const float4*)(wsASP_ + (J) * 132 + lane * 4);

// tb = dot(W_row_lane, X[0..127])
#define DOT_B(J, WJ) { const float4 x_ = *(const float4*)(dXp_ + 4 * (J));   \
    dt0_ = fmaf(WJ.x, x_.x, dt0_); dt1_ = fmaf(WJ.y, x_.y, dt1_);            \
    dt2_ = fmaf(WJ.z, x_.z, dt2_); dt3_ = fmaf(WJ.w, x_.w, dt3_); }
#define DOT128M(OUT, XP) { const float* dXp_ = (XP);                         \
    float dt0_ = 0.f, dt1_ = 0.f, dt2_ = 0.f, dt3_ = 0.f;                    \
    REPW(DOT_B) (OUT) = (dt0_ + dt1_) + (dt2_ + dt3_); }

// two parents, shared W row
#define DOTX2_B(J, WJ) {                                                     \
    const float4 x_ = *(const float4*)(dXp0_ + 4 * (J));                     \
    const float4 y_ = *(const float4*)(dXp1_ + 4 * (J));                     \
    da0_ = fmaf(WJ.x, x_.x, da0_); db0_ = fmaf(WJ.x, y_.x, db0_);            \
    da1_ = fmaf(WJ.y, x_.y, da1_); db1_ = fmaf(WJ.y, y_.y, db1_);            \
    da2_ = fmaf(WJ.z, x_.z, da2_); db2_ = fmaf(WJ.z, y_.z, db2_);            \
    da3_ = fmaf(WJ.w, x_.w, da3_); db3_ = fmaf(WJ.w, y_.w, db3_); }
#define DOT128X2M(O0, O1, XP0, XP1) {                                        \
    const float* dXp0_ = (XP0); const float* dXp1_ = (XP1);                  \
    float da0_ = 0.f, da1_ = 0.f, da2_ = 0.f, da3_ = 0.f;                    \
    float db0_ = 0.f, db1_ = 0.f, db2_ = 0.f, db3_ = 0.f;                    \
    REPW(DOTX2_B) (O0) = (da0_ + da1_) + (da2_ + da3_);                      \
    (O1) = (db0_ + db1_) + (db2_ + db3_); }

// path walk: w only.  w_l += W[i].l * rb[i]
#define WO_B(Q, WA, WB, WC, WD) {                                            \
    const float4 rv_ = *(const float4*)(rbp_ + 4 * (Q));                     \
    ww0_ = fmaf(WA.x, rv_.x, ww0_); ww1_ = fmaf(WA.y, rv_.x, ww1_);          \
    ww2_ = fmaf(WA.z, rv_.x, ww2_); ww3_ = fmaf(WA.w, rv_.x, ww3_);          \
    ww0_ = fmaf(WB.x, rv_.y, ww0_); ww1_ = fmaf(WB.y, rv_.y, ww1_);          \
    ww2_ = fmaf(WB.z, rv_.y, ww2_); ww3_ = fmaf(WB.w, rv_.y, ww3_);          \
    ww0_ = fmaf(WC.x, rv_.z, ww0_); ww1_ = fmaf(WC.y, rv_.z, ww1_);          \
    ww2_ = fmaf(WC.z, rv_.z, ww2_); ww3_ = fmaf(WC.w, rv_.z, ww3_);          \
    ww0_ = fmaf(WD.x, rv_.w, ww0_); ww1_ = fmaf(WD.y, rv_.w, ww1_);          \
    ww2_ = fmaf(WD.z, rv_.w, ww2_); ww3_ = fmaf(WD.w, rv_.w, ww3_); }
#define WONLY128M(W, RBP) { const float* rbp_ = (RBP);                       \
    float ww0_ = 0.f, ww1_ = 0.f, ww2_ = 0.f, ww3_ = 0.f;                    \
    REPQ(WO_B) (W)[0] = ww0_; (W)[1] = ww1_; (W)[2] = ww2_; (W)[3] = ww3_; }

// w + u (u from ALG rows in scr)
#define WU_SUB(ROW, WX, RC) {                                                \
    const float4 av_ = *(const float4*)(ALGp_ + (ROW) * 128);                \
    ww0_ = fmaf(WX.x, RC, ww0_); uu0_ = fmaf(av_.x, RC, uu0_);               \
    ww1_ = fmaf(WX.y, RC, ww1_); uu1_ = fmaf(av_.y, RC, uu1_);               \
    ww2_ = fmaf(WX.z, RC, ww2_); uu2_ = fmaf(av_.z, RC, uu2_);               \
    ww3_ = fmaf(WX.w, RC, ww3_); uu3_ = fmaf(av_.w, RC, uu3_); }
#define WU_B(Q, WA, WB, WC, WD) {                                            \
    const float4 rv_ = *(const float4*)(rbp_ + 4 * (Q));                     \
    WU_SUB(4 * (Q) + 0, WA, rv_.x) WU_SUB(4 * (Q) + 1, WB, rv_.y)            \
    WU_SUB(4 * (Q) + 2, WC, rv_.z) WU_SUB(4 * (Q) + 3, WD, rv_.w) }
#define WU128M(W, U, RBP) { const float* rbp_ = (RBP);                       \
    const float* ALGp_ = scr + lane * 4;                                     \
    float ww0_ = 0.f, ww1_ = 0.f, ww2_ = 0.f, ww3_ = 0.f;                    \
    float uu0_ = 0.f, uu1_ = 0.f, uu2_ = 0.f, uu3_ = 0.f;                    \
    REPQ(WU_B) (W)[0] = ww0_; (W)[1] = ww1_; (W)[2] = ww2_; (W)[3] = ww3_;   \
    (U)[0] = uu0_; (U)[1] = uu1_; (U)[2] = uu2_; (U)[3] = uu3_; }

// two parents share the ALG read stream
#define WUX2_SUB(ROW, WX, RC0, RC1) {                                        \
    const float4 av_ = *(const float4*)(ALGp_ + (ROW) * 128);                \
    wa0_ = fmaf(WX.x, RC0, wa0_); wb0_ = fmaf(WX.x, RC1, wb0_);              \
    ua0_ = fmaf(av_.x, RC0, ua0_); ub0_ = fmaf(av_.x, RC1, ub0_);            \
    wa1_ = fmaf(WX.y, RC0, wa1_); wb1_ = fmaf(WX.y, RC1, wb1_);              \
    ua1_ = fmaf(av_.y, RC0, ua1_); ub1_ = fmaf(av_.y, RC1, ub1_);            \
    wa2_ = fmaf(WX.z, RC0, wa2_); wb2_ = fmaf(WX.z, RC1, wb2_);              \
    ua2_ = fmaf(av_.z, RC0, ua2_); ub2_ = fmaf(av_.z, RC1, ub2_);            \
    wa3_ = fmaf(WX.w, RC0, wa3_); wb3_ = fmaf(WX.w, RC1, wb3_);              \
    ua3_ = fmaf(av_.w, RC0, ua3_); ub3_ = fmaf(av_.w, RC1, ub3_); }
#define WUX2_B(Q, WA, WB, WC, WD) {                                          \
    const float4 rv0_ = *(const float4*)(rbp0_ + 4 * (Q));                   \
    const float4 rv1_ = *(const float4*)(rbp1_ + 4 * (Q));                   \
    WUX2_SUB(4 * (Q) + 0, WA, rv0_.x, rv1_.x)                                \
    WUX2_SUB(4 * (Q) + 1, WB, rv0_.y, rv1_.y)                                \
    WUX2_SUB(4 * (Q) + 2, WC, rv0_.z, rv1_.z)                                \
    WUX2_SUB(4 * (Q) + 3, WD, rv0_.w, rv1_.w) }
#define WU128X2M(W0, U0, W1, U1, RBP0, RBP1) {                               \
    const float* rbp0_ = (RBP0); const float* rbp1_ = (RBP1);                \
    const float* ALGp_ = scr + lane * 4;                                     \
    float wa0_ = 0.f, wa1_ = 0.f, wa2_ = 0.f, wa3_ = 0.f;                    \
    float ua0_ = 0.f, ua1_ = 0.f, ua2_ = 0.f, ua3_ = 0.f;                    \
    float wb0_ = 0.f, wb1_ = 0.f, wb2_ = 0.f, wb3_ = 0.f;                    \
    float ub0_ = 0.f, ub1_ = 0.f, ub2_ = 0.f, ub3_ = 0.f;                    \
    REPQ(WUX2_B)                                                             \
    (W0)[0] = wa0_; (W0)[1] = wa1_; (W0)[2] = wa2_; (W0)[3] = wa3_;          \
    (U0)[0] = ua0_; (U0)[1] = ua1_; (U0)[2] = ua2_; (U0)[3] = ua3_;          \
    (W1)[0] = wb0_; (W1)[1] = wb1_; (W1)[2] = wb2_; (W1)[3] = wb3_;          \
    (U1)[0] = ub0_; (U1)[1] = ub1_; (U1)[2] = ub2_; (U1)[3] = ub3_; }

// phase-4 rebuild (FALLBACK k_down only): W -> down orient; ALG into scr
#define WRD_B(J, WJ) { const float4 av = A4[(J) * 32 + lane];                \
    const float4 e = exp4f(av);                                              \
    const float4 asp = make_float4(e.x * inv4.x, e.y * inv4.y,               \
                                   e.z * inv4.z, e.w * inv4.w);              \
    WJ = asp;                                                                \
    if (grp == ((J) >> 1))                                                   \
      *(float4*)(scr + (J) * 128 + lane * 4) =                               \
          make_float4(asp.x * (av.x - sub4.x), asp.y * (av.y - sub4.y),      \
                      asp.z * (av.z - sub4.z), asp.w * (av.w - sub4.w)); }

// ======================================================================
// ===================== FALLBACK PATH (R18, proven) ====================
// ======================================================================
__global__ __launch_bounds__(256, 1) void k_up_f(const int* __restrict__ labels,
                                                 const float* __restrict__ A,
                                                 const float* __restrict__ B,
                                                 const float* __restrict__ Pi,
                                                 const float* __restrict__ SP,
                                                 float* __restrict__ ws) {
  __shared__ __align__(16) float scr[4224];
  __shared__ __align__(16) float regB[4224];
  __shared__ __align__(16) float sPt[132];
  __shared__ int labs[425];
  const int t = threadIdx.x, lane = t & 31, grp = t >> 5;
  const int s = blockIdx.x;
  int* wsi = (int*)ws;
  const float4* A4 = (const float4*)A;
  const float4* B4 = (const float4*)B;

  if (t < 16) wsi[IC2 + 32 * t] = 0;
  else if (t == 16) wsi[IROOT2] = 0;

  const float sv0 = SP[0], sv1 = SP[1], sv2 = SP[2], sv3 = SP[3];
  const float sp0 = __expf(sv0), sp1 = __expf(sv1), sp2 = __expf(sv2), sp3 = __expf(sv3);
  const float spsum = sp0 + sp1 + sp2 + sp3;
  const float spinv = 1.f / spsum;
  float4 c4 = make_float4(0.f, 0.f, 0.f, 0.f);
  for (int i = 0; i < 32; ++i) {
    const float4 e = exp4f(A4[i * 32 + lane]);
    c4.x += e.x; c4.y += e.y; c4.z += e.z; c4.w += e.w;
  }
  const float4 inv4 = make_float4(sp0 * spinv / c4.x, sp1 * spinv / c4.y,
                                  sp2 * spinv / c4.z, sp3 * spinv / c4.w);
#pragma unroll
  for (int k = 0; k < 4; ++k) {
    const int i = grp * 4 + k;
    const float4 e = exp4f(A4[i * 32 + lane]);
    *(float4*)(scr + i * 132 + 4 * lane) =
        make_float4(e.x * inv4.x, e.y * inv4.y, e.z * inv4.z, e.w * inv4.w);
  }
#pragma unroll
  for (int rI = 0; rI < 4; ++rI) {
    const int i = grp + rI * 8;
    const float4 e = exp4f(B4[i * 32 + lane]);
    const float sinv = 1.f / rsum32(e.x + e.y + e.z + e.w);
    regB[(4 * lane + 0) * 33 + i] = e.x * sinv;
    regB[(4 * lane + 1) * 33 + i] = e.y * sinv;
    regB[(4 * lane + 2) * 33 + i] = e.z * sinv;
    regB[(4 * lane + 3) * 33 + i] = e.w * sinv;
  }
  if (grp < 4) {
    const float e = __expf(Pi[lane * 4 + grp]);
    sPt[grp * 33 + lane] = e / rsum32(e);
  }
  if (t < 84) {
    int g, d;
    if (t < 4) { g = 341 + 4 * s + t; d = 341 + t; }
    else if (t < 20) { g = 1365 + 16 * s + (t - 4); d = 345 + (t - 4); }
    else { g = 5461 + 64 * s + (t - 20); d = 361 + (t - 20); }
    labs[d] = labels[g];
  }
  if (t == 84) labs[85 + (s & 255)] = labels[85 + s];
  __syncthreads();
  W_DECL
  W_LOADUP
  __syncthreads();

#pragma unroll
  for (int h = 0; h < 2; ++h) {
    const int q0 = grp + 32 * h, q1 = q0 + 8, q2 = q0 + 16, q3 = q0 + 24;
    float v0 = sPt[(q0 & 3) * 33 + lane] * regB[labs[361 + q0] * 33 + lane];
    float v1 = sPt[(q1 & 3) * 33 + lane] * regB[labs[361 + q1] * 33 + lane];
    float v2 = sPt[(q2 & 3) * 33 + lane] * regB[labs[361 + q2] * 33 + lane];
    float v3 = sPt[(q3 & 3) * 33 + lane] * regB[labs[361 + q3] * 33 + lane];
    float s0 = v0, s1 = v1, s2 = v2, s3 = v3;
    rsum32x4(s0, s1, s2, s3);
    scr[(q0 >> 2) * 128 + lane * 4 + (q0 & 3)] = v0 / s0;
    scr[(q1 >> 2) * 128 + lane * 4 + (q1 & 3)] = v1 / s1;
    scr[(q2 >> 2) * 128 + lane * 4 + (q2 & 3)] = v2 / s2;
    scr[(q3 >> 2) * 128 + lane * 4 + (q3 & 3)] = v3 / s3;
  }
  __syncthreads();
  {
    const int p0 = grp, p1 = grp + 8;
    float tb0, tb1;
    DOT128X2M(tb0, tb1, scr + p0 * 128, scr + p1 * 128)
    float bl0 = tb0 * regB[labs[345 + p0] * 33 + lane];
    float bl1 = tb1 * regB[labs[345 + p1] * 33 + lane];
    float s0 = bl0, s1 = bl1;
    rsum32x2(s0, s1);
    bl0 /= s0; bl1 /= s1;
    scr[2048 + (p0 >> 2) * 128 + lane * 4 + (p0 & 3)] = bl0;
    scr[2048 + (p1 >> 2) * 128 + lane * 4 + (p1 & 3)] = bl1;
  }
  __syncthreads();
  if (grp < 4) {
    float tb;
    DOT128M(tb, scr + 2048 + grp * 128)
    float bl = tb * regB[labs[341 + grp] * 33 + lane];
    bl /= rsum32(bl);
    scr[2560 + lane * 4 + grp] = bl;
  }
  __syncthreads();
  if (grp == 0) {
    float tb;
    DOT128M(tb, scr + 2560)
    float bl = tb * regB[labs[85 + (s & 255)] * 33 + lane];
    bl /= rsum32(bl);
    ws[OFF_B4 + s * 32 + lane] = bl;
  }
}

__global__ __launch_bounds__(512, 1)
void k_down_f(const int* __restrict__ labels,
              const float* __restrict__ A,
              const float* __restrict__ B,
              const float* __restrict__ Pi,
              const float* __restrict__ SP,
              float* __restrict__ ws,
              float* __restrict__ out) {
  __shared__ __align__(16) float scr[6144];
  __shared__ __align__(16) float regB[4224];
  __shared__ __align__(16) float sPt[132];
  __shared__ __align__(16) float tbrT[2720];
  __shared__ __align__(16) float tbS[672];
  __shared__ __align__(16) float ownb[32];
  __shared__ __align__(16) float r_buf[512];
  __shared__ int labs[425];
  __shared__ int fin;
  const int t = threadIdx.x, lane = t & 31, grp = t >> 5;
  const int s = blockIdx.x;
  int* wsi = (int*)ws;
  double* partd = (double*)(ws + OFF_PART);
  const float4* A4 = (const float4*)A;
  const float4* B4 = (const float4*)B;

  float pf0[8], pf1[8];
#pragma unroll
  for (int h = 0; h < 2; ++h) {
    const int p0 = grp + 32 * h, p1 = p0 + 16;
#pragma unroll
    for (int l = 0; l < 4; ++l) {
      pf0[h * 4 + l] = ws[OFF_B4 + (p0 * 4 + l) * 32 + lane];
      pf1[h * 4 + l] = ws[OFF_B4 + (p1 * 4 + l) * 32 + lane];
    }
  }

  const float sv0 = SP[0], sv1 = SP[1], sv2 = SP[2], sv3 = SP[3];
  const float sp0 = __expf(sv0), sp1 = __expf(sv1), sp2 = __expf(sv2), sp3 = __expf(sv3);
  const float spsum = sp0 + sp1 + sp2 + sp3;
  const float spinv = 1.f / spsum;
  const float lss = __logf(spsum);
  float4 c4 = make_float4(0.f, 0.f, 0.f, 0.f);
  for (int i = 0; i < 32; ++i) {
    const float4 e = exp4f(A4[i * 32 + lane]);
    c4.x += e.x; c4.y += e.y; c4.z += e.z; c4.w += e.w;
  }
  const float4 inv4 = make_float4(sp0 * spinv / c4.x, sp1 * spinv / c4.y,
                                  sp2 * spinv / c4.z, sp3 * spinv / c4.w);
  const float4 sub4 = make_float4(__logf(c4.x) - (sv0 - lss), __logf(c4.y) - (sv1 - lss),
                                  __logf(c4.z) - (sv2 - lss), __logf(c4.w) - (sv3 - lss));
#pragma unroll
  for (int k = 0; k < 2; ++k) {
    const int i = grp * 2 + k;
    const float4 e = exp4f(A4[i * 32 + lane]);
    *(float4*)(scr + i * 132 + 4 * lane) =
        make_float4(e.x * inv4.x, e.y * inv4.y, e.z * inv4.z, e.w * inv4.w);
  }
#pragma unroll
  for (int rI = 0; rI < 2; ++rI) {
    const int i = grp + rI * 16;
    const float4 e = exp4f(B4[i * 32 + lane]);
    const float sinv = 1.f / rsum32(e.x + e.y + e.z + e.w);
    regB[(4 * lane + 0) * 33 + i] = e.x * sinv;
    regB[(4 * lane + 1) * 33 + i] = e.y * sinv;
    regB[(4 * lane + 2) * 33 + i] = e.z * sinv;
    regB[(4 * lane + 3) * 33 + i] = e.w * sinv;
  }
  if (grp < 4) {
    const float e = __expf(Pi[lane * 4 + grp]);
    sPt[grp * 33 + lane] = e / rsum32(e);
  }
  for (int idx = t; idx < 341; idx += 512) labs[idx] = labels[idx];
  if (t < 84) {
    int g, d;
    if (t < 4) { g = 341 + 4 * s + t; d = 341 + t; }
    else if (t < 20) { g = 1365 + 16 * s + (t - 4); d = 345 + (t - 4); }
    else { g = 5461 + 64 * s + (t - 20); d = 361 + (t - 20); }
    labs[d] = labels[g];
  }
  __syncthreads();
  W_DECL
  W_LOADUP
  __syncthreads();

  {
    const int q0 = grp, q1 = grp + 16, q2 = grp + 32, q3 = grp + 48;
    float v0 = sPt[(q0 & 3) * 33 + lane] * regB[labs[361 + q0] * 33 + lane];
    float v1 = sPt[(q1 & 3) * 33 + lane] * regB[labs[361 + q1] * 33 + lane];
    float v2 = sPt[(q2 & 3) * 33 + lane] * regB[labs[361 + q2] * 33 + lane];
    float v3 = sPt[(q3 & 3) * 33 + lane] * regB[labs[361 + q3] * 33 + lane];
    float s0 = v0, s1 = v1, s2 = v2, s3 = v3;
    rsum32x4(s0, s1, s2, s3);
    scr[(q0 >> 2) * 128 + lane * 4 + (q0 & 3)] = v0 / s0;
    scr[(q1 >> 2) * 128 + lane * 4 + (q1 & 3)] = v1 / s1;
    scr[(q2 >> 2) * 128 + lane * 4 + (q2 & 3)] = v2 / s2;
    scr[(q3 >> 2) * 128 + lane * 4 + (q3 & 3)] = v3 / s3;
  }
  __syncthreads();
  if (grp < 8) {
    const int p0 = grp, p1 = grp + 8;
    float tb0, tb1;
    DOT128X2M(tb0, tb1, scr + p0 * 128, scr + p1 * 128)
    float bl0 = tb0 * regB[labs[345 + p0] * 33 + lane];
    float bl1 = tb1 * regB[labs[345 + p1] * 33 + lane];
    float s0 = bl0, s1 = bl1;
    rsum32x2(s0, s1);
    bl0 /= s0; bl1 /= s1;
    tbS[(5 + p0) * 32 + lane] = tb0;
    tbS[(5 + p1) * 32 + lane] = tb1;
    scr[2048 + (p0 >> 2) * 128 + lane * 4 + (p0 & 3)] = bl0;
    scr[2048 + (p1 >> 2) * 128 + lane * 4 + (p1 & 3)] = bl1;
  }
  __syncthreads();
  if (grp < 4) {
    float tb;
    DOT128M(tb, scr + 2048 + grp * 128)
    float bl = tb * regB[labs[341 + grp] * 33 + lane];
    bl /= rsum32(bl);
    tbS[(1 + grp) * 32 + lane] = tb;
    scr[2560 + lane * 4 + grp] = bl;
  }
  __syncthreads();
  if (grp == 0) {
    float tb;
    DOT128M(tb, scr + 2560)
    float bl = tb * regB[labs[85 + s] * 33 + lane];
    bl /= rsum32(bl);
    tbS[lane] = tb;
    ownb[lane] = bl;
  }
  __syncthreads();

#pragma unroll
  for (int h = 0; h < 2; ++h) {
    const int p0 = grp + 32 * h, p1 = p0 + 16;
    float* st0 = scr + grp * 128;
    float* st1 = scr + 2048 + grp * 128;
#pragma unroll
    for (int l = 0; l < 4; ++l) {
      st0[lane * 4 + l] = pf0[h * 4 + l];
      st1[lane * 4 + l] = pf1[h * 4 + l];
    }
    float tb0, tb1;
    DOT128X2M(tb0, tb1, st0, st1)
    float bl0 = tb0 * regB[labs[21 + p0] * 33 + lane];
    float bl1 = tb1 * regB[labs[21 + p1] * 33 + lane];
    float s0 = bl0, s1 = bl1;
    rsum32x2(s0, s1);
    bl0 /= s0; bl1 /= s1;
    tbrT[(21 + p0) * 32 + lane] = tb0;
    tbrT[(21 + p1) * 32 + lane] = tb1;
    scr[4096 + (p0 >> 2) * 128 + lane * 4 + (p0 & 3)] = bl0;
    scr[4096 + (p1 >> 2) * 128 + lane * 4 + (p1 & 3)] = bl1;
  }
  __syncthreads();
  {
    const int p = grp;
    float tb;
    DOT128M(tb, scr + 4096 + p * 128)
    float bl = tb * regB[labs[5 + p] * 33 + lane];
    bl /= rsum32(bl);
    tbrT[(5 + p) * 32 + lane] = tb;
    scr[(p >> 2) * 128 + lane * 4 + (p & 3)] = bl;
  }
  __syncthreads();
  if (grp < 4) {
    float tb;
    DOT128M(tb, scr + grp * 128)
    float bl = tb * regB[labs[1 + grp] * 33 + lane];
    bl /= rsum32(bl);
    tbrT[(1 + grp) * 32 + lane] = tb;
    scr[512 + lane * 4 + grp] = bl;
  }
  __syncthreads();
  if (grp == 0) { float tb; DOT128M(tb, scr + 512) tbrT[lane] = tb; }
  __syncthreads();

  for (int idx = t; idx < 4224; idx += 512) regB[idx] = __logf(regB[idx]);
  if (t < 132) sPt[t] = __logf(sPt[t]);
  REPW(WRD_B)
  __syncthreads();

  double ll = 0.0;
  float eps4own = 0.f;
  if (grp < 4) {
    const int n1 = 1 + (s >> 6), n2 = 5 + (s >> 4), n3 = 21 + (s >> 2);
    const int a0 = s >> 6, a1 = (s >> 4) & 3, a2 = (s >> 2) & 3, a3 = s & 3;
    float w[4], uv[4];
    float* rb = r_buf + grp * 32;

    float tbv = tbrT[lane];
    float bcv = tbv * __expf(regB[labs[0] * 33 + lane]);
    bcv /= rsum32(bcv);
    rb[lane] = bcv / tbv;
    if (grp == 0 && s == 0) {
      ll += (double)(bcv * regB[labs[0] * 33 + lane]);
      WU128M(w, uv, rb)
      const float lb0 = regB[labs[1] * 33 + lane], lb1 = regB[labs[2] * 33 + lane];
      const float lb2 = regB[labs[3] * 33 + lane], lb3 = regB[labs[4] * 33 + lane];
      float b0 = tbrT[1 * 32 + lane] * __expf(lb0);
      float b1 = tbrT[2 * 32 + lane] * __expf(lb1);
      float b2 = tbrT[3 * 32 + lane] * __expf(lb2);
      float b3 = tbrT[4 * 32 + lane] * __expf(lb3);
      float s0 = b0, s1 = b1, s2 = b2, s3 = b3;
      rsum32x4(s0, s1, s2, s3);
      b0 /= s0; b1 /= s1; b2 /= s2; b3 /= s3;
      ll += (double)(b0 * uv[0]) + (double)(b0 * w[0] * lb0);
      ll += (double)(b1 * uv[1]) + (double)(b1 * w[1] * lb1);
      ll += (double)(b2 * uv[2]) + (double)(b2 * w[2] * lb2);
      ll += (double)(b3 * uv[3]) + (double)(b3 * w[3] * lb3);
    } else {
      WONLY128M(w, rb)
    }

    tbv = tbrT[n1 * 32 + lane];
    bcv = tbv * __expf(regB[labs[n1] * 33 + lane]);
    bcv /= rsum32(bcv);
    rb[lane] = (bcv * w[a0]) / tbv;
    if (grp == 1 && (s & 63) == 0) {
      WU128M(w, uv, rb)
      const int cb = 5 + 4 * (s >> 6);
      const float lb0 = regB[labs[cb + 0] * 33 + lane], lb1 = regB[labs[cb + 1] * 33 + lane];
      const float lb2 = regB[labs[cb + 2] * 33 + lane], lb3 = regB[labs[cb + 3] * 33 + lane];
      float b0 = tbrT[(cb + 0) * 32 + lane] * __expf(lb0);
      float b1 = tbrT[(cb + 1) * 32 + lane] * __expf(lb1);
      float b2 = tbrT[(cb + 2) * 32 + lane] * __expf(lb2);
      float b3 = tbrT[(cb + 3) * 32 + lane] * __expf(lb3);
      float s0 = b0, s1 = b1, s2 = b2, s3 = b3;
      rsum32x4(s0, s1, s2, s3);
      b0 /= s0; b1 /= s1; b2 /= s2; b3 /= s3;
      ll += (double)(b0 * uv[0]) + (double)(b0 * w[0] * lb0);
      ll += (double)(b1 * uv[1]) + (double)(b1 * w[1] * lb1);
      ll += (double)(b2 * uv[2]) + (double)(b2 * w[2] * lb2);
      ll += (double)(b3 * uv[3]) + (double)(b3 * w[3] * lb3);
    } else {
      WONLY128M(w, rb)
    }

    tbv = tbrT[n2 * 32 + lane];
    bcv = tbv * __expf(regB[labs[n2] * 33 + lane]);
    bcv /= rsum32(bcv);
    rb[lane] = (bcv * w[a1]) / tbv;
    if (grp == 2 && (s & 15) == 0) {
      WU128M(w, uv, rb)
      const int cb = 21 + 4 * (s >> 4);
      const float lb0 = regB[labs[cb + 0] * 33 + lane], lb1 = regB[labs[cb + 1] * 33 + lane];
      const float lb2 = regB[labs[cb + 2] * 33 + lane], lb3 = regB[labs[cb + 3] * 33 + lane];
      float b0 = tbrT[(cb + 0) * 32 + lane] * __expf(lb0);
      float b1 = tbrT[(cb + 1) * 32 + lane] * __expf(lb1);
      float b2 = tbrT[(cb + 2) * 32 + lane] * __expf(lb2);
      float b3 = tbrT[(cb + 3) * 32 + lane] * __expf(lb3);
      float s0 = b0, s1 = b1, s2 = b2, s3 = b3;
      rsum32x4(s0, s1, s2, s3);
      b0 /= s0; b1 /= s1; b2 /= s2; b3 /= s3;
      ll += (double)(b0 * uv[0]) + (double)(b0 * w[0] * lb0);
      ll += (double)(b1 * uv[1]) + (double)(b1 * w[1] * lb1);
      ll += (double)(b2 * uv[2]) + (double)(b2 * w[2] * lb2);
      ll += (double)(b3 * uv[3]) + (double)(b3 * w[3] * lb3);
    } else {
      WONLY128M(w, rb)
    }

    tbv = tbrT[n3 * 32 + lane];
    bcv = tbv * __expf(regB[labs[n3] * 33 + lane]);
    bcv /= rsum32(bcv);
    rb[lane] = (bcv * w[a2]) / tbv;
    if (grp == 3 && (s & 3) == 0) {
      WU128M(w, uv, rb)
      const int cb = s & ~3;
#pragma unroll
      for (int l = 0; l < 4; ++l) {
        const int ci = cb + l;
        const float bc = ws[OFF_B4 + ci * 32 + lane];
        const float e = bc * w[l];
        ll += (double)(bc * uv[l]) + (double)(e * regB[labs[85 + ci] * 33 + lane]);
      }
    } else {
      WONLY128M(w, rb)
    }
    eps4own = ownb[lane] * w[a3];
  }
  __syncthreads();

  if (grp == 0) {
    r_buf[lane] = eps4own / tbS[lane];
    float w[4], u[4];
    WU128M(w, u, r_buf)
#pragma unroll
    for (int l = 0; l < 4; ++l) {
      const int lab = labs[341 + l];
      const float tbv = tbS[(1 + l) * 32 + lane];
      float bcv = tbv * __expf(regB[lab * 33 + lane]);
      bcv /= rsum32(bcv);
      const float e = bcv * w[l];
      ll += (double)(bcv * u[l]) + (double)(e * regB[lab * 33 + lane]);
      tbS[(1 + l) * 32 + lane] = e / tbv;
    }
  }
  __syncthreads();
  if (grp < 4) {
    const int p = grp;
    r_buf[p * 32 + lane] = tbS[(1 + p) * 32 + lane];
    float w[4], u[4];
    WU128M(w, u, r_buf + p * 32)
#pragma unroll
    for (int l = 0; l < 4; ++l) {
      const int q = p * 4 + l;
      const int lab = labs[345 + q];
      const float tbv = tbS[(5 + q) * 32 + lane];
      float bcv = tbv * __expf(regB[lab * 33 + lane]);
      bcv /= rsum32(bcv);
      const float e = bcv * w[l];
      ll += (double)(bcv * u[l]) + (double)(e * regB[lab * 33 + lane]);
      tbS[(5 + q) * 32 + lane] = e / tbv;
    }
  }
  __syncthreads();
  if (grp < 8) {
    const int p0 = grp, p1 = grp + 8;
    float* rb0 = r_buf + grp * 32;
    float* rb1 = r_buf + 256 + grp * 32;
    rb0[lane] = tbS[(5 + p0) * 32 + lane];
    rb1[lane] = tbS[(5 + p1) * 32 + lane];
    float w0[4], u0[4], w1[4], u1[4];
    WU128X2M(w0, u0, w1, u1, rb0, rb1)
#pragma unroll
    for (int l = 0; l < 4; ++l) {
      const int q0 = p0 * 4 + l, q1 = p1 * 4 + l;
      const float lb0 = regB[labs[361 + q0] * 33 + lane];
      const float lb1 = regB[labs[361 + q1] * 33 + lane];
      const float lp = sPt[l * 33 + lane];
      float b0 = __expf(lp + lb0);
      float b1 = __expf(lp + lb1);
      float s0 = b0, s1 = b1;
      rsum32x2(s0, s1);
      b0 /= s0; b1 /= s1;
      const float e0 = b0 * w0[l], e1 = b1 * w1[l];
      ll += (double)(b0 * u0[l]) + (double)(e0 * lb0) + (double)(e0 * lp);
      ll += (double)(b1 * u1[l]) + (double)(e1 * lb1) + (double)(e1 * lp);
    }
  }

#pragma unroll
  for (int k = 32; k >= 1; k >>= 1) ll += __shfl_xor(ll, k);
  double* rbd = (double*)r_buf;
  __syncthreads();
  if ((t & 63) == 0) rbd[t >> 6] = ll;
  __syncthreads();
  if (t == 0) {
    partd[s] = ((rbd[0] + rbd[1]) + (rbd[2] + rbd[3])) +
               ((rbd[4] + rbd[5]) + (rbd[6] + rbd[7]));
    __threadfence();
    int f = 0;
    if (atomicAdd(&wsi[IC2 + 32 * (s >> 4)], 1) == 15)
      if (atomicAdd(&wsi[IROOT2], 1) == 15) f = 1;
    fin = f;
  }
  __syncthreads();
  if (fin) {
    __threadfence();
    if (t < 64) {
      double v = 0.0;
      for (int k = t; k < 256; k += 64) v += partd[k];
#pragma unroll
      for (int k = 32; k >= 1; k >>= 1) v += __shfl_xor(v, k);
      if (t == 0) out[0] = (float)v;
    }
  }
}

// ======================================================================
// ================= PERSIST PATH (R21 design + R22 cuts) ===============
// ======================================================================
__global__ __launch_bounds__(512, 1) void k_up_p(const int* __restrict__ labels,
                                                 const float* __restrict__ A,
                                                 const float* __restrict__ B,
                                                 const float* __restrict__ Pi,
                                                 const float* __restrict__ SP,
                                                 float* __restrict__ ws) {
  __shared__ __align__(16) float scr[4224];
  __shared__ __align__(16) float regB[4224];
  __shared__ __align__(16) float sPt[132];
  __shared__ int labs[425];
  const int t = threadIdx.x, lane = t & 31, grp = t >> 5;  // 16 groups
  const int s = blockIdx.x;
  int* wsi = (int*)ws;
  const float4* A4 = (const float4*)A;
  const float4* B4 = (const float4*)B;

  if (t < 16) wsi[IC2 + 32 * t] = 0;
  else if (t == 16) wsi[IROOT2] = 0;

  const float sv0 = SP[0], sv1 = SP[1], sv2 = SP[2], sv3 = SP[3];
  const float sp0 = __expf(sv0), sp1 = __expf(sv1), sp2 = __expf(sv2), sp3 = __expf(sv3);
  const float spsum = sp0 + sp1 + sp2 + sp3;
  const float spinv = 1.f / spsum;
  const float lss = __logf(spsum);
  float4 c4 = make_float4(0.f, 0.f, 0.f, 0.f);
  for (int i = 0; i < 32; ++i) {
    const float4 e = exp4f(A4[i * 32 + lane]);
    c4.x += e.x; c4.y += e.y; c4.z += e.z; c4.w += e.w;
  }
  const float4 inv4 = make_float4(sp0 * spinv / c4.x, sp1 * spinv / c4.y,
                                  sp2 * spinv / c4.z, sp3 * spinv / c4.w);
  const float4 sub4 = make_float4(__logf(c4.x) - (sv0 - lss), __logf(c4.y) - (sv1 - lss),
                                  __logf(c4.z) - (sv2 - lss), __logf(c4.w) - (sv3 - lss));
#pragma unroll
  for (int k = 0; k < 2; ++k) {
    const int i = grp * 2 + k;
    const float4 e = exp4f(A4[i * 32 + lane]);
    *(float4*)(scr + i * 132 + 4 * lane) =
        make_float4(e.x * inv4.x, e.y * inv4.y, e.z * inv4.z, e.w * inv4.w);
  }
#pragma unroll
  for (int rI = 0; rI < 2; ++rI) {
    const int i = grp + rI * 16;
    const float4 e = exp4f(B4[i * 32 + lane]);
    const float sinv = 1.f / rsum32(e.x + e.y + e.z + e.w);
    regB[(4 * lane + 0) * 33 + i] = e.x * sinv;
    regB[(4 * lane + 1) * 33 + i] = e.y * sinv;
    regB[(4 * lane + 2) * 33 + i] = e.z * sinv;
    regB[(4 * lane + 3) * 33 + i] = e.w * sinv;
  }
  if (grp < 4) {
    const float e = __expf(Pi[lane * 4 + grp]);
    sPt[grp * 33 + lane] = e / rsum32(e);
  } else if (grp == 4) {  // fill the 4 gap slots so persisted logs are finite
    if (lane < 4) sPt[lane * 33 + 32] = 1.f;
  }
  if (t < 84) {
    int g, d;
    if (t < 4) { g = 341 + 4 * s + t; d = 341 + t; }
    else if (t < 20) { g = 1365 + 16 * s + (t - 4); d = 345 + (t - 4); }
    else { g = 5461 + 64 * s + (t - 20); d = 361 + (t - 20); }
    labs[d] = labels[g];
  }
  if (t == 84) labs[85 + (s & 255)] = labels[85 + s];
  __syncthreads();

  // ---------- block 0: persist block-independent tables ----------
  if (s == 0) {
    for (int idx = t; idx < 4224; idx += 512) {
      ws[OFF_ASP + idx] = scr[idx];
      const float v = regB[idx];
      ws[OFF_RB + idx] = v;
      ws[OFF_LRB + idx] = __logf(v);
    }
    if (t < 132) ws[OFF_LSP + t] = __logf(sPt[t]);
#pragma unroll
    for (int k = 0; k < 2; ++k) {
      const int i = grp * 2 + k;
      const float4 av = A4[i * 32 + lane];
      const float4 e = exp4f(av);
      const float4 asp = make_float4(e.x * inv4.x, e.y * inv4.y,
                                     e.z * inv4.z, e.w * inv4.w);
      *(float4*)(ws + OFF_ALG + i * 128 + lane * 4) =
          make_float4(asp.x * (av.x - sub4.x), asp.y * (av.y - sub4.y),
                      asp.z * (av.z - sub4.z), asp.w * (av.w - sub4.w));
    }
  }
  W_DECL
  W_LOADUP
  __syncthreads();

  // ---------- phase 2: subtree up sweep; persist tbS rows + b4 ----------
  float* tbs = ws + OFF_TBO + s * 672;
  {
    const int q0 = grp, q1 = grp + 16, q2 = grp + 32, q3 = grp + 48;
    float v0 = sPt[(q0 & 3) * 33 + lane] * regB[labs[361 + q0] * 33 + lane];
    float v1 = sPt[(q1 & 3) * 33 + lane] * regB[labs[361 + q1] * 33 + lane];
    float v2 = sPt[(q2 & 3) * 33 + lane] * regB[labs[361 + q2] * 33 + lane];
    float v3 = sPt[(q3 & 3) * 33 + lane] * regB[labs[361 + q3] * 33 + lane];
    float s0 = v0, s1 = v1, s2 = v2, s3 = v3;
    rsum32x4(s0, s1, s2, s3);
    scr[(q0 >> 2) * 128 + lane * 4 + (q0 & 3)] = v0 / s0;
    scr[(q1 >> 2) * 128 + lane * 4 + (q1 & 3)] = v1 / s1;
    scr[(q2 >> 2) * 128 + lane * 4 + (q2 & 3)] = v2 / s2;
    scr[(q3 >> 2) * 128 + lane * 4 + (q3 & 3)] = v3 / s3;
  }
  __syncthreads();
  {  // S2: 16 L6 parents, ONE per group
    const int p = grp;
    float tb;
    DOT128M(tb, scr + p * 128)
    float bl = tb * regB[labs[345 + p] * 33 + lane];
    bl /= rsum32(bl);
    tbs[(5 + p) * 32 + lane] = tb;
    scr[2048 + (p >> 2) * 128 + lane * 4 + (p & 3)] = bl;  // X6
  }
  __syncthreads();
  if (grp < 4) {
    float tb;
    DOT128M(tb, scr + 2048 + grp * 128)
    float bl = tb * regB[labs[341 + grp] * 33 + lane];
    bl /= rsum32(bl);
    tbs[(1 + grp) * 32 + lane] = tb;
    scr[2560 + lane * 4 + grp] = bl;
  }
  __syncthreads();
  if (grp == 0) {
    float tb;
    DOT128M(tb, scr + 2560)
    float bl = tb * regB[labs[85 + (s & 255)] * 33 + lane];
    bl /= rsum32(bl);
    tbs[lane] = tb;
    ws[OFF_B4 + s * 32 + lane] = bl;
  }
}

__global__ __launch_bounds__(512, 1)
void k_down_p(const int* __restrict__ labels,
              const float* __restrict__ ws_c,
              float* __restrict__ ws,
              float* __restrict__ out) {
  __shared__ __align__(16) float scr[10240];   // R22: 80 rows (P3 disjoint)
  __shared__ __align__(16) float regB[4224];
  __shared__ __align__(16) float sPt[132];
  __shared__ __align__(16) float tbrT[2720];
  __shared__ __align__(16) float tbS[672];
  __shared__ __align__(16) float ownb[32];
  __shared__ __align__(16) float r_buf[512];
  __shared__ int labs[425];
  __shared__ int fin;
  const int t = threadIdx.x, lane = t & 31, grp = t >> 5;  // 16 groups
  const int s = blockIdx.x;
  int* wsi = (int*)ws;
  double* partd = (double*)(ws + OFF_PART);
  (void)ws_c;

  // ---------- early prefetch: P3's b4 children ----------
  float pf0[8], pf1[8];
#pragma unroll
  for (int h = 0; h < 2; ++h) {
    const int p0 = grp + 32 * h, p1 = p0 + 16;
#pragma unroll
    for (int l = 0; l < 4; ++l) {
      pf0[h * 4 + l] = ws[OFF_B4 + (p0 * 4 + l) * 32 + lane];
      pf1[h * 4 + l] = ws[OFF_B4 + (p1 * 4 + l) * 32 + lane];
    }
  }
  // ---------- early prefetch: P4's ALG + logB tables into regs ----------
  const float4* wsALG4 = (const float4*)(ws + OFF_ALG);   // 1024 float4
  const float4* wsLRB4 = (const float4*)(ws + OFF_LRB);   // 1056 float4
  float4 pfA0 = wsALG4[t];
  float4 pfA1 = wsALG4[t + 512];
  float4 pfL0 = wsLRB4[t];
  float4 pfL1 = wsLRB4[t + 512];
  float4 pfL2 = make_float4(0.f, 0.f, 0.f, 0.f);
  if (t < 32) pfL2 = wsLRB4[t + 1024];

  // ---------- stage tables + per-block state from ws (R22: float4) ------
  {
    const float4* wsASP4 = (const float4*)(ws + OFF_ASP);  // 1056 float4
    const float4* wsRB4 = (const float4*)(ws + OFF_RB);    // 1056 float4
    float4* scr4 = (float4*)scr;
    float4* regB4 = (float4*)regB;
    scr4[t] = wsASP4[t];
    scr4[t + 512] = wsASP4[t + 512];
    regB4[t] = wsRB4[t];
    regB4[t + 512] = wsRB4[t + 512];
    if (t < 32) {
      scr4[t + 1024] = wsASP4[t + 1024];
      regB4[t + 1024] = wsRB4[t + 1024];
    }
    if (t < 33) ((float4*)sPt)[t] = ((const float4*)(ws + OFF_LSP))[t];
    if (t < 168) ((float4*)tbS)[t] = ((const float4*)(ws + OFF_TBO + s * 672))[t];
    if (t < 8) ((float4*)ownb)[t] = ((const float4*)(ws + OFF_B4 + s * 32))[t];
  }
  for (int idx = t; idx < 341; idx += 512) labs[idx] = labels[idx];
  if (t < 84) {
    int g, d;
    if (t < 4) { g = 341 + 4 * s + t; d = 341 + t; }
    else if (t < 20) { g = 1365 + 16 * s + (t - 4); d = 345 + (t - 4); }
    else { g = 5461 + 64 * s + (t - 20); d = 361 + (t - 20); }
    labs[d] = labels[g];
  }
  __syncthreads();
  W_DECL
  W_LOADUP
  __syncthreads();

  // ---------- phase 3: top up sweep (R22: rounds de-serialized) ----------
  // h=0 stages rows 0..31 (scr[0..4095]), h=1 rows 32..63 (scr[4096..8191]);
  // bX3 outputs rows 64..79 (scr[8192..10239]). Group-local LDS, no barrier
  // needed between stage and dot (wave-synchronous, as before).
  {
#pragma unroll
    for (int h = 0; h < 2; ++h) {
      float* st0 = scr + h * 4096 + grp * 128;
      float* st1 = scr + h * 4096 + 2048 + grp * 128;
#pragma unroll
      for (int l = 0; l < 4; ++l) {
        st0[lane * 4 + l] = pf0[h * 4 + l];
        st1[lane * 4 + l] = pf1[h * 4 + l];
      }
    }
    const int pA0 = grp, pA1 = grp + 16, pB0 = grp + 32, pB1 = grp + 48;
    float tbA0, tbA1, tbB0, tbB1;
    DOT128X2M(tbA0, tbA1, scr + grp * 128, scr + 2048 + grp * 128)
    DOT128X2M(tbB0, tbB1, scr + 4096 + grp * 128, scr + 4096 + 2048 + grp * 128)
    float blA0 = tbA0 * regB[labs[21 + pA0] * 33 + lane];
    float blA1 = tbA1 * regB[labs[21 + pA1] * 33 + lane];
    float blB0 = tbB0 * regB[labs[21 + pB0] * 33 + lane];
    float blB1 = tbB1 * regB[labs[21 + pB1] * 33 + lane];
    float sA0 = blA0, sA1 = blA1, sB0 = blB0, sB1 = blB1;
    rsum32x4(sA0, sA1, sB0, sB1);
    blA0 /= sA0; blA1 /= sA1; blB0 /= sB0; blB1 /= sB1;
    tbrT[(21 + pA0) * 32 + lane] = tbA0;
    tbrT[(21 + pA1) * 32 + lane] = tbA1;
    tbrT[(21 + pB0) * 32 + lane] = tbB0;
    tbrT[(21 + pB1) * 32 + lane] = tbB1;
    scr[8192 + (pA0 >> 2) * 128 + lane * 4 + (pA0 & 3)] = blA0;  // bX3
    scr[8192 + (pA1 >> 2) * 128 + lane * 4 + (pA1 & 3)] = blA1;
    scr[8192 + (pB0 >> 2) * 128 + lane * 4 + (pB0 & 3)] = blB0;
    scr[8192 + (pB1 >> 2) * 128 + lane * 4 + (pB1 & 3)] = blB1;
  }
  __syncthreads();
  {  // L2: 16 parents, one per group
    const int p = grp;
    float tb;
    DOT128M(tb, scr + 8192 + p * 128)
    float bl = tb * regB[labs[5 + p] * 33 + lane];
    bl /= rsum32(bl);
    tbrT[(5 + p) * 32 + lane] = tb;
    scr[(p >> 2) * 128 + lane * 4 + (p & 3)] = bl;  // bX2 rows 0..3
  }
  __syncthreads();
  if (grp < 4) {  // L1: 4 parents
    float tb;
    DOT128M(tb, scr + grp * 128)
    float bl = tb * regB[labs[1 + grp] * 33 + lane];
    bl /= rsum32(bl);
    tbrT[(1 + grp) * 32 + lane] = tb;
    scr[512 + lane * 4 + grp] = bl;  // bX1 (row 4)
  }
  __syncthreads();
  if (grp == 0) { float tb; DOT128M(tb, scr + 512) tbrT[lane] = tb; }
  __syncthreads();

  // ---------- phase 4 (slim): write prefetched ALG + logB; reload W ------
  ((float4*)scr)[t] = pfA0;
  ((float4*)scr)[t + 512] = pfA1;
  ((float4*)regB)[t] = pfL0;
  ((float4*)regB)[t + 512] = pfL1;
  if (t < 32) ((float4*)regB)[t + 1024] = pfL2;
  if (grp < 8) {
    const float* wsASP_ = ws + OFF_ASP;
    REPW(WLDDN_B)
  }
  __syncthreads();

  // ---------- phase 5: distributed owners, R22 step gating ----------
  double ll = 0.0;
  float eps4own = 0.f;  // valid in grp 0
  if (grp < 4) {
    const int n1 = 1 + (s >> 6), n2 = 5 + (s >> 4), n3 = 21 + (s >> 2);
    const int a0 = s >> 6, a1 = (s >> 4) & 3, a2 = (s >> 2) & 3, a3 = s & 3;
    float w[4], uv[4];
    float* rb = r_buf + grp * 32;

    // ---- step 0 (all grps 0-3) ----
    float tbv = tbrT[lane];
    float bcv = tbv * __expf(regB[labs[0] * 33 + lane]);
    bcv /= rsum32(bcv);
    rb[lane] = bcv / tbv;
    if (grp == 0 && s == 0) {
      ll += (double)(bcv * regB[labs[0] * 33 + lane]);
      WU128M(w, uv, rb)
      const float lb0 = regB[labs[1] * 33 + lane], lb1 = regB[labs[2] * 33 + lane];
      const float lb2 = regB[labs[3] * 33 + lane], lb3 = regB[labs[4] * 33 + lane];
      float b0 = tbrT[1 * 32 + lane] * __expf(lb0);
      float b1 = tbrT[2 * 32 + lane] * __expf(lb1);
      float b2 = tbrT[3 * 32 + lane] * __expf(lb2);
      float b3 = tbrT[4 * 32 + lane] * __expf(lb3);
      float s0 = b0, s1 = b1, s2 = b2, s3 = b3;
      rsum32x4(s0, s1, s2, s3);
      b0 /= s0; b1 /= s1; b2 /= s2; b3 /= s3;
      ll += (double)(b0 * uv[0]) + (double)(b0 * w[0] * lb0);
      ll += (double)(b1 * uv[1]) + (double)(b1 * w[1] * lb1);
      ll += (double)(b2 * uv[2]) + (double)(b2 * w[2] * lb2);
      ll += (double)(b3 * uv[3]) + (double)(b3 * w[3] * lb3);
    } else {
      WONLY128M(w, rb)
    }

    // ---- step 1 (all grps 0-3) ----
    tbv = tbrT[n1 * 32 + lane];
    bcv = tbv * __expf(regB[labs[n1] * 33 + lane]);
    bcv /= rsum32(bcv);
    rb[lane] = (bcv * w[a0]) / tbv;
    if (grp == 1 && (s & 63) == 0) {
      WU128M(w, uv, rb)
      const int cb = 5 + 4 * (s >> 6);
      const float lb0 = regB[labs[cb + 0] * 33 + lane], lb1 = regB[labs[cb + 1] * 33 + lane];
      const float lb2 = regB[labs[cb + 2] * 33 + lane], lb3 = regB[labs[cb + 3] * 33 + lane];
      float b0 = tbrT[(cb + 0) * 32 + lane] * __expf(lb0);
      float b1 = tbrT[(cb + 1) * 32 + lane] * __expf(lb1);
      float b2 = tbrT[(cb + 2) * 32 + lane] * __expf(lb2);
      float b3 = tbrT[(cb + 3) * 32 + lane] * __expf(lb3);
      float s0 = b0, s1 = b1, s2 = b2, s3 = b3;
      rsum32x4(s0, s1, s2, s3);
      b0 /= s0; b1 /= s1; b2 /= s2; b3 /= s3;
      ll += (double)(b0 * uv[0]) + (double)(b0 * w[0] * lb0);
      ll += (double)(b1 * uv[1]) + (double)(b1 * w[1] * lb1);
      ll += (double)(b2 * uv[2]) + (double)(b2 * w[2] * lb2);
      ll += (double)(b3 * uv[3]) + (double)(b3 * w[3] * lb3);
    } else {
      WONLY128M(w, rb)
    }

    // ---- step 2 (grps 0,2,3 -- grp 1 done) ----
    if (grp != 1) {
      tbv = tbrT[n2 * 32 + lane];
      bcv = tbv * __expf(regB[labs[n2] * 33 + lane]);
      bcv /= rsum32(bcv);
      rb[lane] = (bcv * w[a1]) / tbv;
      if (grp == 2 && (s & 15) == 0) {
        WU128M(w, uv, rb)
        const int cb = 21 + 4 * (s >> 4);
        const float lb0 = regB[labs[cb + 0] * 33 + lane], lb1 = regB[labs[cb + 1] * 33 + lane];
        const float lb2 = regB[labs[cb + 2] * 33 + lane], lb3 = regB[labs[cb + 3] * 33 + lane];
        float b0 = tbrT[(cb + 0) * 32 + lane] * __expf(lb0);
        float b1 = tbrT[(cb + 1) * 32 + lane] * __expf(lb1);
        float b2 = tbrT[(cb + 2) * 32 + lane] * __expf(lb2);
        float b3 = tbrT[(cb + 3) * 32 + lane] * __expf(lb3);
        float s0 = b0, s1 = b1, s2 = b2, s3 = b3;
        rsum32x4(s0, s1, s2, s3);
        b0 /= s0; b1 /= s1; b2 /= s2; b3 /= s3;
        ll += (double)(b0 * uv[0]) + (double)(b0 * w[0] * lb0);
        ll += (double)(b1 * uv[1]) + (double)(b1 * w[1] * lb1);
        ll += (double)(b2 * uv[2]) + (double)(b2 * w[2] * lb2);
        ll += (double)(b3 * uv[3]) + (double)(b3 * w[3] * lb3);
      } else {
        WONLY128M(w, rb)
      }
    }

    // ---- step 3 (grps 0,3 -- grp 2 done) ----
    if (grp == 0 || grp == 3) {
      tbv = tbrT[n3 * 32 + lane];
      bcv = tbv * __expf(regB[labs[n3] * 33 + lane]);
      bcv /= rsum32(bcv);
      rb[lane] = (bcv * w[a2]) / tbv;
      if (grp == 3 && (s & 3) == 0) {
        WU128M(w, uv, rb)
        const int cb = s & ~3;
#pragma unroll
        for (int l = 0; l < 4; ++l) {
          const int ci = cb + l;
          const float bc = ws[OFF_B4 + ci * 32 + lane];
          const float e = bc * w[l];
          ll += (double)(bc * uv[l]) + (double)(e * regB[labs[85 + ci] * 33 + lane]);
        }
      } else {
        WONLY128M(w, rb)
      }
      eps4own = ownb[lane] * w[a3];
    }
  }
  __syncthreads();

  // ---------- phase 6: subtree down sweep ----------
  if (grp == 0) {
    r_buf[lane] = eps4own / tbS[lane];
    float w[4], u[4];
    WU128M(w, u, r_buf)
#pragma unroll
    for (int l = 0; l < 4; ++l) {
      const int lab = labs[341 + l];
      const float tbv = tbS[(1 + l) * 32 + lane];
      float bcv = tbv * __expf(regB[lab * 33 + lane]);
      bcv /= rsum32(bcv);
      const float e = bcv * w[l];
      ll += (double)(bcv * u[l]) + (double)(e * regB[lab * 33 + lane]);
      tbS[(1 + l) * 32 + lane] = e / tbv;
    }
  }
  __syncthreads();
  if (grp < 4) {
    const int p = grp;
    r_buf[p * 32 + lane] = tbS[(1 + p) * 32 + lane];
    float w[4], u[4];
    WU128M(w, u, r_buf + p * 32)
#pragma unroll
    for (int l = 0; l < 4; ++l) {
      const int q = p * 4 + l;
      const int lab = labs[345 + q];
      const float tbv = tbS[(5 + q) * 32 + lane];
      float bcv = tbv * __expf(regB[lab * 33 + lane]);
      bcv /= rsum32(bcv);
      const float e = bcv * w[l];
      ll += (double)(bcv * u[l]) + (double)(e * regB[lab * 33 + lane]);
      tbS[(5 + q) * 32 + lane] = e / tbv;
    }
  }
  __syncthreads();
  {  // d2: 16 L6 parents, one per group
    const int p = grp;
    float* rb0 = r_buf + grp * 32;
    rb0[lane] = tbS[(5 + p) * 32 + lane];
    float w[4], u[4];
    WU128M(w, u, rb0)
#pragma unroll
    for (int l = 0; l < 4; ++l) {
      const int q = p * 4 + l;
      const float lb = regB[labs[361 + q] * 33 + lane];
      const float lp = sPt[l * 33 + lane];
      float b = __expf(lp + lb);
      b /= rsum32(b);
      const float e = b * w[l];
      ll += (double)(b * u[l]) + (double)(e * lb) + (double)(e * lp);
    }
  }

  // ---------- phase 7: partials + tree finalize ----------
#pragma unroll
  for (int k = 32; k >= 1; k >>= 1) ll += __shfl_xor(ll, k);
  double* rbd = (double*)r_buf;
  __syncthreads();
  if ((t & 63) == 0) rbd[t >> 6] = ll;
  __syncthreads();
  if (t == 0) {
    partd[s] = ((rbd[0] + rbd[1]) + (rbd[2] + rbd[3])) +
               ((rbd[4] + rbd[5]) + (rbd[6] + rbd[7]));
    __threadfence();
    int f = 0;
    if (atomicAdd(&wsi[IC2 + 32 * (s >> 4)], 1) == 15)
      if (atomicAdd(&wsi[IROOT2], 1) == 15) f = 1;
    fin = f;
  }
  __syncthreads();
  if (fin) {
    __threadfence();
    if (t < 64) {
      double v = 0.0;
      for (int k = t; k < 256; k += 64) v += partd[k];
#pragma unroll
      for (int k = 32; k >= 1; k >>= 1) v += __shfl_xor(v, k);
      if (t == 0) out[0] = (float)v;
    }
  }
}

extern "C" void kernel_launch(void* const* d_in, const int* in_sizes, int n_in,
                              void* d_out, int out_size, void* d_ws, size_t ws_size,
                              hipStream_t stream) {
  (void)in_sizes; (void)n_in; (void)out_size;
  const int* labels = (const int*)d_in[0];
  const float* A = (const float*)d_in[1];
  const float* B = (const float*)d_in[2];
  const float* Pi = (const float*)d_in[3];
  const float* SP = (const float*)d_in[4];
  float* ws = (float*)d_ws;
  float* out = (float*)d_out;

  // ws_size is constant across calls -> host branch is graph-capture-safe.
  if (ws_size >= WS_NEED_BYTES) {
    hipLaunchKernelGGL(k_up_p, dim3(256), dim3(512), 0, stream,
                       labels, A, B, Pi, SP, ws);
    hipLaunchKernelGGL(k_down_p, dim3(256), dim3(512), 0, stream,
                       labels, ws, ws, out);
  } else {
    hipLaunchKernelGGL(k_up_f, dim3(256), dim3(256), 0, stream,
                       labels, A, B, Pi, SP, ws);
    hipLaunchKernelGGL(k_down_f, dim3(256), dim3(512), 0, stream,
                       labels, A, B, Pi, SP, ws, out);
  }
}